// Round 6
// baseline (1694.065 us; speedup 1.0000x reference)
//
#include <hip/hip_runtime.h>
#include <hip/hip_bf16.h>

// Problem geometry (fixed by the reference):
// B=4, C=256, H=W=112, ps=7, N=49, nP=256 windows/batch, NH=8, d=32.
// Inputs fp32. d_out is FP32 (reference output dtype): [out | shortcut], each (B,C,H,W).

#define PS 7
#define NWIN_N 49
#define CH 256
#define HH 112
#define WW 112
#define BB 4
#define NHEAD 8
#define HD 32

static constexpr size_t ELEMS = (size_t)BB * CH * HH * WW;      // 12,845,056
static constexpr size_t SZ    = ELEMS * 2;                      // bytes of one bf16 plane

// ---------------------------------------------------------------------------
// 1) LayerNorm over C + window partition -> patches[(b*256+p)*49+i][c] (bf16)
// block = (b*112 + h)*7 + seg ; seg covers 16 w-columns; 256 threads.
// ---------------------------------------------------------------------------
__global__ __launch_bounds__(256) void ln_partition_kernel(
    const float* __restrict__ x, const float* __restrict__ gamma,
    const float* __restrict__ beta, __hip_bfloat16* __restrict__ patches)
{
    int blk = blockIdx.x;
    int seg = blk % 7;
    int bh = blk / 7;
    int h = bh % HH, b = bh / HH;
    int w0 = seg * 16;
    int tid = threadIdx.x;

    __shared__ float X[256][17];
    __shared__ float mus[16], rstds[16];

    #pragma unroll
    for (int l = 0; l < 16; ++l) {
        int idx = l * 256 + tid;
        int c = idx >> 4, wl = idx & 15;
        X[c][wl] = x[((size_t)(b * CH + c) * HH + h) * WW + w0 + wl];
    }
    __syncthreads();

    if (tid < 16) {
        float s = 0.f, ss = 0.f;
        for (int c = 0; c < 256; ++c) { float v = X[c][tid]; s += v; ss += v * v; }
        float mu = s * (1.f / 256.f);
        float var = ss * (1.f / 256.f) - mu * mu;
        mus[tid] = mu;
        rstds[tid] = rsqrtf(var + 1e-5f);
    }
    __syncthreads();

    int c = tid;
    float g = gamma[c], be = beta[c];
    int hp = h / PS, r = h - hp * PS;
    #pragma unroll
    for (int wl = 0; wl < 16; ++wl) {
        int w = w0 + wl;
        int wp = w / PS, cc = w - wp * PS;
        int win = (b * 16 + hp) * 16 + wp;
        int i = r * PS + cc;
        float v = (X[c][wl] - mus[wl]) * rstds[wl] * g + be;
        patches[((size_t)win * NWIN_N + i) * CH + c] = __float2bfloat16(v);
    }
}

// ---------------------------------------------------------------------------
// 2) shortcut: fp32 -> fp32 copy (float4 vectorized)
// ---------------------------------------------------------------------------
__global__ __launch_bounds__(256) void copy_f32_kernel(
    const float* __restrict__ x, float* __restrict__ out)
{
    size_t i = ((size_t)blockIdx.x * 256 + threadIdx.x) * 4;
    *(float4*)(out + i) = *(const float4*)(x + i);
}

// ---------------------------------------------------------------------------
// 3) generic GEMM: C[M][N] = A[M][K] @ W[K][N] + bias (A bf16 row stride K)
// BM=BN=64, BK=16, 256 thr, 4x4/thread. M multiple of 64; N,K guarded.
// ---------------------------------------------------------------------------
__global__ __launch_bounds__(256) void gemm_bf16_kernel(
    const __hip_bfloat16* __restrict__ A,
    const float* __restrict__ W, const float* __restrict__ bias,
    __hip_bfloat16* __restrict__ Cout, int M, int N, int K)
{
    __shared__ float As[16][65];
    __shared__ float Ws[16][65];
    int m0 = blockIdx.y * 64, n0 = blockIdx.x * 64;
    int tid = threadIdx.x;
    int tx = tid & 15, ty = tid >> 4;
    float acc[4][4] = {};

    for (int k0 = 0; k0 < K; k0 += 16) {
        #pragma unroll
        for (int l = 0; l < 4; ++l) {
            int idx = l * 256 + tid;
            int rr = idx >> 4;      // 0..63
            int kk = idx & 15;
            int k = k0 + kk;
            float v = 0.f;
            if (k < K) v = __bfloat162float(A[(size_t)(m0 + rr) * K + k]);
            As[kk][rr] = v;
        }
        #pragma unroll
        for (int l = 0; l < 4; ++l) {
            int idx = l * 256 + tid;
            int rr = idx >> 6;      // 0..15
            int cc = idx & 63;
            int k = k0 + rr, n = n0 + cc;
            Ws[rr][cc] = (k < K && n < N) ? W[(size_t)k * N + n] : 0.f;
        }
        __syncthreads();
        #pragma unroll
        for (int kk = 0; kk < 16; ++kk) {
            float a[4], bb[4];
            #pragma unroll
            for (int i = 0; i < 4; ++i) a[i] = As[kk][ty * 4 + i];
            #pragma unroll
            for (int j = 0; j < 4; ++j) bb[j] = Ws[kk][tx * 4 + j];
            #pragma unroll
            for (int i = 0; i < 4; ++i)
                #pragma unroll
                for (int j = 0; j < 4; ++j)
                    acc[i][j] += a[i] * bb[j];
        }
        __syncthreads();
    }

    #pragma unroll
    for (int i = 0; i < 4; ++i) {
        int m = m0 + ty * 4 + i;
        #pragma unroll
        for (int j = 0; j < 4; ++j) {
            int n = n0 + tx * 4 + j;
            if (n < N) {
                float v = acc[i][j] + (bias ? bias[n] : 0.f);
                Cout[(size_t)m * N + n] = __float2bfloat16(v);
            }
        }
    }
}

// ---------------------------------------------------------------------------
// 3b) FINAL GEMM, fused epilogue: [localOut | crossT] (50176x512) @ proj_w
// (512x256) -> writes FP32 out0 directly in (B,C,H,W) order. grid dim3(4,784).
// ---------------------------------------------------------------------------
__global__ __launch_bounds__(256) void final_gemm_out_kernel(
    const __hip_bfloat16* __restrict__ A1,   // localOut [50176][256]
    const __hip_bfloat16* __restrict__ A2,   // crossT   [50176][256]
    const float* __restrict__ W,             // proj_w [512][256]
    float* __restrict__ out)                 // fp32 [4][256][112][112]
{
    __shared__ float As[16][65];
    __shared__ float Ws[16][65];
    int m0 = blockIdx.y * 64, n0 = blockIdx.x * 64;
    int tid = threadIdx.x;
    int tx = tid & 15, ty = tid >> 4;
    float acc[4][4] = {};

    for (int k0 = 0; k0 < 512; k0 += 16) {
        #pragma unroll
        for (int l = 0; l < 4; ++l) {
            int idx = l * 256 + tid;
            int rr = idx >> 4, kk = idx & 15;
            int k = k0 + kk;
            size_t m = (size_t)(m0 + rr);
            float v = (k < 256) ? __bfloat162float(A1[m * 256 + k])
                                : __bfloat162float(A2[m * 256 + (k - 256)]);
            As[kk][rr] = v;
        }
        #pragma unroll
        for (int l = 0; l < 4; ++l) {
            int idx = l * 256 + tid;
            int rr = idx >> 6, cc = idx & 63;
            Ws[rr][cc] = W[(size_t)(k0 + rr) * 256 + n0 + cc];
        }
        __syncthreads();
        #pragma unroll
        for (int kk = 0; kk < 16; ++kk) {
            float a[4], bb[4];
            #pragma unroll
            for (int i = 0; i < 4; ++i) a[i] = As[kk][ty * 4 + i];
            #pragma unroll
            for (int j = 0; j < 4; ++j) bb[j] = Ws[kk][tx * 4 + j];
            #pragma unroll
            for (int i = 0; i < 4; ++i)
                #pragma unroll
                for (int j = 0; j < 4; ++j)
                    acc[i][j] += a[i] * bb[j];
        }
        __syncthreads();
    }

    // epilogue: m = (b*256 + p)*49 + t ; p = hp*16+wp ; t = r*7+c7
    #pragma unroll
    for (int i = 0; i < 4; ++i) {
        int m = m0 + ty * 4 + i;
        int b = m / 12544;
        int rem = m - b * 12544;
        int p = rem / 49, t = rem - p * 49;
        int hp = p >> 4, wp = p & 15;
        int r = t / 7, c7 = t - r * 7;
        int h = hp * 7 + r, w = wp * 7 + c7;
        size_t obase = ((size_t)(b * 256) * HH + h) * WW + w;
        #pragma unroll
        for (int j = 0; j < 4; ++j) {
            int ch = n0 + tx * 4 + j;
            out[obase + (size_t)ch * (HH * WW)] = acc[i][j];
        }
    }
}

// ---------------------------------------------------------------------------
// 4) local windowed attention with relative position bias.
// ---------------------------------------------------------------------------
__global__ __launch_bounds__(64) void local_attn_kernel(
    const __hip_bfloat16* __restrict__ qkv,   // [50176][768]
    const float* __restrict__ rpb,            // [169][8]
    __hip_bfloat16* __restrict__ outp)        // [50176][256]
{
    int win = blockIdx.x >> 3;
    int head = blockIdx.x & 7;
    int tid = threadIdx.x;
    __shared__ float ks[NWIN_N][33], vsh[NWIN_N][33];
    const size_t rowbase = (size_t)win * NWIN_N * 768;

    for (int idx = tid; idx < NWIN_N * HD; idx += 64) {
        int i = idx >> 5, dd = idx & 31;
        size_t ro = rowbase + (size_t)i * 768 + head * HD + dd;
        ks[i][dd]  = __bfloat162float(qkv[ro + 256]);
        vsh[i][dd] = __bfloat162float(qkv[ro + 512]);
    }
    __syncthreads();

    if (tid < NWIN_N) {
        int i = tid;
        float q[HD];
        #pragma unroll
        for (int dd = 0; dd < HD; ++dd)
            q[dd] = __bfloat162float(qkv[rowbase + (size_t)i * 768 + head * HD + dd]);
        int ri = i / PS, ci = i - (i / PS) * PS;
        const float scale = 0.17677669529663687f;   // 32^-0.5
        float sc[NWIN_N];
        float mx = -1e30f;
        #pragma unroll
        for (int j = 0; j < NWIN_N; ++j) {
            float s = 0.f;
            #pragma unroll
            for (int dd = 0; dd < HD; ++dd) s += q[dd] * ks[j][dd];
            int rj = j / PS, cj = j - (j / PS) * PS;
            s = s * scale + rpb[((ri - rj + 6) * 13 + (ci - cj + 6)) * NHEAD + head];
            sc[j] = s;
            mx = fmaxf(mx, s);
        }
        float l = 0.f;
        #pragma unroll
        for (int j = 0; j < NWIN_N; ++j) { sc[j] = __expf(sc[j] - mx); l += sc[j]; }
        float inv = 1.f / l;
        float o[HD];
        #pragma unroll
        for (int dd = 0; dd < HD; ++dd) o[dd] = 0.f;
        #pragma unroll
        for (int j = 0; j < NWIN_N; ++j) {
            float pw = sc[j];
            #pragma unroll
            for (int dd = 0; dd < HD; ++dd) o[dd] += pw * vsh[j][dd];
        }
        size_t ob = ((size_t)win * NWIN_N + i) * CH + head * HD;
        #pragma unroll
        for (int dd = 0; dd < HD; ++dd) outp[ob + dd] = __float2bfloat16(o[dd] * inv);
    }
}

// ---------------------------------------------------------------------------
// 5) cross-channel attention: block per (b,c), thread p (256 tokens), dim 49
// ---------------------------------------------------------------------------
__global__ __launch_bounds__(256) void cross_attn_kernel(
    const __hip_bfloat16* __restrict__ qkv,   // [262144][147]
    __hip_bfloat16* __restrict__ outp)        // [262144][49]
{
    int bc = blockIdx.x;
    int p = threadIdx.x;
    __shared__ __hip_bfloat16 ks[256][50], vsh[256][50];
    const size_t base = (size_t)bc * 256;

    for (int idx = p; idx < 256 * 49; idx += 256) {
        int j = idx / 49, n = idx - j * 49;
        size_t ro = (base + j) * 147;
        ks[j][n]  = qkv[ro + 49 + n];
        vsh[j][n] = qkv[ro + 98 + n];
    }
    __syncthreads();

    float q[49];
    #pragma unroll
    for (int n = 0; n < 49; ++n) q[n] = __bfloat162float(qkv[(base + p) * 147 + n]);
    const float scale = 1.f / 7.f;   // 49^-0.5
    float m = -1e30f, l = 0.f;
    float o[49];
    #pragma unroll
    for (int n = 0; n < 49; ++n) o[n] = 0.f;

    for (int j = 0; j < 256; ++j) {
        float s = 0.f;
        #pragma unroll
        for (int n = 0; n < 49; ++n) s += q[n] * __bfloat162float(ks[j][n]);
        s *= scale;
        if (s > m) {
            float corr = __expf(m - s);
            l *= corr;
            #pragma unroll
            for (int n = 0; n < 49; ++n) o[n] *= corr;
            m = s;
        }
        float e = __expf(s - m);
        l += e;
        #pragma unroll
        for (int n = 0; n < 49; ++n) o[n] += e * __bfloat162float(vsh[j][n]);
    }
    float inv = 1.f / l;
    size_t ob = (base + p) * 49;
    #pragma unroll
    for (int n = 0; n < 49; ++n) outp[ob + n] = __float2bfloat16(o[n] * inv);
}

// ---------------------------------------------------------------------------
// 6) batched 2D transpose: src[b][R][Cc] -> dst[b][Cc][R]; grid (Cc/64,R/64,B)
// ---------------------------------------------------------------------------
__global__ __launch_bounds__(256) void transpose_bf16_kernel(
    const __hip_bfloat16* __restrict__ src, __hip_bfloat16* __restrict__ dst,
    int R, int Cc)
{
    __shared__ __hip_bfloat16 T[64][66];
    int b = blockIdx.z;
    int r0 = blockIdx.y * 64, c0 = blockIdx.x * 64;
    const __hip_bfloat16* s = src + (size_t)b * R * Cc;
    __hip_bfloat16* d = dst + (size_t)b * R * Cc;
    int tid = threadIdx.x;
    int lr = tid >> 6, lc = tid & 63;

    #pragma unroll
    for (int l = 0; l < 16; ++l) {
        int rr = l * 4 + lr;
        T[rr][lc] = s[(size_t)(r0 + rr) * Cc + c0 + lc];
    }
    __syncthreads();
    #pragma unroll
    for (int l = 0; l < 16; ++l) {
        int cc = l * 4 + lr;
        d[(size_t)(c0 + cc) * R + r0 + lc] = T[lc][cc];
    }
}

// ---------------------------------------------------------------------------
// fallback marker if workspace too small (diagnosable as ~777 error)
// ---------------------------------------------------------------------------
__global__ void ws_marker_kernel(float* __restrict__ out0)
{
    if (threadIdx.x == 0) out0[0] = 777.0f;
}

// ---------------------------------------------------------------------------
extern "C" void kernel_launch(void* const* d_in, const int* in_sizes, int n_in,
                              void* d_out, int out_size, void* d_ws, size_t ws_size,
                              hipStream_t stream)
{
    const float* x        = (const float*)d_in[0];
    const float* gamma    = (const float*)d_in[1];
    const float* beta     = (const float*)d_in[2];
    const float* qkv_l_w  = (const float*)d_in[3];
    const float* qkv_l_b  = (const float*)d_in[4];
    const float* proj_l_w = (const float*)d_in[5];
    const float* proj_l_b = (const float*)d_in[6];
    const float* rpb      = (const float*)d_in[7];
    const float* qkv_c_w  = (const float*)d_in[8];
    const float* qkv_c_b  = (const float*)d_in[9];
    const float* proj_c_w = (const float*)d_in[10];
    const float* proj_c_b = (const float*)d_in[11];
    const float* proj_w   = (const float*)d_in[12];

    float* out0 = (float*)d_out;              // (B,C,H,W) fp32
    float* out1 = out0 + ELEMS;               // shortcut  fp32

    // shortcut copy (fp32 exact), float4-vectorized: ELEMS = 1024 * 12544
    copy_f32_kernel<<<(int)(ELEMS / 1024), 256, 0, stream>>>(x, out1);

    char* ws = (char*)d_ws;
    if (ws_size < 6 * SZ) {
        ws_marker_kernel<<<1, 64, 0, stream>>>(out0);
        return;
    }

    // plane map (simple write->read lifetimes)
    __hip_bfloat16* patches   = (__hip_bfloat16*)(ws + 0 * SZ);  // K1 W; K3,K6 R
    __hip_bfloat16* qkv_l     = (__hip_bfloat16*)(ws + 1 * SZ);  // planes 1-3
    __hip_bfloat16* attnL     = (__hip_bfloat16*)(ws + 4 * SZ);
    __hip_bfloat16* localOut  = (__hip_bfloat16*)(ws + 5 * SZ);
    __hip_bfloat16* pc        = (__hip_bfloat16*)(ws + 1 * SZ);
    __hip_bfloat16* qkvc      = (__hip_bfloat16*)(ws + 2 * SZ);  // planes 2-4
    __hip_bfloat16* crossAttn = (__hip_bfloat16*)(ws + 1 * SZ);
    __hip_bfloat16* crossProj = (__hip_bfloat16*)(ws + 2 * SZ);
    __hip_bfloat16* crossT    = (__hip_bfloat16*)(ws + 3 * SZ);

    ln_partition_kernel<<<BB * HH * 7, 256, 0, stream>>>(x, gamma, beta, patches);
    gemm_bf16_kernel<<<dim3(12, 784), 256, 0, stream>>>(
        patches, qkv_l_w, qkv_l_b, qkv_l, 50176, 768, 256);
    local_attn_kernel<<<1024 * NHEAD, 64, 0, stream>>>(qkv_l, rpb, attnL);
    gemm_bf16_kernel<<<dim3(4, 784), 256, 0, stream>>>(
        attnL, proj_l_w, proj_l_b, localOut, 50176, 256, 256);
    transpose_bf16_kernel<<<dim3(4, 196, BB), 256, 0, stream>>>(patches, pc, 12544, 256);
    gemm_bf16_kernel<<<dim3(3, 4096), 256, 0, stream>>>(
        pc, qkv_c_w, qkv_c_b, qkvc, 262144, 147, 49);
    cross_attn_kernel<<<1024, 256, 0, stream>>>(qkvc, crossAttn);
    gemm_bf16_kernel<<<dim3(1, 4096), 256, 0, stream>>>(
        crossAttn, proj_c_w, proj_c_b, crossProj, 262144, 49, 49);
    transpose_bf16_kernel<<<dim3(196, 4, BB), 256, 0, stream>>>(crossProj, crossT, 256, 12544);
    final_gemm_out_kernel<<<dim3(4, 784), 256, 0, stream>>>(localOut, crossT, proj_w, out0);
}

// Round 7
// 1306.085 us; speedup vs baseline: 1.2971x; 1.2971x over previous
//
#include <hip/hip_runtime.h>
#include <hip/hip_bf16.h>

// Problem geometry (fixed by the reference):
// B=4, C=256, H=W=112, ps=7, N=49, nP=256 windows/batch, NH=8, d=32.
// Inputs fp32. d_out is FP32: [out | shortcut], each (B,C,H,W).

#define PS 7
#define NWIN_N 49
#define CH 256
#define HH 112
#define WW 112
#define BB 4
#define NHEAD 8
#define HD 32

static constexpr size_t ELEMS = (size_t)BB * CH * HH * WW;      // 12,845,056
static constexpr size_t SZ    = ELEMS * 2;                      // bytes of one bf16 plane

typedef __attribute__((ext_vector_type(8))) short short8;
typedef __attribute__((ext_vector_type(4))) float f32x4;

static __device__ __forceinline__ unsigned short bf16_bits(float v) {
    __hip_bfloat16 h = __float2bfloat16(v);
    return *reinterpret_cast<unsigned short*>(&h);
}

// ---------------------------------------------------------------------------
// 1) LayerNorm over C + window partition -> patches[(b*256+p)*49+i][c] (bf16)
// ---------------------------------------------------------------------------
__global__ __launch_bounds__(256) void ln_partition_kernel(
    const float* __restrict__ x, const float* __restrict__ gamma,
    const float* __restrict__ beta, __hip_bfloat16* __restrict__ patches)
{
    int blk = blockIdx.x;
    int seg = blk % 7;
    int bh = blk / 7;
    int h = bh % HH, b = bh / HH;
    int w0 = seg * 16;
    int tid = threadIdx.x;

    __shared__ float X[256][17];
    __shared__ float mus[16], rstds[16];

    #pragma unroll
    for (int l = 0; l < 16; ++l) {
        int idx = l * 256 + tid;
        int c = idx >> 4, wl = idx & 15;
        X[c][wl] = x[((size_t)(b * CH + c) * HH + h) * WW + w0 + wl];
    }
    __syncthreads();

    if (tid < 16) {
        float s = 0.f, ss = 0.f;
        for (int c = 0; c < 256; ++c) { float v = X[c][tid]; s += v; ss += v * v; }
        float mu = s * (1.f / 256.f);
        float var = ss * (1.f / 256.f) - mu * mu;
        mus[tid] = mu;
        rstds[tid] = rsqrtf(var + 1e-5f);
    }
    __syncthreads();

    int c = tid;
    float g = gamma[c], be = beta[c];
    int hp = h / PS, r = h - hp * PS;
    #pragma unroll
    for (int wl = 0; wl < 16; ++wl) {
        int w = w0 + wl;
        int wp = w / PS, cc = w - wp * PS;
        int win = (b * 16 + hp) * 16 + wp;
        int i = r * PS + cc;
        float v = (X[c][wl] - mus[wl]) * rstds[wl] * g + be;
        patches[((size_t)win * NWIN_N + i) * CH + c] = __float2bfloat16(v);
    }
}

// ---------------------------------------------------------------------------
// 2) shortcut: fp32 -> fp32 copy (float4 vectorized)
// ---------------------------------------------------------------------------
__global__ __launch_bounds__(256) void copy_f32_kernel(
    const float* __restrict__ x, float* __restrict__ out)
{
    size_t i = ((size_t)blockIdx.x * 256 + threadIdx.x) * 4;
    *(float4*)(out + i) = *(const float4*)(x + i);
}

// ---------------------------------------------------------------------------
// 3) generic GEMM: C[M][N] = A[M][K] @ W[K][N] + bias (A bf16 row stride K)
// BM=BN=64, BK=16, 256 thr, 4x4/thread. M multiple of 64; N,K guarded.
// ---------------------------------------------------------------------------
__global__ __launch_bounds__(256) void gemm_bf16_kernel(
    const __hip_bfloat16* __restrict__ A,
    const float* __restrict__ W, const float* __restrict__ bias,
    __hip_bfloat16* __restrict__ Cout, int M, int N, int K)
{
    __shared__ float As[16][65];
    __shared__ float Ws[16][65];
    int m0 = blockIdx.y * 64, n0 = blockIdx.x * 64;
    int tid = threadIdx.x;
    int tx = tid & 15, ty = tid >> 4;
    float acc[4][4] = {};

    for (int k0 = 0; k0 < K; k0 += 16) {
        #pragma unroll
        for (int l = 0; l < 4; ++l) {
            int idx = l * 256 + tid;
            int rr = idx >> 4;      // 0..63
            int kk = idx & 15;
            int k = k0 + kk;
            float v = 0.f;
            if (k < K) v = __bfloat162float(A[(size_t)(m0 + rr) * K + k]);
            As[kk][rr] = v;
        }
        #pragma unroll
        for (int l = 0; l < 4; ++l) {
            int idx = l * 256 + tid;
            int rr = idx >> 6;      // 0..15
            int cc = idx & 63;
            int k = k0 + rr, n = n0 + cc;
            Ws[rr][cc] = (k < K && n < N) ? W[(size_t)k * N + n] : 0.f;
        }
        __syncthreads();
        #pragma unroll
        for (int kk = 0; kk < 16; ++kk) {
            float a[4], bb[4];
            #pragma unroll
            for (int i = 0; i < 4; ++i) a[i] = As[kk][ty * 4 + i];
            #pragma unroll
            for (int j = 0; j < 4; ++j) bb[j] = Ws[kk][tx * 4 + j];
            #pragma unroll
            for (int i = 0; i < 4; ++i)
                #pragma unroll
                for (int j = 0; j < 4; ++j)
                    acc[i][j] += a[i] * bb[j];
        }
        __syncthreads();
    }

    #pragma unroll
    for (int i = 0; i < 4; ++i) {
        int m = m0 + ty * 4 + i;
        #pragma unroll
        for (int j = 0; j < 4; ++j) {
            int n = n0 + tx * 4 + j;
            if (n < N) {
                float v = acc[i][j] + (bias ? bias[n] : 0.f);
                Cout[(size_t)m * N + n] = __float2bfloat16(v);
            }
        }
    }
}

// ---------------------------------------------------------------------------
// 3b) FINAL GEMM, fused epilogue: [localOut | crossT] (50176x512) @ proj_w
// (512x256) -> writes FP32 out0 directly in (B,C,H,W) order. grid dim3(4,784).
// ---------------------------------------------------------------------------
__global__ __launch_bounds__(256) void final_gemm_out_kernel(
    const __hip_bfloat16* __restrict__ A1,   // localOut [50176][256]
    const __hip_bfloat16* __restrict__ A2,   // crossT   [50176][256]
    const float* __restrict__ W,             // proj_w [512][256]
    float* __restrict__ out)                 // fp32 [4][256][112][112]
{
    __shared__ float As[16][65];
    __shared__ float Ws[16][65];
    int m0 = blockIdx.y * 64, n0 = blockIdx.x * 64;
    int tid = threadIdx.x;
    int tx = tid & 15, ty = tid >> 4;
    float acc[4][4] = {};

    for (int k0 = 0; k0 < 512; k0 += 16) {
        #pragma unroll
        for (int l = 0; l < 4; ++l) {
            int idx = l * 256 + tid;
            int rr = idx >> 4, kk = idx & 15;
            int k = k0 + kk;
            size_t m = (size_t)(m0 + rr);
            float v = (k < 256) ? __bfloat162float(A1[m * 256 + k])
                                : __bfloat162float(A2[m * 256 + (k - 256)]);
            As[kk][rr] = v;
        }
        #pragma unroll
        for (int l = 0; l < 4; ++l) {
            int idx = l * 256 + tid;
            int rr = idx >> 6, cc = idx & 63;
            Ws[rr][cc] = W[(size_t)(k0 + rr) * 256 + n0 + cc];
        }
        __syncthreads();
        #pragma unroll
        for (int kk = 0; kk < 16; ++kk) {
            float a[4], bb[4];
            #pragma unroll
            for (int i = 0; i < 4; ++i) a[i] = As[kk][ty * 4 + i];
            #pragma unroll
            for (int j = 0; j < 4; ++j) bb[j] = Ws[kk][tx * 4 + j];
            #pragma unroll
            for (int i = 0; i < 4; ++i)
                #pragma unroll
                for (int j = 0; j < 4; ++j)
                    acc[i][j] += a[i] * bb[j];
        }
        __syncthreads();
    }

    // epilogue: m = (b*256 + p)*49 + t ; p = hp*16+wp ; t = r*7+c7
    #pragma unroll
    for (int i = 0; i < 4; ++i) {
        int m = m0 + ty * 4 + i;
        int b = m / 12544;
        int rem = m - b * 12544;
        int p = rem / 49, t = rem - p * 49;
        int hp = p >> 4, wp = p & 15;
        int r = t / 7, c7 = t - r * 7;
        int h = hp * 7 + r, w = wp * 7 + c7;
        size_t obase = ((size_t)(b * 256) * HH + h) * WW + w;
        #pragma unroll
        for (int j = 0; j < 4; ++j) {
            int ch = n0 + tx * 4 + j;
            out[obase + (size_t)ch * (HH * WW)] = acc[i][j];
        }
    }
}

// ---------------------------------------------------------------------------
// 4) local windowed attention with relative position bias.
// ---------------------------------------------------------------------------
__global__ __launch_bounds__(64) void local_attn_kernel(
    const __hip_bfloat16* __restrict__ qkv,   // [50176][768]
    const float* __restrict__ rpb,            // [169][8]
    __hip_bfloat16* __restrict__ outp)        // [50176][256]
{
    int win = blockIdx.x >> 3;
    int head = blockIdx.x & 7;
    int tid = threadIdx.x;
    __shared__ float ks[NWIN_N][33], vsh[NWIN_N][33];
    const size_t rowbase = (size_t)win * NWIN_N * 768;

    for (int idx = tid; idx < NWIN_N * HD; idx += 64) {
        int i = idx >> 5, dd = idx & 31;
        size_t ro = rowbase + (size_t)i * 768 + head * HD + dd;
        ks[i][dd]  = __bfloat162float(qkv[ro + 256]);
        vsh[i][dd] = __bfloat162float(qkv[ro + 512]);
    }
    __syncthreads();

    if (tid < NWIN_N) {
        int i = tid;
        float q[HD];
        #pragma unroll
        for (int dd = 0; dd < HD; ++dd)
            q[dd] = __bfloat162float(qkv[rowbase + (size_t)i * 768 + head * HD + dd]);
        int ri = i / PS, ci = i - (i / PS) * PS;
        const float scale = 0.17677669529663687f;   // 32^-0.5
        float sc[NWIN_N];
        float mx = -1e30f;
        #pragma unroll
        for (int j = 0; j < NWIN_N; ++j) {
            float s = 0.f;
            #pragma unroll
            for (int dd = 0; dd < HD; ++dd) s += q[dd] * ks[j][dd];
            int rj = j / PS, cj = j - (j / PS) * PS;
            s = s * scale + rpb[((ri - rj + 6) * 13 + (ci - cj + 6)) * NHEAD + head];
            sc[j] = s;
            mx = fmaxf(mx, s);
        }
        float l = 0.f;
        #pragma unroll
        for (int j = 0; j < NWIN_N; ++j) { sc[j] = __expf(sc[j] - mx); l += sc[j]; }
        float inv = 1.f / l;
        float o[HD];
        #pragma unroll
        for (int dd = 0; dd < HD; ++dd) o[dd] = 0.f;
        #pragma unroll
        for (int j = 0; j < NWIN_N; ++j) {
            float pw = sc[j];
            #pragma unroll
            for (int dd = 0; dd < HD; ++dd) o[dd] += pw * vsh[j][dd];
        }
        size_t ob = ((size_t)win * NWIN_N + i) * CH + head * HD;
        #pragma unroll
        for (int dd = 0; dd < HD; ++dd) outp[ob + dd] = __float2bfloat16(o[dd] * inv);
    }
}

// ---------------------------------------------------------------------------
// 5) cross-channel attention, MFMA flash version.
// Block = (b,c) pair (1024 blocks), 256 threads = 4 waves; wave owns 64 i.
// S^T = mfma(A=K_tile, B=Q): C col = i (lane&15), row = j (4*(lane>>4)+reg).
// Online softmax over j via 4-lane shfl_xor(16,32). P -> LDS [i][j] bf16.
// O^T = mfma(A=V^T, B=P): rows d, cols i. All LDS rows padded to 72 bf16
// (144B stride -> 2-way bank aliasing = free). k dim 49 zero-padded to 64.
// ---------------------------------------------------------------------------
__global__ __launch_bounds__(256) void cross_attn_mfma_kernel(
    const __hip_bfloat16* __restrict__ qkv,   // [262144][147] q|k|v
    __hip_bfloat16* __restrict__ outp)        // [262144][49]
{
    __shared__ __align__(16) unsigned short K_lds[64][72];
    __shared__ __align__(16) unsigned short VT_lds[64][72];
    __shared__ __align__(16) unsigned short P_lds[256][72];

    const int bc = blockIdx.x;
    const size_t base = (size_t)bc * 256;
    const int tid  = threadIdx.x;
    const int lane = tid & 63;
    const int wave = tid >> 6;
    const int i0w  = wave * 64;
    const int lr   = lane & 15;   // A-row / B-col / C-col selector
    const int lk   = lane >> 4;   // k-group / C-row group

    const unsigned short* q16 = (const unsigned short*)qkv;
    const float inv7 = 1.f / 7.f;   // 49^-0.5

    // hoisted Q fragments (B-operand): lane holds Q[i][k0..k0+7],
    // i = i0w + it*16 + lr, k0 = lk*8 + kst*32 ; zero for k >= 49.
    short8 qf[4][2];
    #pragma unroll
    for (int it = 0; it < 4; ++it) {
        const unsigned short* qrow = q16 + (base + i0w + it * 16 + lr) * 147;
        #pragma unroll
        for (int kst = 0; kst < 2; ++kst) {
            int k0 = lk * 8 + kst * 32;
            short8 f;
            #pragma unroll
            for (int e = 0; e < 8; ++e) {
                int k = k0 + e;
                f[e] = (short)((k < 49) ? qrow[k] : 0);
            }
            qf[it][kst] = f;
        }
    }

    float m_run[4], l_run[4];
    f32x4 acc_o[4][4];   // [dt][it]
    #pragma unroll
    for (int it = 0; it < 4; ++it) { m_run[it] = -1e30f; l_run[it] = 0.f; }
    #pragma unroll
    for (int dt = 0; dt < 4; ++dt)
        #pragma unroll
        for (int it = 0; it < 4; ++it) acc_o[dt][it] = (f32x4){0.f, 0.f, 0.f, 0.f};

    for (int jt4 = 0; jt4 < 4; ++jt4) {
        const int j0 = jt4 * 64;

        // stage K (zero-padded k>=49) and V^T (rows d>=49 zeroed)
        {
            int row = tid >> 2, sub = tid & 3;            // row = token jj in tile
            const unsigned short* krow = q16 + (base + j0 + row) * 147 + 49;
            const unsigned short* vrow = q16 + (base + j0 + row) * 147 + 98;
            #pragma unroll
            for (int c = sub * 18; c < sub * 18 + 18; ++c) {
                K_lds[row][c] = (c < 49) ? krow[c] : (unsigned short)0;
                if (c < 64) VT_lds[c][row] = (c < 49) ? vrow[c] : (unsigned short)0;
            }
        }
        __syncthreads();

        #pragma unroll
        for (int it = 0; it < 4; ++it) {
            // ---- S^T for 4 j-subtiles ----
            f32x4 sacc[4];
            #pragma unroll
            for (int jt = 0; jt < 4; ++jt) sacc[jt] = (f32x4){0.f, 0.f, 0.f, 0.f};
            #pragma unroll
            for (int kst = 0; kst < 2; ++kst) {
                #pragma unroll
                for (int jt = 0; jt < 4; ++jt) {
                    short8 af = *(const short8*)&K_lds[jt * 16 + lr][lk * 8 + kst * 32];
                    sacc[jt] = __builtin_amdgcn_mfma_f32_16x16x32_bf16(
                        af, qf[it][kst], sacc[jt], 0, 0, 0);
                }
            }
            // ---- online softmax over j for this i-column ----
            float mt = -1e30f;
            #pragma unroll
            for (int jt = 0; jt < 4; ++jt)
                #pragma unroll
                for (int r = 0; r < 4; ++r) mt = fmaxf(mt, sacc[jt][r]);
            mt = fmaxf(mt, __shfl_xor(mt, 16, 64));
            mt = fmaxf(mt, __shfl_xor(mt, 32, 64));
            float mnew = fmaxf(m_run[it], mt * inv7);
            float corr = __expf(m_run[it] - mnew);
            m_run[it] = mnew;
            l_run[it] *= corr;
            #pragma unroll
            for (int dt = 0; dt < 4; ++dt)
                #pragma unroll
                for (int r = 0; r < 4; ++r) acc_o[dt][it][r] *= corr;

            float psum = 0.f;
            int irow = i0w + it * 16 + lr;
            #pragma unroll
            for (int jt = 0; jt < 4; ++jt) {
                float p0 = __expf(sacc[jt][0] * inv7 - mnew);
                float p1 = __expf(sacc[jt][1] * inv7 - mnew);
                float p2 = __expf(sacc[jt][2] * inv7 - mnew);
                float p3 = __expf(sacc[jt][3] * inv7 - mnew);
                psum += (p0 + p1) + (p2 + p3);
                uint2 w;
                w.x = (unsigned)bf16_bits(p0) | ((unsigned)bf16_bits(p1) << 16);
                w.y = (unsigned)bf16_bits(p2) | ((unsigned)bf16_bits(p3) << 16);
                *(uint2*)&P_lds[irow][jt * 16 + lk * 4] = w;
            }
            psum += __shfl_xor(psum, 16, 64);
            psum += __shfl_xor(psum, 32, 64);
            l_run[it] += psum;
        }

        // ---- PV: O^T += V^T @ P^T (wave reads ONLY its own P rows: no barrier) ----
        #pragma unroll
        for (int it = 0; it < 4; ++it) {
            #pragma unroll
            for (int kst = 0; kst < 2; ++kst) {
                short8 bf = *(const short8*)&P_lds[i0w + it * 16 + lr][lk * 8 + kst * 32];
                #pragma unroll
                for (int dt = 0; dt < 4; ++dt) {
                    short8 af = *(const short8*)&VT_lds[dt * 16 + lr][lk * 8 + kst * 32];
                    acc_o[dt][it] = __builtin_amdgcn_mfma_f32_16x16x32_bf16(
                        af, bf, acc_o[dt][it], 0, 0, 0);
                }
            }
        }
        __syncthreads();   // protect K/VT before next tile's staging
    }

    // epilogue: O[i][d] = acc_o / l ; C layout: col=i (lr), row=d (lk*4+r)
    #pragma unroll
    for (int it = 0; it < 4; ++it) {
        float inv = 1.f / l_run[it];
        unsigned short* orow = (unsigned short*)outp + (base + i0w + it * 16 + lr) * 49;
        #pragma unroll
        for (int dt = 0; dt < 4; ++dt) {
            #pragma unroll
            for (int r = 0; r < 4; ++r) {
                int d = dt * 16 + lk * 4 + r;
                if (d < 49) orow[d] = bf16_bits(acc_o[dt][it][r] * inv);
            }
        }
    }
}

// ---------------------------------------------------------------------------
// 6) batched 2D transpose: src[b][R][Cc] -> dst[b][Cc][R]; grid (Cc/64,R/64,B)
// ---------------------------------------------------------------------------
__global__ __launch_bounds__(256) void transpose_bf16_kernel(
    const __hip_bfloat16* __restrict__ src, __hip_bfloat16* __restrict__ dst,
    int R, int Cc)
{
    __shared__ __hip_bfloat16 T[64][66];
    int b = blockIdx.z;
    int r0 = blockIdx.y * 64, c0 = blockIdx.x * 64;
    const __hip_bfloat16* s = src + (size_t)b * R * Cc;
    __hip_bfloat16* d = dst + (size_t)b * R * Cc;
    int tid = threadIdx.x;
    int lr = tid >> 6, lc = tid & 63;

    #pragma unroll
    for (int l = 0; l < 16; ++l) {
        int rr = l * 4 + lr;
        T[rr][lc] = s[(size_t)(r0 + rr) * Cc + c0 + lc];
    }
    __syncthreads();
    #pragma unroll
    for (int l = 0; l < 16; ++l) {
        int cc = l * 4 + lr;
        d[(size_t)(c0 + cc) * R + r0 + lc] = T[lc][cc];
    }
}

// ---------------------------------------------------------------------------
__global__ void ws_marker_kernel(float* __restrict__ out0)
{
    if (threadIdx.x == 0) out0[0] = 777.0f;
}

// ---------------------------------------------------------------------------
extern "C" void kernel_launch(void* const* d_in, const int* in_sizes, int n_in,
                              void* d_out, int out_size, void* d_ws, size_t ws_size,
                              hipStream_t stream)
{
    const float* x        = (const float*)d_in[0];
    const float* gamma    = (const float*)d_in[1];
    const float* beta     = (const float*)d_in[2];
    const float* qkv_l_w  = (const float*)d_in[3];
    const float* qkv_l_b  = (const float*)d_in[4];
    const float* proj_l_w = (const float*)d_in[5];
    const float* proj_l_b = (const float*)d_in[6];
    const float* rpb      = (const float*)d_in[7];
    const float* qkv_c_w  = (const float*)d_in[8];
    const float* qkv_c_b  = (const float*)d_in[9];
    const float* proj_c_w = (const float*)d_in[10];
    const float* proj_c_b = (const float*)d_in[11];
    const float* proj_w   = (const float*)d_in[12];

    float* out0 = (float*)d_out;              // (B,C,H,W) fp32
    float* out1 = out0 + ELEMS;               // shortcut  fp32

    copy_f32_kernel<<<(int)(ELEMS / 1024), 256, 0, stream>>>(x, out1);

    char* ws = (char*)d_ws;
    if (ws_size < 6 * SZ) {
        ws_marker_kernel<<<1, 64, 0, stream>>>(out0);
        return;
    }

    // plane map (simple write->read lifetimes)
    __hip_bfloat16* patches   = (__hip_bfloat16*)(ws + 0 * SZ);
    __hip_bfloat16* qkv_l     = (__hip_bfloat16*)(ws + 1 * SZ);  // planes 1-3
    __hip_bfloat16* attnL     = (__hip_bfloat16*)(ws + 4 * SZ);
    __hip_bfloat16* localOut  = (__hip_bfloat16*)(ws + 5 * SZ);
    __hip_bfloat16* pc        = (__hip_bfloat16*)(ws + 1 * SZ);
    __hip_bfloat16* qkvc      = (__hip_bfloat16*)(ws + 2 * SZ);  // planes 2-4
    __hip_bfloat16* crossAttn = (__hip_bfloat16*)(ws + 1 * SZ);
    __hip_bfloat16* crossProj = (__hip_bfloat16*)(ws + 2 * SZ);
    __hip_bfloat16* crossT    = (__hip_bfloat16*)(ws + 3 * SZ);

    ln_partition_kernel<<<BB * HH * 7, 256, 0, stream>>>(x, gamma, beta, patches);
    gemm_bf16_kernel<<<dim3(12, 784), 256, 0, stream>>>(
        patches, qkv_l_w, qkv_l_b, qkv_l, 50176, 768, 256);
    local_attn_kernel<<<1024 * NHEAD, 64, 0, stream>>>(qkv_l, rpb, attnL);
    gemm_bf16_kernel<<<dim3(4, 784), 256, 0, stream>>>(
        attnL, proj_l_w, proj_l_b, localOut, 50176, 256, 256);
    transpose_bf16_kernel<<<dim3(4, 196, BB), 256, 0, stream>>>(patches, pc, 12544, 256);
    gemm_bf16_kernel<<<dim3(3, 4096), 256, 0, stream>>>(
        pc, qkv_c_w, qkv_c_b, qkvc, 262144, 147, 49);
    cross_attn_mfma_kernel<<<1024, 256, 0, stream>>>(qkvc, crossAttn);
    gemm_bf16_kernel<<<dim3(1, 4096), 256, 0, stream>>>(
        crossAttn, proj_c_w, proj_c_b, crossProj, 262144, 49, 49);
    transpose_bf16_kernel<<<dim3(196, 4, BB), 256, 0, stream>>>(crossProj, crossT, 256, 12544);
    final_gemm_out_kernel<<<dim3(4, 784), 256, 0, stream>>>(localOut, crossT, proj_w, out0);
}

// Round 8
// 527.227 us; speedup vs baseline: 3.2132x; 2.4773x over previous
//
#include <hip/hip_runtime.h>
#include <hip/hip_bf16.h>

// Problem geometry (fixed by the reference):
// B=4, C=256, H=W=112, ps=7, N=49, nP=256 windows/batch, NH=8, d=32.
// Inputs fp32. d_out is FP32: [out | shortcut], each (B,C,H,W).

#define PS 7
#define NWIN_N 49
#define CH 256
#define HH 112
#define WW 112
#define BB 4
#define NHEAD 8
#define HD 32

static constexpr size_t ELEMS = (size_t)BB * CH * HH * WW;      // 12,845,056
static constexpr size_t SZ    = ELEMS * 2;                      // 25,690,112 B (one bf16 plane)

typedef __attribute__((ext_vector_type(8))) short short8;
typedef __attribute__((ext_vector_type(4))) float f32x4;

static __device__ __forceinline__ unsigned short bf16_bits(float v) {
    __hip_bfloat16 h = __float2bfloat16(v);
    return *reinterpret_cast<unsigned short*>(&h);
}

// ---------------------------------------------------------------------------
// 1) LayerNorm over C + window partition -> patches[(b*256+p)*49+i][c] (bf16)
// ---------------------------------------------------------------------------
__global__ __launch_bounds__(256) void ln_partition_kernel(
    const float* __restrict__ x, const float* __restrict__ gamma,
    const float* __restrict__ beta, __hip_bfloat16* __restrict__ patches)
{
    int blk = blockIdx.x;
    int seg = blk % 7;
    int bh = blk / 7;
    int h = bh % HH, b = bh / HH;
    int w0 = seg * 16;
    int tid = threadIdx.x;

    __shared__ float X[256][17];
    __shared__ float mus[16], rstds[16];

    #pragma unroll
    for (int l = 0; l < 16; ++l) {
        int idx = l * 256 + tid;
        int c = idx >> 4, wl = idx & 15;
        X[c][wl] = x[((size_t)(b * CH + c) * HH + h) * WW + w0 + wl];
    }
    __syncthreads();

    if (tid < 16) {
        float s = 0.f, ss = 0.f;
        for (int c = 0; c < 256; ++c) { float v = X[c][tid]; s += v; ss += v * v; }
        float mu = s * (1.f / 256.f);
        float var = ss * (1.f / 256.f) - mu * mu;
        mus[tid] = mu;
        rstds[tid] = rsqrtf(var + 1e-5f);
    }
    __syncthreads();

    int c = tid;
    float g = gamma[c], be = beta[c];
    int hp = h / PS, r = h - hp * PS;
    #pragma unroll
    for (int wl = 0; wl < 16; ++wl) {
        int w = w0 + wl;
        int wp = w / PS, cc = w - wp * PS;
        int win = (b * 16 + hp) * 16 + wp;
        int i = r * PS + cc;
        float v = (X[c][wl] - mus[wl]) * rstds[wl] * g + be;
        patches[((size_t)win * NWIN_N + i) * CH + c] = __float2bfloat16(v);
    }
}

// ---------------------------------------------------------------------------
// 2) shortcut: fp32 -> fp32 copy (float4)
// ---------------------------------------------------------------------------
__global__ __launch_bounds__(256) void copy_f32_kernel(
    const float* __restrict__ x, float* __restrict__ out)
{
    size_t i = ((size_t)blockIdx.x * 256 + threadIdx.x) * 4;
    *(float4*)(out + i) = *(const float4*)(x + i);
}

// ---------------------------------------------------------------------------
// prep: W fp32 [Kreal][N] -> Wt bf16 [Npad][Kpad] k-major, zero padded
// ---------------------------------------------------------------------------
__global__ __launch_bounds__(256) void prep_wt_kernel(
    const float* __restrict__ W, unsigned short* __restrict__ Wt,
    int Kreal, int N, int Kpad, int Npad)
{
    int idx = blockIdx.x * 256 + threadIdx.x;
    if (idx >= Npad * Kpad) return;
    int n = idx / Kpad, k = idx - n * Kpad;
    float v = (n < N && k < Kreal) ? W[(size_t)k * N + n] : 0.f;
    Wt[idx] = bf16_bits(v);
}

// ---------------------------------------------------------------------------
// pad49: src [M][49] -> dst [M][64] zero-padded (M = 262144)
// ---------------------------------------------------------------------------
__global__ __launch_bounds__(256) void pad49_kernel(
    const unsigned short* __restrict__ src, unsigned short* __restrict__ dst)
{
    size_t idx = (size_t)blockIdx.x * 256 + threadIdx.x;   // < 262144*64
    int t = idx & 63;
    size_t m = idx >> 6;
    dst[idx] = (t < 49) ? src[m * 49 + t] : (unsigned short)0;
}

// ---------------------------------------------------------------------------
// Unified MFMA GEMM: C[M][N] = concat(A1[.][K1], A2[.][K-K1]) @ Wt^T + bias
// A row-major bf16 (row strides K1 / K-K1, 16B-aligned); Wt bf16 [Npad][K]
// k-major. BM=128, BN=64, BK=64; 256 thr = 4 waves (2x2); 16x16x32 MFMA.
// Output: Cb bf16 stride N (guarded), OR Cf fp32 with fused BCHW permute.
// LDS rows padded to 72 (144B stride -> 2-way bank aliasing = free).
// ---------------------------------------------------------------------------
__global__ __launch_bounds__(256) void gemm_mfma_kernel(
    const __hip_bfloat16* __restrict__ A1p, const __hip_bfloat16* __restrict__ A2p,
    int K1, const unsigned short* __restrict__ Wt, const float* __restrict__ bias,
    __hip_bfloat16* __restrict__ Cb, float* __restrict__ Cf,
    int M, int N, int K)
{
    __shared__ __align__(16) unsigned short Alds[128][72];
    __shared__ __align__(16) unsigned short Wlds[64][72];
    const unsigned short* A1 = (const unsigned short*)A1p;
    const unsigned short* A2 = (const unsigned short*)A2p;
    const int m0 = blockIdx.y * 128, n0 = blockIdx.x * 64;
    const int tid = threadIdx.x, lane = tid & 63, wave = tid >> 6;
    const int wm = wave >> 1, wn = wave & 1;
    const int lr = lane & 15, lk = lane >> 4;

    f32x4 acc[4][2];
    #pragma unroll
    for (int i = 0; i < 4; ++i)
        #pragma unroll
        for (int j = 0; j < 2; ++j) acc[i][j] = (f32x4){0.f, 0.f, 0.f, 0.f};

    for (int k0 = 0; k0 < K; k0 += 64) {
        #pragma unroll
        for (int i = 0; i < 4; ++i) {
            int s = tid + 256 * i;
            int row = s >> 3, c8 = (s & 7) * 8;
            int k = k0 + c8;
            const unsigned short* src = (k < K1)
                ? A1 + (size_t)(m0 + row) * K1 + k
                : A2 + (size_t)(m0 + row) * (K - K1) + (k - K1);
            *(short8*)&Alds[row][c8] = *(const short8*)src;
        }
        #pragma unroll
        for (int i = 0; i < 2; ++i) {
            int s = tid + 256 * i;
            int row = s >> 3, c8 = (s & 7) * 8;
            *(short8*)&Wlds[row][c8] =
                *(const short8*)(Wt + (size_t)(n0 + row) * K + k0 + c8);
        }
        __syncthreads();
        #pragma unroll
        for (int kk = 0; kk < 64; kk += 32) {
            short8 a[4], w[2];
            #pragma unroll
            for (int mi = 0; mi < 4; ++mi)
                a[mi] = *(const short8*)&Alds[wm * 64 + mi * 16 + lr][kk + lk * 8];
            #pragma unroll
            for (int nj = 0; nj < 2; ++nj)
                w[nj] = *(const short8*)&Wlds[wn * 32 + nj * 16 + lr][kk + lk * 8];
            #pragma unroll
            for (int mi = 0; mi < 4; ++mi)
                #pragma unroll
                for (int nj = 0; nj < 2; ++nj)
                    acc[mi][nj] = __builtin_amdgcn_mfma_f32_16x16x32_bf16(
                        a[mi], w[nj], acc[mi][nj], 0, 0, 0);
        }
        __syncthreads();
    }

    if (Cb) {
        #pragma unroll
        for (int nj = 0; nj < 2; ++nj) {
            int n = n0 + wn * 32 + nj * 16 + lr;
            if (n >= N) continue;
            float bv = bias ? bias[n] : 0.f;
            #pragma unroll
            for (int mi = 0; mi < 4; ++mi) {
                #pragma unroll
                for (int r = 0; r < 4; ++r) {
                    int m = m0 + wm * 64 + mi * 16 + lk * 4 + r;
                    ((unsigned short*)Cb)[(size_t)m * N + n] =
                        bf16_bits(acc[mi][nj][r] + bv);
                }
            }
        }
    } else {
        // fused epilogue: m=(b*256+p)*49+t -> (b,h,w); n -> ch; fp32 BCHW
        #pragma unroll
        for (int mi = 0; mi < 4; ++mi) {
            #pragma unroll
            for (int r = 0; r < 4; ++r) {
                int m = m0 + wm * 64 + mi * 16 + lk * 4 + r;
                int b = m / 12544, rem = m - b * 12544;
                int p = rem / 49, t = rem - p * 49;
                int h = (p >> 4) * 7 + t / 7, w = (p & 15) * 7 + (t % 7);
                size_t ob = ((size_t)(b * 256) * HH + h) * WW + w;
                #pragma unroll
                for (int nj = 0; nj < 2; ++nj) {
                    int ch = n0 + wn * 32 + nj * 16 + lr;
                    Cf[ob + (size_t)ch * (HH * WW)] = acc[mi][nj][r];
                }
            }
        }
    }
}

// ---------------------------------------------------------------------------
// 4) local windowed attention with relative position bias (unchanged).
// ---------------------------------------------------------------------------
__global__ __launch_bounds__(64) void local_attn_kernel(
    const __hip_bfloat16* __restrict__ qkv,   // [50176][768]
    const float* __restrict__ rpb,            // [169][8]
    __hip_bfloat16* __restrict__ outp)        // [50176][256]
{
    int win = blockIdx.x >> 3;
    int head = blockIdx.x & 7;
    int tid = threadIdx.x;
    __shared__ float ks[NWIN_N][33], vsh[NWIN_N][33];
    const size_t rowbase = (size_t)win * NWIN_N * 768;

    for (int idx = tid; idx < NWIN_N * HD; idx += 64) {
        int i = idx >> 5, dd = idx & 31;
        size_t ro = rowbase + (size_t)i * 768 + head * HD + dd;
        ks[i][dd]  = __bfloat162float(qkv[ro + 256]);
        vsh[i][dd] = __bfloat162float(qkv[ro + 512]);
    }
    __syncthreads();

    if (tid < NWIN_N) {
        int i = tid;
        float q[HD];
        #pragma unroll
        for (int dd = 0; dd < HD; ++dd)
            q[dd] = __bfloat162float(qkv[rowbase + (size_t)i * 768 + head * HD + dd]);
        int ri = i / PS, ci = i - (i / PS) * PS;
        const float scale = 0.17677669529663687f;   // 32^-0.5
        float sc[NWIN_N];
        float mx = -1e30f;
        #pragma unroll
        for (int j = 0; j < NWIN_N; ++j) {
            float s = 0.f;
            #pragma unroll
            for (int dd = 0; dd < HD; ++dd) s += q[dd] * ks[j][dd];
            int rj = j / PS, cj = j - (j / PS) * PS;
            s = s * scale + rpb[((ri - rj + 6) * 13 + (ci - cj + 6)) * NHEAD + head];
            sc[j] = s;
            mx = fmaxf(mx, s);
        }
        float l = 0.f;
        #pragma unroll
        for (int j = 0; j < NWIN_N; ++j) { sc[j] = __expf(sc[j] - mx); l += sc[j]; }
        float inv = 1.f / l;
        float o[HD];
        #pragma unroll
        for (int dd = 0; dd < HD; ++dd) o[dd] = 0.f;
        #pragma unroll
        for (int j = 0; j < NWIN_N; ++j) {
            float pw = sc[j];
            #pragma unroll
            for (int dd = 0; dd < HD; ++dd) o[dd] += pw * vsh[j][dd];
        }
        size_t ob = ((size_t)win * NWIN_N + i) * CH + head * HD;
        #pragma unroll
        for (int dd = 0; dd < HD; ++dd) outp[ob + dd] = __float2bfloat16(o[dd] * inv);
    }
}

// ---------------------------------------------------------------------------
// 5) cross-channel attention, MFMA flash version. Output stride now 64
// (cols 49..63 become zeros automatically: V^T pad rows are zeroed).
// ---------------------------------------------------------------------------
__global__ __launch_bounds__(256) void cross_attn_mfma_kernel(
    const __hip_bfloat16* __restrict__ qkv,   // [262144][147] q|k|v
    __hip_bfloat16* __restrict__ outp)        // [262144][64] padded
{
    __shared__ __align__(16) unsigned short K_lds[64][72];
    __shared__ __align__(16) unsigned short VT_lds[64][72];
    __shared__ __align__(16) unsigned short P_lds[256][72];

    const int bc = blockIdx.x;
    const size_t base = (size_t)bc * 256;
    const int tid  = threadIdx.x;
    const int lane = tid & 63;
    const int wave = tid >> 6;
    const int i0w  = wave * 64;
    const int lr   = lane & 15;
    const int lk   = lane >> 4;

    const unsigned short* q16 = (const unsigned short*)qkv;
    const float inv7 = 1.f / 7.f;   // 49^-0.5

    short8 qf[4][2];
    #pragma unroll
    for (int it = 0; it < 4; ++it) {
        const unsigned short* qrow = q16 + (base + i0w + it * 16 + lr) * 147;
        #pragma unroll
        for (int kst = 0; kst < 2; ++kst) {
            int k0 = lk * 8 + kst * 32;
            short8 f;
            #pragma unroll
            for (int e = 0; e < 8; ++e) {
                int k = k0 + e;
                f[e] = (short)((k < 49) ? qrow[k] : 0);
            }
            qf[it][kst] = f;
        }
    }

    float m_run[4], l_run[4];
    f32x4 acc_o[4][4];   // [dt][it]
    #pragma unroll
    for (int it = 0; it < 4; ++it) { m_run[it] = -1e30f; l_run[it] = 0.f; }
    #pragma unroll
    for (int dt = 0; dt < 4; ++dt)
        #pragma unroll
        for (int it = 0; it < 4; ++it) acc_o[dt][it] = (f32x4){0.f, 0.f, 0.f, 0.f};

    for (int jt4 = 0; jt4 < 4; ++jt4) {
        const int j0 = jt4 * 64;
        {
            int row = tid >> 2, sub = tid & 3;
            const unsigned short* krow = q16 + (base + j0 + row) * 147 + 49;
            const unsigned short* vrow = q16 + (base + j0 + row) * 147 + 98;
            #pragma unroll
            for (int c = sub * 18; c < sub * 18 + 18; ++c) {
                K_lds[row][c] = (c < 49) ? krow[c] : (unsigned short)0;
                if (c < 64) VT_lds[c][row] = (c < 49) ? vrow[c] : (unsigned short)0;
            }
        }
        __syncthreads();

        #pragma unroll
        for (int it = 0; it < 4; ++it) {
            f32x4 sacc[4];
            #pragma unroll
            for (int jt = 0; jt < 4; ++jt) sacc[jt] = (f32x4){0.f, 0.f, 0.f, 0.f};
            #pragma unroll
            for (int kst = 0; kst < 2; ++kst) {
                #pragma unroll
                for (int jt = 0; jt < 4; ++jt) {
                    short8 af = *(const short8*)&K_lds[jt * 16 + lr][lk * 8 + kst * 32];
                    sacc[jt] = __builtin_amdgcn_mfma_f32_16x16x32_bf16(
                        af, qf[it][kst], sacc[jt], 0, 0, 0);
                }
            }
            float mt = -1e30f;
            #pragma unroll
            for (int jt = 0; jt < 4; ++jt)
                #pragma unroll
                for (int r = 0; r < 4; ++r) mt = fmaxf(mt, sacc[jt][r]);
            mt = fmaxf(mt, __shfl_xor(mt, 16, 64));
            mt = fmaxf(mt, __shfl_xor(mt, 32, 64));
            float mnew = fmaxf(m_run[it], mt * inv7);
            float corr = __expf(m_run[it] - mnew);
            m_run[it] = mnew;
            l_run[it] *= corr;
            #pragma unroll
            for (int dt = 0; dt < 4; ++dt)
                #pragma unroll
                for (int r = 0; r < 4; ++r) acc_o[dt][it][r] *= corr;

            float psum = 0.f;
            int irow = i0w + it * 16 + lr;
            #pragma unroll
            for (int jt = 0; jt < 4; ++jt) {
                float p0 = __expf(sacc[jt][0] * inv7 - mnew);
                float p1 = __expf(sacc[jt][1] * inv7 - mnew);
                float p2 = __expf(sacc[jt][2] * inv7 - mnew);
                float p3 = __expf(sacc[jt][3] * inv7 - mnew);
                psum += (p0 + p1) + (p2 + p3);
                uint2 wv;
                wv.x = (unsigned)bf16_bits(p0) | ((unsigned)bf16_bits(p1) << 16);
                wv.y = (unsigned)bf16_bits(p2) | ((unsigned)bf16_bits(p3) << 16);
                *(uint2*)&P_lds[irow][jt * 16 + lk * 4] = wv;
            }
            psum += __shfl_xor(psum, 16, 64);
            psum += __shfl_xor(psum, 32, 64);
            l_run[it] += psum;
        }

        #pragma unroll
        for (int it = 0; it < 4; ++it) {
            #pragma unroll
            for (int kst = 0; kst < 2; ++kst) {
                short8 bfv = *(const short8*)&P_lds[i0w + it * 16 + lr][lk * 8 + kst * 32];
                #pragma unroll
                for (int dt = 0; dt < 4; ++dt) {
                    short8 af = *(const short8*)&VT_lds[dt * 16 + lr][lk * 8 + kst * 32];
                    acc_o[dt][it] = __builtin_amdgcn_mfma_f32_16x16x32_bf16(
                        af, bfv, acc_o[dt][it], 0, 0, 0);
                }
            }
        }
        __syncthreads();
    }

    #pragma unroll
    for (int it = 0; it < 4; ++it) {
        float inv = 1.f / l_run[it];
        unsigned short* orow = (unsigned short*)outp + (base + i0w + it * 16 + lr) * 64;
        #pragma unroll
        for (int dt = 0; dt < 4; ++dt) {
            #pragma unroll
            for (int r = 0; r < 4; ++r) {
                int d = dt * 16 + lk * 4 + r;
                orow[d] = bf16_bits(acc_o[dt][it][r] * inv);
            }
        }
    }
}

// ---------------------------------------------------------------------------
// 6) batched 2D transpose: src[b][R][Cc] -> dst[b][Cc][R]; grid (Cc/64,R/64,B)
// ---------------------------------------------------------------------------
__global__ __launch_bounds__(256) void transpose_bf16_kernel(
    const __hip_bfloat16* __restrict__ src, __hip_bfloat16* __restrict__ dst,
    int R, int Cc)
{
    __shared__ __hip_bfloat16 T[64][66];
    int b = blockIdx.z;
    int r0 = blockIdx.y * 64, c0 = blockIdx.x * 64;
    const __hip_bfloat16* s = src + (size_t)b * R * Cc;
    __hip_bfloat16* d = dst + (size_t)b * R * Cc;
    int tid = threadIdx.x;
    int lr = tid >> 6, lc = tid & 63;

    #pragma unroll
    for (int l = 0; l < 16; ++l) {
        int rr = l * 4 + lr;
        T[rr][lc] = s[(size_t)(r0 + rr) * Cc + c0 + lc];
    }
    __syncthreads();
    #pragma unroll
    for (int l = 0; l < 16; ++l) {
        int cc = l * 4 + lr;
        d[(size_t)(c0 + cc) * R + r0 + lc] = T[lc][cc];
    }
}

// ---------------------------------------------------------------------------
__global__ void ws_marker_kernel(float* __restrict__ out0)
{
    if (threadIdx.x == 0) out0[0] = 777.0f;
}

// ---------------------------------------------------------------------------
extern "C" void kernel_launch(void* const* d_in, const int* in_sizes, int n_in,
                              void* d_out, int out_size, void* d_ws, size_t ws_size,
                              hipStream_t stream)
{
    const float* x        = (const float*)d_in[0];
    const float* gamma    = (const float*)d_in[1];
    const float* beta     = (const float*)d_in[2];
    const float* qkv_l_w  = (const float*)d_in[3];
    const float* qkv_l_b  = (const float*)d_in[4];
    const float* proj_l_w = (const float*)d_in[5];
    const float* proj_l_b = (const float*)d_in[6];
    const float* rpb      = (const float*)d_in[7];
    const float* qkv_c_w  = (const float*)d_in[8];
    const float* qkv_c_b  = (const float*)d_in[9];
    const float* proj_c_w = (const float*)d_in[10];
    const float* proj_c_b = (const float*)d_in[11];
    const float* proj_w   = (const float*)d_in[12];

    float* out0 = (float*)d_out;
    float* out1 = out0 + ELEMS;

    copy_f32_kernel<<<(int)(ELEMS / 1024), 256, 0, stream>>>(x, out1);

    char* ws = (char*)d_ws;
    if (ws_size < 6 * SZ) {
        ws_marker_kernel<<<1, 64, 0, stream>>>(out0);
        return;
    }

    const size_t P = SZ;
    // plane/lifetime map (verified: no overlap while live):
    __hip_bfloat16* localOut  = (__hip_bfloat16*)(ws + 0 * P);          // K5 W -> K11 R
    __hip_bfloat16* patches   = (__hip_bfloat16*)(ws + 1 * P);          // K1 W -> K6a R
    __hip_bfloat16* qkv_l     = (__hip_bfloat16*)(ws + 2 * P);          // K3 W -> K4 R (3 planes)
    __hip_bfloat16* attnL     = (__hip_bfloat16*)(ws + 5 * P);          // K4 W -> K5 R
    unsigned short* wt_qkv_l  = (unsigned short*)(ws + 0 * P);          // K0 W -> K3 R (dead before localOut)
    char*           G         = ws + 4 * P;                             // weight gap (free after K4)
    unsigned short* wt_proj_l = (unsigned short*)(G + 0x000000);
    unsigned short* wt_qkv_c  = (unsigned short*)(G + 0x080000);
    unsigned short* wt_proj_c = (unsigned short*)(G + 0x100000);
    unsigned short* wt_final  = (unsigned short*)(G + 0x180000);
    __hip_bfloat16* pc_dense  = (__hip_bfloat16*)(ws + 2 * P);          // K6a W -> K6b R
    __hip_bfloat16* pc_pad    = (__hip_bfloat16*)(ws + 6 * P - (size_t)262144 * 64 * 2); // K6b W -> K7 R
    __hip_bfloat16* qkvc      = (__hip_bfloat16*)(ws + 1 * P);          // K7 W -> K8 R (exactly 3P)
    __hip_bfloat16* crossAttn = pc_pad;                                 // K8 W -> K9 R (pc dead)
    __hip_bfloat16* crossProj = (__hip_bfloat16*)(ws + 1 * P);          // K9 W -> K10 R
    __hip_bfloat16* crossT    = (__hip_bfloat16*)(ws + 2 * P);          // K10 W -> K11 R

    // K0) weight prep needed before K3
    prep_wt_kernel<<<768, 256, 0, stream>>>(qkv_l_w, wt_qkv_l, 256, 768, 256, 768);
    // K1) LN + window partition
    ln_partition_kernel<<<BB * HH * 7, 256, 0, stream>>>(x, gamma, beta, patches);
    // K3) qkv_local: [50176,256] @ [256,768]
    gemm_mfma_kernel<<<dim3(12, 392), 256, 0, stream>>>(
        patches, nullptr, 256, wt_qkv_l, qkv_l_b, qkv_l, nullptr, 50176, 768, 256);
    // K4) local attention
    local_attn_kernel<<<1024 * NHEAD, 64, 0, stream>>>(qkv_l, rpb, attnL);
    // K4.5) remaining weight preps (gap region free after K4)
    prep_wt_kernel<<<256, 256, 0, stream>>>(proj_l_w, wt_proj_l, 256, 256, 256, 256);
    prep_wt_kernel<<<48, 256, 0, stream>>>(qkv_c_w, wt_qkv_c, 49, 147, 64, 192);
    prep_wt_kernel<<<16, 256, 0, stream>>>(proj_c_w, wt_proj_c, 49, 49, 64, 64);
    prep_wt_kernel<<<512, 256, 0, stream>>>(proj_w, wt_final, 512, 256, 512, 256);
    // K5) proj_local: [50176,256] @ [256,256]
    gemm_mfma_kernel<<<dim3(4, 392), 256, 0, stream>>>(
        attnL, nullptr, 256, wt_proj_l, proj_l_b, localOut, nullptr, 50176, 256, 256);
    // K6a) pc_dense = per-b transpose of patches
    transpose_bf16_kernel<<<dim3(4, 196, BB), 256, 0, stream>>>(patches, pc_dense, 12544, 256);
    // K6b) zero-pad rows 49 -> 64
    pad49_kernel<<<65536, 256, 0, stream>>>(
        (const unsigned short*)pc_dense, (unsigned short*)pc_pad);
    // K7) qkv_cross: [262144,64pad] @ [64,147]
    gemm_mfma_kernel<<<dim3(3, 2048), 256, 0, stream>>>(
        pc_pad, nullptr, 64, wt_qkv_c, qkv_c_b, qkvc, nullptr, 262144, 147, 64);
    // K8) cross attention (writes [262144][64], zero-padded)
    cross_attn_mfma_kernel<<<1024, 256, 0, stream>>>(qkvc, crossAttn);
    // K9) proj_cross: [262144,64pad] @ [64,49] -> dense [262144][49]
    gemm_mfma_kernel<<<dim3(1, 2048), 256, 0, stream>>>(
        crossAttn, nullptr, 64, wt_proj_c, proj_c_b, crossProj, nullptr, 262144, 49, 64);
    // K10) crossT = per-b transpose back
    transpose_bf16_kernel<<<dim3(196, 4, BB), 256, 0, stream>>>(crossProj, crossT, 256, 12544);
    // K11) final: concat[localOut|crossT] @ proj_w -> out0 fp32 BCHW
    gemm_mfma_kernel<<<dim3(4, 392), 256, 0, stream>>>(
        localOut, crossT, 256, wt_final, nullptr, nullptr, out0, 50176, 256, 512);
}

// Round 9
// 473.433 us; speedup vs baseline: 3.5783x; 1.1136x over previous
//
#include <hip/hip_runtime.h>
#include <hip/hip_bf16.h>

// Problem geometry (fixed by the reference):
// B=4, C=256, H=W=112, ps=7, N=49, nP=256 windows/batch, NH=8, d=32.
// Inputs fp32. d_out is FP32: [out | shortcut], each (B,C,H,W).

#define PS 7
#define NWIN_N 49
#define CH 256
#define HH 112
#define WW 112
#define BB 4
#define NHEAD 8
#define HD 32

static constexpr size_t ELEMS = (size_t)BB * CH * HH * WW;      // 12,845,056
static constexpr size_t SZ    = ELEMS * 2;                      // 25,690,112 B (one bf16 plane)

typedef __attribute__((ext_vector_type(8))) short short8;
typedef __attribute__((ext_vector_type(4))) float f32x4;

static __device__ __forceinline__ unsigned short bf16_bits(float v) {
    __hip_bfloat16 h = __float2bfloat16(v);
    return *reinterpret_cast<unsigned short*>(&h);
}

// ---------------------------------------------------------------------------
// 1) LayerNorm over C + window partition -> patches[(b*256+p)*49+i][c] (bf16)
// ---------------------------------------------------------------------------
__global__ __launch_bounds__(256) void ln_partition_kernel(
    const float* __restrict__ x, const float* __restrict__ gamma,
    const float* __restrict__ beta, __hip_bfloat16* __restrict__ patches)
{
    int blk = blockIdx.x;
    int seg = blk % 7;
    int bh = blk / 7;
    int h = bh % HH, b = bh / HH;
    int w0 = seg * 16;
    int tid = threadIdx.x;

    __shared__ float X[256][17];
    __shared__ float mus[16], rstds[16];

    #pragma unroll
    for (int l = 0; l < 16; ++l) {
        int idx = l * 256 + tid;
        int c = idx >> 4, wl = idx & 15;
        X[c][wl] = x[((size_t)(b * CH + c) * HH + h) * WW + w0 + wl];
    }
    __syncthreads();

    if (tid < 16) {
        float s = 0.f, ss = 0.f;
        for (int c = 0; c < 256; ++c) { float v = X[c][tid]; s += v; ss += v * v; }
        float mu = s * (1.f / 256.f);
        float var = ss * (1.f / 256.f) - mu * mu;
        mus[tid] = mu;
        rstds[tid] = rsqrtf(var + 1e-5f);
    }
    __syncthreads();

    int c = tid;
    float g = gamma[c], be = beta[c];
    int hp = h / PS, r = h - hp * PS;
    #pragma unroll
    for (int wl = 0; wl < 16; ++wl) {
        int w = w0 + wl;
        int wp = w / PS, cc = w - wp * PS;
        int win = (b * 16 + hp) * 16 + wp;
        int i = r * PS + cc;
        float v = (X[c][wl] - mus[wl]) * rstds[wl] * g + be;
        patches[((size_t)win * NWIN_N + i) * CH + c] = __float2bfloat16(v);
    }
}

// ---------------------------------------------------------------------------
// 2) shortcut: fp32 -> fp32 copy (float4)
// ---------------------------------------------------------------------------
__global__ __launch_bounds__(256) void copy_f32_kernel(
    const float* __restrict__ x, float* __restrict__ out)
{
    size_t i = ((size_t)blockIdx.x * 256 + threadIdx.x) * 4;
    *(float4*)(out + i) = *(const float4*)(x + i);
}

// ---------------------------------------------------------------------------
// prep: W fp32 [Kreal][N] -> Wt bf16 [Npad][Kpad] k-major, zero padded
// ---------------------------------------------------------------------------
__global__ __launch_bounds__(256) void prep_wt_kernel(
    const float* __restrict__ W, unsigned short* __restrict__ Wt,
    int Kreal, int N, int Kpad, int Npad)
{
    int idx = blockIdx.x * 256 + threadIdx.x;
    if (idx >= Npad * Kpad) return;
    int n = idx / Kpad, k = idx - n * Kpad;
    float v = (n < N && k < Kreal) ? W[(size_t)k * N + n] : 0.f;
    Wt[idx] = bf16_bits(v);
}

// ---------------------------------------------------------------------------
// bias prep: rpb [169][8] -> biasb[8][64][64] fp32 padded.
// j>=49: -1e9 (softmax mask for padded keys); i>=49: 0 (rows unused).
// ---------------------------------------------------------------------------
__global__ __launch_bounds__(256) void bias_prep_kernel(
    const float* __restrict__ rpb, float* __restrict__ biasb)
{
    int idx = blockIdx.x * 256 + threadIdx.x;   // < 32768
    int head = idx >> 12;
    int rem = idx & 4095;
    int i = rem >> 6, j = rem & 63;
    float v;
    if (j >= NWIN_N) v = -1e9f;
    else if (i >= NWIN_N) v = 0.f;
    else {
        int ri = i / 7, ci = i - ri * 7;
        int rj = j / 7, cj = j - rj * 7;
        v = rpb[((ri - rj + 6) * 13 + (ci - cj + 6)) * NHEAD + head];
    }
    biasb[idx] = v;
}

// ---------------------------------------------------------------------------
// pad49: src [M][49] -> dst [M][64] zero-padded (M = 262144)
// ---------------------------------------------------------------------------
__global__ __launch_bounds__(256) void pad49_kernel(
    const unsigned short* __restrict__ src, unsigned short* __restrict__ dst)
{
    size_t idx = (size_t)blockIdx.x * 256 + threadIdx.x;   // < 262144*64
    int t = idx & 63;
    size_t m = idx >> 6;
    dst[idx] = (t < 49) ? src[m * 49 + t] : (unsigned short)0;
}

// ---------------------------------------------------------------------------
// Unified MFMA GEMM: C[M][N] = concat(A1[.][K1], A2[.][K-K1]) @ Wt^T + bias
// BM=128, BN=64, BK=64; 256 thr = 4 waves (2x2); 16x16x32 MFMA.
// ---------------------------------------------------------------------------
__global__ __launch_bounds__(256) void gemm_mfma_kernel(
    const __hip_bfloat16* __restrict__ A1p, const __hip_bfloat16* __restrict__ A2p,
    int K1, const unsigned short* __restrict__ Wt, const float* __restrict__ bias,
    __hip_bfloat16* __restrict__ Cb, float* __restrict__ Cf,
    int M, int N, int K)
{
    __shared__ __align__(16) unsigned short Alds[128][72];
    __shared__ __align__(16) unsigned short Wlds[64][72];
    const unsigned short* A1 = (const unsigned short*)A1p;
    const unsigned short* A2 = (const unsigned short*)A2p;
    const int m0 = blockIdx.y * 128, n0 = blockIdx.x * 64;
    const int tid = threadIdx.x, lane = tid & 63, wave = tid >> 6;
    const int wm = wave >> 1, wn = wave & 1;
    const int lr = lane & 15, lk = lane >> 4;

    f32x4 acc[4][2];
    #pragma unroll
    for (int i = 0; i < 4; ++i)
        #pragma unroll
        for (int j = 0; j < 2; ++j) acc[i][j] = (f32x4){0.f, 0.f, 0.f, 0.f};

    for (int k0 = 0; k0 < K; k0 += 64) {
        #pragma unroll
        for (int i = 0; i < 4; ++i) {
            int s = tid + 256 * i;
            int row = s >> 3, c8 = (s & 7) * 8;
            int k = k0 + c8;
            const unsigned short* src = (k < K1)
                ? A1 + (size_t)(m0 + row) * K1 + k
                : A2 + (size_t)(m0 + row) * (K - K1) + (k - K1);
            *(short8*)&Alds[row][c8] = *(const short8*)src;
        }
        #pragma unroll
        for (int i = 0; i < 2; ++i) {
            int s = tid + 256 * i;
            int row = s >> 3, c8 = (s & 7) * 8;
            *(short8*)&Wlds[row][c8] =
                *(const short8*)(Wt + (size_t)(n0 + row) * K + k0 + c8);
        }
        __syncthreads();
        #pragma unroll
        for (int kk = 0; kk < 64; kk += 32) {
            short8 a[4], w[2];
            #pragma unroll
            for (int mi = 0; mi < 4; ++mi)
                a[mi] = *(const short8*)&Alds[wm * 64 + mi * 16 + lr][kk + lk * 8];
            #pragma unroll
            for (int nj = 0; nj < 2; ++nj)
                w[nj] = *(const short8*)&Wlds[wn * 32 + nj * 16 + lr][kk + lk * 8];
            #pragma unroll
            for (int mi = 0; mi < 4; ++mi)
                #pragma unroll
                for (int nj = 0; nj < 2; ++nj)
                    acc[mi][nj] = __builtin_amdgcn_mfma_f32_16x16x32_bf16(
                        a[mi], w[nj], acc[mi][nj], 0, 0, 0);
        }
        __syncthreads();
    }

    if (Cb) {
        #pragma unroll
        for (int nj = 0; nj < 2; ++nj) {
            int n = n0 + wn * 32 + nj * 16 + lr;
            if (n >= N) continue;
            float bv = bias ? bias[n] : 0.f;
            #pragma unroll
            for (int mi = 0; mi < 4; ++mi) {
                #pragma unroll
                for (int r = 0; r < 4; ++r) {
                    int m = m0 + wm * 64 + mi * 16 + lk * 4 + r;
                    ((unsigned short*)Cb)[(size_t)m * N + n] =
                        bf16_bits(acc[mi][nj][r] + bv);
                }
            }
        }
    } else {
        #pragma unroll
        for (int mi = 0; mi < 4; ++mi) {
            #pragma unroll
            for (int r = 0; r < 4; ++r) {
                int m = m0 + wm * 64 + mi * 16 + lk * 4 + r;
                int b = m / 12544, rem = m - b * 12544;
                int p = rem / 49, t = rem - p * 49;
                int h = (p >> 4) * 7 + t / 7, w = (p & 15) * 7 + (t % 7);
                size_t ob = ((size_t)(b * 256) * HH + h) * WW + w;
                #pragma unroll
                for (int nj = 0; nj < 2; ++nj) {
                    int ch = n0 + wn * 32 + nj * 16 + lr;
                    Cf[ob + (size_t)ch * (HH * WW)] = acc[mi][nj][r];
                }
            }
        }
    }
}

// ---------------------------------------------------------------------------
// 4) local windowed attention, MFMA. One wave per (win, head), grid 8192x64.
// S^T = mfma(A=K, B=Q), d=32 = single K-step; K/Q frags direct from global
// (16B aligned). K rows j>=49 zeroed in-register; bias table masks j>=49
// with -1e9. Softmax single-shot per i (all 64 j in regs). PV via 16-row
// P_lds round-trip; O^T = mfma(A=V^T, B=P).
// ---------------------------------------------------------------------------
__global__ __launch_bounds__(64) void local_attn_mfma_kernel(
    const __hip_bfloat16* __restrict__ qkv,   // [50176][768] q|k|v
    const float* __restrict__ biasb,          // [8][64][64] fp32 padded
    __hip_bfloat16* __restrict__ outp)        // [50176][256]
{
    __shared__ __align__(16) unsigned short VT_lds[32][72];
    __shared__ __align__(16) unsigned short P_lds[16][72];

    const int win  = blockIdx.x >> 3;
    const int head = blockIdx.x & 7;
    const int lane = threadIdx.x;
    const int lr = lane & 15, lk = lane >> 4;
    const unsigned short* q16 = (const unsigned short*)qkv;
    const size_t rowbase = (size_t)win * NWIN_N;
    const float scale = 0.17677669529663687f;   // 32^-0.5

    // stage V^T (VT[d][j], j>=49 zeroed); lanes: d = lane&31, j advances by 2
    for (int t = 0; t < 32; ++t) {
        int idx = lane + 64 * t;
        int j = idx >> 5, d = idx & 31;
        unsigned short v = 0;
        if (j < NWIN_N) v = q16[(rowbase + j) * 768 + 512 + head * HD + d];
        VT_lds[d][j] = v;
    }

    // K and Q fragments direct from global
    short8 kf[4], qf[4];
    #pragma unroll
    for (int jt = 0; jt < 4; ++jt) {
        int j = jt * 16 + lr;
        short8 f = *(const short8*)(q16 + (rowbase + j) * 768 + 256 + head * HD + lk * 8);
        if (j >= NWIN_N) {
            #pragma unroll
            for (int e = 0; e < 8; ++e) f[e] = 0;
        }
        kf[jt] = f;
    }
    #pragma unroll
    for (int it = 0; it < 4; ++it) {
        int i = it * 16 + lr;
        qf[it] = *(const short8*)(q16 + (rowbase + i) * 768 + head * HD + lk * 8);
    }
    __syncthreads();

    #pragma unroll
    for (int it = 0; it < 4; ++it) {
        const int i = it * 16 + lr;
        // S^T tiles: value at (col i, row j = jt*16 + lk*4 + r)
        f32x4 sacc[4];
        #pragma unroll
        for (int jt = 0; jt < 4; ++jt) {
            f32x4 z = (f32x4){0.f, 0.f, 0.f, 0.f};
            sacc[jt] = __builtin_amdgcn_mfma_f32_16x16x32_bf16(kf[jt], qf[it], z, 0, 0, 0);
        }
        // scale + bias, row max (across lk groups via shfl)
        const float* brow = biasb + head * 4096 + i * 64;
        float sv[4][4];
        float mt = -1e30f;
        #pragma unroll
        for (int jt = 0; jt < 4; ++jt) {
            float4 bv = *(const float4*)&brow[jt * 16 + lk * 4];
            sv[jt][0] = sacc[jt][0] * scale + bv.x;
            sv[jt][1] = sacc[jt][1] * scale + bv.y;
            sv[jt][2] = sacc[jt][2] * scale + bv.z;
            sv[jt][3] = sacc[jt][3] * scale + bv.w;
            #pragma unroll
            for (int r = 0; r < 4; ++r) mt = fmaxf(mt, sv[jt][r]);
        }
        mt = fmaxf(mt, __shfl_xor(mt, 16, 64));
        mt = fmaxf(mt, __shfl_xor(mt, 32, 64));
        // exp, sum, pack P
        float psum = 0.f;
        #pragma unroll
        for (int jt = 0; jt < 4; ++jt) {
            float p0 = __expf(sv[jt][0] - mt);
            float p1 = __expf(sv[jt][1] - mt);
            float p2 = __expf(sv[jt][2] - mt);
            float p3 = __expf(sv[jt][3] - mt);
            psum += (p0 + p1) + (p2 + p3);
            uint2 wv;
            wv.x = (unsigned)bf16_bits(p0) | ((unsigned)bf16_bits(p1) << 16);
            wv.y = (unsigned)bf16_bits(p2) | ((unsigned)bf16_bits(p3) << 16);
            *(uint2*)&P_lds[lr][jt * 16 + lk * 4] = wv;
        }
        psum += __shfl_xor(psum, 16, 64);
        psum += __shfl_xor(psum, 32, 64);
        __syncthreads();

        // PV: O^T for this i-tile (col i, row d = dt*16 + lk*4 + r)
        f32x4 oacc[2];
        oacc[0] = (f32x4){0.f, 0.f, 0.f, 0.f};
        oacc[1] = (f32x4){0.f, 0.f, 0.f, 0.f};
        #pragma unroll
        for (int kst = 0; kst < 2; ++kst) {
            short8 bfv = *(const short8*)&P_lds[lr][kst * 32 + lk * 8];
            #pragma unroll
            for (int dt = 0; dt < 2; ++dt) {
                short8 af = *(const short8*)&VT_lds[dt * 16 + lr][kst * 32 + lk * 8];
                oacc[dt] = __builtin_amdgcn_mfma_f32_16x16x32_bf16(af, bfv, oacc[dt], 0, 0, 0);
            }
        }
        if (i < NWIN_N) {
            float inv = 1.f / psum;
            unsigned short* orow = (unsigned short*)outp + (rowbase + i) * CH + head * HD;
            #pragma unroll
            for (int dt = 0; dt < 2; ++dt) {
                uint2 wv;
                wv.x = (unsigned)bf16_bits(oacc[dt][0] * inv)
                     | ((unsigned)bf16_bits(oacc[dt][1] * inv) << 16);
                wv.y = (unsigned)bf16_bits(oacc[dt][2] * inv)
                     | ((unsigned)bf16_bits(oacc[dt][3] * inv) << 16);
                *(uint2*)&orow[dt * 16 + lk * 4] = wv;
            }
        }
        __syncthreads();   // P_lds rows reused next it
    }
}

// ---------------------------------------------------------------------------
// 5) cross-channel attention, MFMA flash (output stride 64, zero-padded).
// ---------------------------------------------------------------------------
__global__ __launch_bounds__(256) void cross_attn_mfma_kernel(
    const __hip_bfloat16* __restrict__ qkv,   // [262144][147] q|k|v
    __hip_bfloat16* __restrict__ outp)        // [262144][64] padded
{
    __shared__ __align__(16) unsigned short K_lds[64][72];
    __shared__ __align__(16) unsigned short VT_lds[64][72];
    __shared__ __align__(16) unsigned short P_lds[256][72];

    const int bc = blockIdx.x;
    const size_t base = (size_t)bc * 256;
    const int tid  = threadIdx.x;
    const int lane = tid & 63;
    const int wave = tid >> 6;
    const int i0w  = wave * 64;
    const int lr   = lane & 15;
    const int lk   = lane >> 4;

    const unsigned short* q16 = (const unsigned short*)qkv;
    const float inv7 = 1.f / 7.f;   // 49^-0.5

    short8 qf[4][2];
    #pragma unroll
    for (int it = 0; it < 4; ++it) {
        const unsigned short* qrow = q16 + (base + i0w + it * 16 + lr) * 147;
        #pragma unroll
        for (int kst = 0; kst < 2; ++kst) {
            int k0 = lk * 8 + kst * 32;
            short8 f;
            #pragma unroll
            for (int e = 0; e < 8; ++e) {
                int k = k0 + e;
                f[e] = (short)((k < 49) ? qrow[k] : 0);
            }
            qf[it][kst] = f;
        }
    }

    float m_run[4], l_run[4];
    f32x4 acc_o[4][4];   // [dt][it]
    #pragma unroll
    for (int it = 0; it < 4; ++it) { m_run[it] = -1e30f; l_run[it] = 0.f; }
    #pragma unroll
    for (int dt = 0; dt < 4; ++dt)
        #pragma unroll
        for (int it = 0; it < 4; ++it) acc_o[dt][it] = (f32x4){0.f, 0.f, 0.f, 0.f};

    for (int jt4 = 0; jt4 < 4; ++jt4) {
        const int j0 = jt4 * 64;
        {
            int row = tid >> 2, sub = tid & 3;
            const unsigned short* krow = q16 + (base + j0 + row) * 147 + 49;
            const unsigned short* vrow = q16 + (base + j0 + row) * 147 + 98;
            #pragma unroll
            for (int c = sub * 18; c < sub * 18 + 18; ++c) {
                K_lds[row][c] = (c < 49) ? krow[c] : (unsigned short)0;
                if (c < 64) VT_lds[c][row] = (c < 49) ? vrow[c] : (unsigned short)0;
            }
        }
        __syncthreads();

        #pragma unroll
        for (int it = 0; it < 4; ++it) {
            f32x4 sacc[4];
            #pragma unroll
            for (int jt = 0; jt < 4; ++jt) sacc[jt] = (f32x4){0.f, 0.f, 0.f, 0.f};
            #pragma unroll
            for (int kst = 0; kst < 2; ++kst) {
                #pragma unroll
                for (int jt = 0; jt < 4; ++jt) {
                    short8 af = *(const short8*)&K_lds[jt * 16 + lr][lk * 8 + kst * 32];
                    sacc[jt] = __builtin_amdgcn_mfma_f32_16x16x32_bf16(
                        af, qf[it][kst], sacc[jt], 0, 0, 0);
                }
            }
            float mt = -1e30f;
            #pragma unroll
            for (int jt = 0; jt < 4; ++jt)
                #pragma unroll
                for (int r = 0; r < 4; ++r) mt = fmaxf(mt, sacc[jt][r]);
            mt = fmaxf(mt, __shfl_xor(mt, 16, 64));
            mt = fmaxf(mt, __shfl_xor(mt, 32, 64));
            float mnew = fmaxf(m_run[it], mt * inv7);
            float corr = __expf(m_run[it] - mnew);
            m_run[it] = mnew;
            l_run[it] *= corr;
            #pragma unroll
            for (int dt = 0; dt < 4; ++dt)
                #pragma unroll
                for (int r = 0; r < 4; ++r) acc_o[dt][it][r] *= corr;

            float psum = 0.f;
            int irow = i0w + it * 16 + lr;
            #pragma unroll
            for (int jt = 0; jt < 4; ++jt) {
                float p0 = __expf(sacc[jt][0] * inv7 - mnew);
                float p1 = __expf(sacc[jt][1] * inv7 - mnew);
                float p2 = __expf(sacc[jt][2] * inv7 - mnew);
                float p3 = __expf(sacc[jt][3] * inv7 - mnew);
                psum += (p0 + p1) + (p2 + p3);
                uint2 wv;
                wv.x = (unsigned)bf16_bits(p0) | ((unsigned)bf16_bits(p1) << 16);
                wv.y = (unsigned)bf16_bits(p2) | ((unsigned)bf16_bits(p3) << 16);
                *(uint2*)&P_lds[irow][jt * 16 + lk * 4] = wv;
            }
            psum += __shfl_xor(psum, 16, 64);
            psum += __shfl_xor(psum, 32, 64);
            l_run[it] += psum;
        }

        #pragma unroll
        for (int it = 0; it < 4; ++it) {
            #pragma unroll
            for (int kst = 0; kst < 2; ++kst) {
                short8 bfv = *(const short8*)&P_lds[i0w + it * 16 + lr][lk * 8 + kst * 32];
                #pragma unroll
                for (int dt = 0; dt < 4; ++dt) {
                    short8 af = *(const short8*)&VT_lds[dt * 16 + lr][lk * 8 + kst * 32];
                    acc_o[dt][it] = __builtin_amdgcn_mfma_f32_16x16x32_bf16(
                        af, bfv, acc_o[dt][it], 0, 0, 0);
                }
            }
        }
        __syncthreads();
    }

    #pragma unroll
    for (int it = 0; it < 4; ++it) {
        float inv = 1.f / l_run[it];
        unsigned short* orow = (unsigned short*)outp + (base + i0w + it * 16 + lr) * 64;
        #pragma unroll
        for (int dt = 0; dt < 4; ++dt) {
            #pragma unroll
            for (int r = 0; r < 4; ++r) {
                int d = dt * 16 + lk * 4 + r;
                orow[d] = bf16_bits(acc_o[dt][it][r] * inv);
            }
        }
    }
}

// ---------------------------------------------------------------------------
// 6) batched 2D transpose: src[b][R][Cc] -> dst[b][Cc][R]; grid (Cc/64,R/64,B)
// ---------------------------------------------------------------------------
__global__ __launch_bounds__(256) void transpose_bf16_kernel(
    const __hip_bfloat16* __restrict__ src, __hip_bfloat16* __restrict__ dst,
    int R, int Cc)
{
    __shared__ __hip_bfloat16 T[64][66];
    int b = blockIdx.z;
    int r0 = blockIdx.y * 64, c0 = blockIdx.x * 64;
    const __hip_bfloat16* s = src + (size_t)b * R * Cc;
    __hip_bfloat16* d = dst + (size_t)b * R * Cc;
    int tid = threadIdx.x;
    int lr = tid >> 6, lc = tid & 63;

    #pragma unroll
    for (int l = 0; l < 16; ++l) {
        int rr = l * 4 + lr;
        T[rr][lc] = s[(size_t)(r0 + rr) * Cc + c0 + lc];
    }
    __syncthreads();
    #pragma unroll
    for (int l = 0; l < 16; ++l) {
        int cc = l * 4 + lr;
        d[(size_t)(c0 + cc) * R + r0 + lc] = T[lc][cc];
    }
}

// ---------------------------------------------------------------------------
__global__ void ws_marker_kernel(float* __restrict__ out0)
{
    if (threadIdx.x == 0) out0[0] = 777.0f;
}

// ---------------------------------------------------------------------------
extern "C" void kernel_launch(void* const* d_in, const int* in_sizes, int n_in,
                              void* d_out, int out_size, void* d_ws, size_t ws_size,
                              hipStream_t stream)
{
    const float* x        = (const float*)d_in[0];
    const float* gamma    = (const float*)d_in[1];
    const float* beta     = (const float*)d_in[2];
    const float* qkv_l_w  = (const float*)d_in[3];
    const float* qkv_l_b  = (const float*)d_in[4];
    const float* proj_l_w = (const float*)d_in[5];
    const float* proj_l_b = (const float*)d_in[6];
    const float* rpb      = (const float*)d_in[7];
    const float* qkv_c_w  = (const float*)d_in[8];
    const float* qkv_c_b  = (const float*)d_in[9];
    const float* proj_c_w = (const float*)d_in[10];
    const float* proj_c_b = (const float*)d_in[11];
    const float* proj_w   = (const float*)d_in[12];

    float* out0 = (float*)d_out;
    float* out1 = out0 + ELEMS;

    copy_f32_kernel<<<(int)(ELEMS / 1024), 256, 0, stream>>>(x, out1);

    char* ws = (char*)d_ws;
    if (ws_size < 6 * SZ) {
        ws_marker_kernel<<<1, 64, 0, stream>>>(out0);
        return;
    }

    const size_t P = SZ;
    // plane/lifetime map (verified: no overlap while live):
    __hip_bfloat16* localOut  = (__hip_bfloat16*)(ws + 0 * P);          // K5 W -> K11 R
    __hip_bfloat16* patches   = (__hip_bfloat16*)(ws + 1 * P);          // K1 W -> K6a R
    __hip_bfloat16* qkv_l     = (__hip_bfloat16*)(ws + 2 * P);          // K3 W -> K4 R (3 planes)
    __hip_bfloat16* attnL     = (__hip_bfloat16*)(ws + 5 * P);          // K4 W -> K5 R
    unsigned short* wt_qkv_l  = (unsigned short*)(ws + 0 * P);          // K0 W -> K3 R (plane0, 393KB)
    float*          biasb     = (float*)(ws + 0 * P + 0x80000);         // K0b W -> K4 R (plane0, 131KB)
    char*           G         = ws + 4 * P;                             // weight gap (free after K4)
    unsigned short* wt_proj_l = (unsigned short*)(G + 0x000000);
    unsigned short* wt_qkv_c  = (unsigned short*)(G + 0x080000);
    unsigned short* wt_proj_c = (unsigned short*)(G + 0x100000);
    unsigned short* wt_final  = (unsigned short*)(G + 0x180000);
    __hip_bfloat16* pc_dense  = (__hip_bfloat16*)(ws + 2 * P);          // K6a W -> K6b R
    __hip_bfloat16* pc_pad    = (__hip_bfloat16*)(ws + 6 * P - (size_t)262144 * 64 * 2); // K6b W -> K7 R
    __hip_bfloat16* qkvc      = (__hip_bfloat16*)(ws + 1 * P);          // K7 W -> K8 R (exactly 3P)
    __hip_bfloat16* crossAttn = pc_pad;                                 // K8 W -> K9 R
    __hip_bfloat16* crossProj = (__hip_bfloat16*)(ws + 1 * P);          // K9 W -> K10 R
    __hip_bfloat16* crossT    = (__hip_bfloat16*)(ws + 2 * P);          // K10 W -> K11 R

    // K0) weight prep needed before K3; bias table before K4
    prep_wt_kernel<<<768, 256, 0, stream>>>(qkv_l_w, wt_qkv_l, 256, 768, 256, 768);
    bias_prep_kernel<<<128, 256, 0, stream>>>(rpb, biasb);
    // K1) LN + window partition
    ln_partition_kernel<<<BB * HH * 7, 256, 0, stream>>>(x, gamma, beta, patches);
    // K3) qkv_local: [50176,256] @ [256,768]
    gemm_mfma_kernel<<<dim3(12, 392), 256, 0, stream>>>(
        patches, nullptr, 256, wt_qkv_l, qkv_l_b, qkv_l, nullptr, 50176, 768, 256);
    // K4) local attention (MFMA)
    local_attn_mfma_kernel<<<1024 * NHEAD, 64, 0, stream>>>(qkv_l, biasb, attnL);
    // K4.5) remaining weight preps (gap free after K4)
    prep_wt_kernel<<<256, 256, 0, stream>>>(proj_l_w, wt_proj_l, 256, 256, 256, 256);
    prep_wt_kernel<<<48, 256, 0, stream>>>(qkv_c_w, wt_qkv_c, 49, 147, 64, 192);
    prep_wt_kernel<<<16, 256, 0, stream>>>(proj_c_w, wt_proj_c, 49, 49, 64, 64);
    prep_wt_kernel<<<512, 256, 0, stream>>>(proj_w, wt_final, 512, 256, 512, 256);
    // K5) proj_local: [50176,256] @ [256,256]
    gemm_mfma_kernel<<<dim3(4, 392), 256, 0, stream>>>(
        attnL, nullptr, 256, wt_proj_l, proj_l_b, localOut, nullptr, 50176, 256, 256);
    // K6a) pc_dense = per-b transpose of patches
    transpose_bf16_kernel<<<dim3(4, 196, BB), 256, 0, stream>>>(patches, pc_dense, 12544, 256);
    // K6b) zero-pad rows 49 -> 64
    pad49_kernel<<<65536, 256, 0, stream>>>(
        (const unsigned short*)pc_dense, (unsigned short*)pc_pad);
    // K7) qkv_cross: [262144,64pad] @ [64,147]
    gemm_mfma_kernel<<<dim3(3, 2048), 256, 0, stream>>>(
        pc_pad, nullptr, 64, wt_qkv_c, qkv_c_b, qkvc, nullptr, 262144, 147, 64);
    // K8) cross attention
    cross_attn_mfma_kernel<<<1024, 256, 0, stream>>>(qkvc, crossAttn);
    // K9) proj_cross: [262144,64pad] @ [64,49]
    gemm_mfma_kernel<<<dim3(1, 2048), 256, 0, stream>>>(
        crossAttn, nullptr, 64, wt_proj_c, proj_c_b, crossProj, nullptr, 262144, 49, 64);
    // K10) crossT = per-b transpose back
    transpose_bf16_kernel<<<dim3(196, 4, BB), 256, 0, stream>>>(crossProj, crossT, 256, 12544);
    // K11) final: concat[localOut|crossT] @ proj_w -> out0 fp32 BCHW
    gemm_mfma_kernel<<<dim3(4, 392), 256, 0, stream>>>(
        localOut, crossT, 256, wt_final, nullptr, nullptr, out0, 50176, 256, 512);
}

// Round 10
// 452.568 us; speedup vs baseline: 3.7432x; 1.0461x over previous
//
#include <hip/hip_runtime.h>
#include <hip/hip_bf16.h>

// Problem geometry (fixed by the reference):
// B=4, C=256, H=W=112, ps=7, N=49, nP=256 windows/batch, NH=8, d=32.
// Inputs fp32. d_out is FP32: [out | shortcut], each (B,C,H,W).

#define PS 7
#define NWIN_N 49
#define CH 256
#define HH 112
#define WW 112
#define BB 4
#define NHEAD 8
#define HD 32

static constexpr size_t ELEMS = (size_t)BB * CH * HH * WW;      // 12,845,056
static constexpr size_t SZ    = ELEMS * 2;                      // 25,690,112 B (one bf16 plane)

typedef __attribute__((ext_vector_type(8))) short short8;
typedef __attribute__((ext_vector_type(4))) float f32x4;

static __device__ __forceinline__ unsigned short bf16_bits(float v) {
    __hip_bfloat16 h = __float2bfloat16(v);
    return *reinterpret_cast<unsigned short*>(&h);
}

// ---------------------------------------------------------------------------
// 1) LayerNorm over C + window partition -> patches[(b*256+p)*49+i][c] (bf16)
// ---------------------------------------------------------------------------
__global__ __launch_bounds__(256) void ln_partition_kernel(
    const float* __restrict__ x, const float* __restrict__ gamma,
    const float* __restrict__ beta, __hip_bfloat16* __restrict__ patches)
{
    int blk = blockIdx.x;
    int seg = blk % 7;
    int bh = blk / 7;
    int h = bh % HH, b = bh / HH;
    int w0 = seg * 16;
    int tid = threadIdx.x;

    __shared__ float X[256][17];
    __shared__ float mus[16], rstds[16];

    #pragma unroll
    for (int l = 0; l < 16; ++l) {
        int idx = l * 256 + tid;
        int c = idx >> 4, wl = idx & 15;
        X[c][wl] = x[((size_t)(b * CH + c) * HH + h) * WW + w0 + wl];
    }
    __syncthreads();

    if (tid < 16) {
        float s = 0.f, ss = 0.f;
        for (int c = 0; c < 256; ++c) { float v = X[c][tid]; s += v; ss += v * v; }
        float mu = s * (1.f / 256.f);
        float var = ss * (1.f / 256.f) - mu * mu;
        mus[tid] = mu;
        rstds[tid] = rsqrtf(var + 1e-5f);
    }
    __syncthreads();

    int c = tid;
    float g = gamma[c], be = beta[c];
    int hp = h / PS, r = h - hp * PS;
    #pragma unroll
    for (int wl = 0; wl < 16; ++wl) {
        int w = w0 + wl;
        int wp = w / PS, cc = w - wp * PS;
        int win = (b * 16 + hp) * 16 + wp;
        int i = r * PS + cc;
        float v = (X[c][wl] - mus[wl]) * rstds[wl] * g + be;
        patches[((size_t)win * NWIN_N + i) * CH + c] = __float2bfloat16(v);
    }
}

// ---------------------------------------------------------------------------
// 2) shortcut: fp32 -> fp32 copy (float4)
// ---------------------------------------------------------------------------
__global__ __launch_bounds__(256) void copy_f32_kernel(
    const float* __restrict__ x, float* __restrict__ out)
{
    size_t i = ((size_t)blockIdx.x * 256 + threadIdx.x) * 4;
    *(float4*)(out + i) = *(const float4*)(x + i);
}

// ---------------------------------------------------------------------------
// prep: W fp32 [Kreal][N] -> Wt bf16 [Npad][Kpad] k-major, zero padded
// ---------------------------------------------------------------------------
__global__ __launch_bounds__(256) void prep_wt_kernel(
    const float* __restrict__ W, unsigned short* __restrict__ Wt,
    int Kreal, int N, int Kpad, int Npad)
{
    int idx = blockIdx.x * 256 + threadIdx.x;
    if (idx >= Npad * Kpad) return;
    int n = idx / Kpad, k = idx - n * Kpad;
    float v = (n < N && k < Kreal) ? W[(size_t)k * N + n] : 0.f;
    Wt[idx] = bf16_bits(v);
}

// ---------------------------------------------------------------------------
// bias prep: rpb [169][8] -> biasb[8][64][64] fp32 padded.
// ---------------------------------------------------------------------------
__global__ __launch_bounds__(256) void bias_prep_kernel(
    const float* __restrict__ rpb, float* __restrict__ biasb)
{
    int idx = blockIdx.x * 256 + threadIdx.x;   // < 32768
    int head = idx >> 12;
    int rem = idx & 4095;
    int i = rem >> 6, j = rem & 63;
    float v;
    if (j >= NWIN_N) v = -1e9f;
    else if (i >= NWIN_N) v = 0.f;
    else {
        int ri = i / 7, ci = i - ri * 7;
        int rj = j / 7, cj = j - rj * 7;
        v = rpb[((ri - rj + 6) * 13 + (ci - cj + 6)) * NHEAD + head];
    }
    biasb[idx] = v;
}

// ---------------------------------------------------------------------------
// pad49: src [M][49] -> dst [M][64] zero-padded (M = 262144)
// ---------------------------------------------------------------------------
__global__ __launch_bounds__(256) void pad49_kernel(
    const unsigned short* __restrict__ src, unsigned short* __restrict__ dst)
{
    size_t idx = (size_t)blockIdx.x * 256 + threadIdx.x;   // < 262144*64
    int t = idx & 63;
    size_t m = idx >> 6;
    dst[idx] = (t < 49) ? src[m * 49 + t] : (unsigned short)0;
}

// ---------------------------------------------------------------------------
// Unified MFMA GEMM: C[M][N] = concat(A1[.][K1], A2[.][K-K1]) @ Wt^T + bias
// BM=128, BN=64, BK=64; 256 thr = 4 waves (2x2); 16x16x32 MFMA.
// ---------------------------------------------------------------------------
__global__ __launch_bounds__(256) void gemm_mfma_kernel(
    const __hip_bfloat16* __restrict__ A1p, const __hip_bfloat16* __restrict__ A2p,
    int K1, const unsigned short* __restrict__ Wt, const float* __restrict__ bias,
    __hip_bfloat16* __restrict__ Cb, float* __restrict__ Cf,
    int M, int N, int K)
{
    __shared__ __align__(16) unsigned short Alds[128][72];
    __shared__ __align__(16) unsigned short Wlds[64][72];
    const unsigned short* A1 = (const unsigned short*)A1p;
    const unsigned short* A2 = (const unsigned short*)A2p;
    const int m0 = blockIdx.y * 128, n0 = blockIdx.x * 64;
    const int tid = threadIdx.x, lane = tid & 63, wave = tid >> 6;
    const int wm = wave >> 1, wn = wave & 1;
    const int lr = lane & 15, lk = lane >> 4;

    f32x4 acc[4][2];
    #pragma unroll
    for (int i = 0; i < 4; ++i)
        #pragma unroll
        for (int j = 0; j < 2; ++j) acc[i][j] = (f32x4){0.f, 0.f, 0.f, 0.f};

    for (int k0 = 0; k0 < K; k0 += 64) {
        #pragma unroll
        for (int i = 0; i < 4; ++i) {
            int s = tid + 256 * i;
            int row = s >> 3, c8 = (s & 7) * 8;
            int k = k0 + c8;
            const unsigned short* src = (k < K1)
                ? A1 + (size_t)(m0 + row) * K1 + k
                : A2 + (size_t)(m0 + row) * (K - K1) + (k - K1);
            *(short8*)&Alds[row][c8] = *(const short8*)src;
        }
        #pragma unroll
        for (int i = 0; i < 2; ++i) {
            int s = tid + 256 * i;
            int row = s >> 3, c8 = (s & 7) * 8;
            *(short8*)&Wlds[row][c8] =
                *(const short8*)(Wt + (size_t)(n0 + row) * K + k0 + c8);
        }
        __syncthreads();
        #pragma unroll
        for (int kk = 0; kk < 64; kk += 32) {
            short8 a[4], w[2];
            #pragma unroll
            for (int mi = 0; mi < 4; ++mi)
                a[mi] = *(const short8*)&Alds[wm * 64 + mi * 16 + lr][kk + lk * 8];
            #pragma unroll
            for (int nj = 0; nj < 2; ++nj)
                w[nj] = *(const short8*)&Wlds[wn * 32 + nj * 16 + lr][kk + lk * 8];
            #pragma unroll
            for (int mi = 0; mi < 4; ++mi)
                #pragma unroll
                for (int nj = 0; nj < 2; ++nj)
                    acc[mi][nj] = __builtin_amdgcn_mfma_f32_16x16x32_bf16(
                        a[mi], w[nj], acc[mi][nj], 0, 0, 0);
        }
        __syncthreads();
    }

    if (Cb) {
        #pragma unroll
        for (int nj = 0; nj < 2; ++nj) {
            int n = n0 + wn * 32 + nj * 16 + lr;
            if (n >= N) continue;
            float bv = bias ? bias[n] : 0.f;
            #pragma unroll
            for (int mi = 0; mi < 4; ++mi) {
                #pragma unroll
                for (int r = 0; r < 4; ++r) {
                    int m = m0 + wm * 64 + mi * 16 + lk * 4 + r;
                    ((unsigned short*)Cb)[(size_t)m * N + n] =
                        bf16_bits(acc[mi][nj][r] + bv);
                }
            }
        }
    } else {
        #pragma unroll
        for (int mi = 0; mi < 4; ++mi) {
            #pragma unroll
            for (int r = 0; r < 4; ++r) {
                int m = m0 + wm * 64 + mi * 16 + lk * 4 + r;
                int b = m / 12544, rem = m - b * 12544;
                int p = rem / 49, t = rem - p * 49;
                int h = (p >> 4) * 7 + t / 7, w = (p & 15) * 7 + (t % 7);
                size_t ob = ((size_t)(b * 256) * HH + h) * WW + w;
                #pragma unroll
                for (int nj = 0; nj < 2; ++nj) {
                    int ch = n0 + wn * 32 + nj * 16 + lr;
                    Cf[ob + (size_t)ch * (HH * WW)] = acc[mi][nj][r];
                }
            }
        }
    }
}

// ---------------------------------------------------------------------------
// 4) local windowed attention, MFMA. One wave per (win, head).
// ---------------------------------------------------------------------------
__global__ __launch_bounds__(64) void local_attn_mfma_kernel(
    const __hip_bfloat16* __restrict__ qkv,   // [50176][768] q|k|v
    const float* __restrict__ biasb,          // [8][64][64] fp32 padded
    __hip_bfloat16* __restrict__ outp)        // [50176][256]
{
    __shared__ __align__(16) unsigned short VT_lds[32][72];
    __shared__ __align__(16) unsigned short P_lds[16][72];

    const int win  = blockIdx.x >> 3;
    const int head = blockIdx.x & 7;
    const int lane = threadIdx.x;
    const int lr = lane & 15, lk = lane >> 4;
    const unsigned short* q16 = (const unsigned short*)qkv;
    const size_t rowbase = (size_t)win * NWIN_N;
    const float scale = 0.17677669529663687f;   // 32^-0.5

    for (int t = 0; t < 32; ++t) {
        int idx = lane + 64 * t;
        int j = idx >> 5, d = idx & 31;
        unsigned short v = 0;
        if (j < NWIN_N) v = q16[(rowbase + j) * 768 + 512 + head * HD + d];
        VT_lds[d][j] = v;
    }

    short8 kf[4], qf[4];
    #pragma unroll
    for (int jt = 0; jt < 4; ++jt) {
        int j = jt * 16 + lr;
        short8 f = *(const short8*)(q16 + (rowbase + j) * 768 + 256 + head * HD + lk * 8);
        if (j >= NWIN_N) {
            #pragma unroll
            for (int e = 0; e < 8; ++e) f[e] = 0;
        }
        kf[jt] = f;
    }
    #pragma unroll
    for (int it = 0; it < 4; ++it) {
        int i = it * 16 + lr;
        qf[it] = *(const short8*)(q16 + (rowbase + i) * 768 + head * HD + lk * 8);
    }
    __syncthreads();

    #pragma unroll
    for (int it = 0; it < 4; ++it) {
        const int i = it * 16 + lr;
        f32x4 sacc[4];
        #pragma unroll
        for (int jt = 0; jt < 4; ++jt) {
            f32x4 z = (f32x4){0.f, 0.f, 0.f, 0.f};
            sacc[jt] = __builtin_amdgcn_mfma_f32_16x16x32_bf16(kf[jt], qf[it], z, 0, 0, 0);
        }
        const float* brow = biasb + head * 4096 + i * 64;
        float sv[4][4];
        float mt = -1e30f;
        #pragma unroll
        for (int jt = 0; jt < 4; ++jt) {
            float4 bv = *(const float4*)&brow[jt * 16 + lk * 4];
            sv[jt][0] = sacc[jt][0] * scale + bv.x;
            sv[jt][1] = sacc[jt][1] * scale + bv.y;
            sv[jt][2] = sacc[jt][2] * scale + bv.z;
            sv[jt][3] = sacc[jt][3] * scale + bv.w;
            #pragma unroll
            for (int r = 0; r < 4; ++r) mt = fmaxf(mt, sv[jt][r]);
        }
        mt = fmaxf(mt, __shfl_xor(mt, 16, 64));
        mt = fmaxf(mt, __shfl_xor(mt, 32, 64));
        float psum = 0.f;
        #pragma unroll
        for (int jt = 0; jt < 4; ++jt) {
            float p0 = __expf(sv[jt][0] - mt);
            float p1 = __expf(sv[jt][1] - mt);
            float p2 = __expf(sv[jt][2] - mt);
            float p3 = __expf(sv[jt][3] - mt);
            psum += (p0 + p1) + (p2 + p3);
            uint2 wv;
            wv.x = (unsigned)bf16_bits(p0) | ((unsigned)bf16_bits(p1) << 16);
            wv.y = (unsigned)bf16_bits(p2) | ((unsigned)bf16_bits(p3) << 16);
            *(uint2*)&P_lds[lr][jt * 16 + lk * 4] = wv;
        }
        psum += __shfl_xor(psum, 16, 64);
        psum += __shfl_xor(psum, 32, 64);
        __syncthreads();

        f32x4 oacc[2];
        oacc[0] = (f32x4){0.f, 0.f, 0.f, 0.f};
        oacc[1] = (f32x4){0.f, 0.f, 0.f, 0.f};
        #pragma unroll
        for (int kst = 0; kst < 2; ++kst) {
            short8 bfv = *(const short8*)&P_lds[lr][kst * 32 + lk * 8];
            #pragma unroll
            for (int dt = 0; dt < 2; ++dt) {
                short8 af = *(const short8*)&VT_lds[dt * 16 + lr][kst * 32 + lk * 8];
                oacc[dt] = __builtin_amdgcn_mfma_f32_16x16x32_bf16(af, bfv, oacc[dt], 0, 0, 0);
            }
        }
        if (i < NWIN_N) {
            float inv = 1.f / psum;
            unsigned short* orow = (unsigned short*)outp + (rowbase + i) * CH + head * HD;
            #pragma unroll
            for (int dt = 0; dt < 2; ++dt) {
                uint2 wv;
                wv.x = (unsigned)bf16_bits(oacc[dt][0] * inv)
                     | ((unsigned)bf16_bits(oacc[dt][1] * inv) << 16);
                wv.y = (unsigned)bf16_bits(oacc[dt][2] * inv)
                     | ((unsigned)bf16_bits(oacc[dt][3] * inv) << 16);
                *(uint2*)&orow[dt * 16 + lk * 4] = wv;
            }
        }
        __syncthreads();
    }
}

// ---------------------------------------------------------------------------
// 5) cross-channel attention, MFMA flash. RESTRUCTURED (R10):
// P_lds shrunk 256->64 rows (16/wave, PV fused into the it-loop; wave-local,
// no extra barriers) -> LDS 55.3KB -> 27.6KB -> 3 blocks/CU resident.
// Staging loops split & branch-minimized with conflict-free write patterns.
// ---------------------------------------------------------------------------
__global__ __launch_bounds__(256) void cross_attn_mfma_kernel(
    const __hip_bfloat16* __restrict__ qkv,   // [262144][147] q|k|v
    __hip_bfloat16* __restrict__ outp)        // [262144][64] padded
{
    __shared__ __align__(16) unsigned short K_lds[64][72];
    __shared__ __align__(16) unsigned short VT_lds[64][72];
    __shared__ __align__(16) unsigned short P_lds[64][72];   // 16 rows per wave

    const int bc = blockIdx.x;
    const size_t base = (size_t)bc * 256;
    const int tid  = threadIdx.x;
    const int lane = tid & 63;
    const int wave = tid >> 6;
    const int i0w  = wave * 64;
    const int lr   = lane & 15;
    const int lk   = lane >> 4;
    const int prow = wave * 16 + lr;          // this lane's P_lds row

    const unsigned short* q16 = (const unsigned short*)qkv;
    const float inv7 = 1.f / 7.f;   // 49^-0.5

    short8 qf[4][2];
    #pragma unroll
    for (int it = 0; it < 4; ++it) {
        const unsigned short* qrow = q16 + (base + i0w + it * 16 + lr) * 147;
        #pragma unroll
        for (int kst = 0; kst < 2; ++kst) {
            int k0 = lk * 8 + kst * 32;
            short8 f;
            #pragma unroll
            for (int e = 0; e < 8; ++e) {
                int k = k0 + e;
                f[e] = (short)((k < 49) ? qrow[k] : 0);
            }
            qf[it][kst] = f;
        }
    }

    float m_run[4], l_run[4];
    f32x4 acc_o[4][4];   // [dt][it]
    #pragma unroll
    for (int it = 0; it < 4; ++it) { m_run[it] = -1e30f; l_run[it] = 0.f; }
    #pragma unroll
    for (int dt = 0; dt < 4; ++dt)
        #pragma unroll
        for (int it = 0; it < 4; ++it) acc_o[dt][it] = (f32x4){0.f, 0.f, 0.f, 0.f};

    for (int jt4 = 0; jt4 < 4; ++jt4) {
        const int j0 = jt4 * 64;
        // ---- stage K (64 tokens x 64 cols, zero-padded) ----
        {
            int j = tid >> 2, sub = tid & 3;
            const unsigned short* krow = q16 + (base + j0 + j) * 147 + 49;
            #pragma unroll
            for (int e = 0; e < 16; ++e) {
                int c = sub * 16 + e;
                K_lds[j][c] = (c < 49) ? krow[c] : (unsigned short)0;
            }
            // ---- stage V^T (d-major; rows d>=49 zeroed) ----
            int jj = tid & 63, dg = tid >> 6;
            const unsigned short* vrow = q16 + (base + j0 + jj) * 147 + 98;
            #pragma unroll
            for (int e = 0; e < 16; ++e) {
                int d = dg * 16 + e;
                VT_lds[d][jj] = (d < 49) ? vrow[d] : (unsigned short)0;
            }
        }
        __syncthreads();

        #pragma unroll
        for (int it = 0; it < 4; ++it) {
            // ---- S^T = mfma(K, Q) for 4 j-subtiles ----
            f32x4 sacc[4];
            #pragma unroll
            for (int jt = 0; jt < 4; ++jt) sacc[jt] = (f32x4){0.f, 0.f, 0.f, 0.f};
            #pragma unroll
            for (int kst = 0; kst < 2; ++kst) {
                #pragma unroll
                for (int jt = 0; jt < 4; ++jt) {
                    short8 af = *(const short8*)&K_lds[jt * 16 + lr][lk * 8 + kst * 32];
                    sacc[jt] = __builtin_amdgcn_mfma_f32_16x16x32_bf16(
                        af, qf[it][kst], sacc[jt], 0, 0, 0);
                }
            }
            // ---- online softmax over j ----
            float mt = -1e30f;
            #pragma unroll
            for (int jt = 0; jt < 4; ++jt)
                #pragma unroll
                for (int r = 0; r < 4; ++r) mt = fmaxf(mt, sacc[jt][r]);
            mt = fmaxf(mt, __shfl_xor(mt, 16, 64));
            mt = fmaxf(mt, __shfl_xor(mt, 32, 64));
            float mnew = fmaxf(m_run[it], mt * inv7);
            float corr = __expf(m_run[it] - mnew);
            m_run[it] = mnew;
            l_run[it] *= corr;
            #pragma unroll
            for (int dt = 0; dt < 4; ++dt)
                #pragma unroll
                for (int r = 0; r < 4; ++r) acc_o[dt][it][r] *= corr;

            float psum = 0.f;
            #pragma unroll
            for (int jt = 0; jt < 4; ++jt) {
                float p0 = __expf(sacc[jt][0] * inv7 - mnew);
                float p1 = __expf(sacc[jt][1] * inv7 - mnew);
                float p2 = __expf(sacc[jt][2] * inv7 - mnew);
                float p3 = __expf(sacc[jt][3] * inv7 - mnew);
                psum += (p0 + p1) + (p2 + p3);
                uint2 wv;
                wv.x = (unsigned)bf16_bits(p0) | ((unsigned)bf16_bits(p1) << 16);
                wv.y = (unsigned)bf16_bits(p2) | ((unsigned)bf16_bits(p3) << 16);
                *(uint2*)&P_lds[prow][jt * 16 + lk * 4] = wv;
            }
            psum += __shfl_xor(psum, 16, 64);
            psum += __shfl_xor(psum, 32, 64);
            l_run[it] += psum;

            // ---- PV fused: O^T += mfma(V^T, P) (wave-local rows; no barrier) ----
            #pragma unroll
            for (int kst = 0; kst < 2; ++kst) {
                short8 bfv = *(const short8*)&P_lds[prow][kst * 32 + lk * 8];
                #pragma unroll
                for (int dt = 0; dt < 4; ++dt) {
                    short8 af = *(const short8*)&VT_lds[dt * 16 + lr][kst * 32 + lk * 8];
                    acc_o[dt][it] = __builtin_amdgcn_mfma_f32_16x16x32_bf16(
                        af, bfv, acc_o[dt][it], 0, 0, 0);
                }
            }
        }
        __syncthreads();   // protect K/VT before next tile's staging
    }

    #pragma unroll
    for (int it = 0; it < 4; ++it) {
        float inv = 1.f / l_run[it];
        unsigned short* orow = (unsigned short*)outp + (base + i0w + it * 16 + lr) * 64;
        #pragma unroll
        for (int dt = 0; dt < 4; ++dt) {
            #pragma unroll
            for (int r = 0; r < 4; ++r) {
                int d = dt * 16 + lk * 4 + r;
                orow[d] = bf16_bits(acc_o[dt][it][r] * inv);
            }
        }
    }
}

// ---------------------------------------------------------------------------
// 6) batched 2D transpose: src[b][R][Cc] -> dst[b][Cc][R]; grid (Cc/64,R/64,B)
// ---------------------------------------------------------------------------
__global__ __launch_bounds__(256) void transpose_bf16_kernel(
    const __hip_bfloat16* __restrict__ src, __hip_bfloat16* __restrict__ dst,
    int R, int Cc)
{
    __shared__ __hip_bfloat16 T[64][66];
    int b = blockIdx.z;
    int r0 = blockIdx.y * 64, c0 = blockIdx.x * 64;
    const __hip_bfloat16* s = src + (size_t)b * R * Cc;
    __hip_bfloat16* d = dst + (size_t)b * R * Cc;
    int tid = threadIdx.x;
    int lr = tid >> 6, lc = tid & 63;

    #pragma unroll
    for (int l = 0; l < 16; ++l) {
        int rr = l * 4 + lr;
        T[rr][lc] = s[(size_t)(r0 + rr) * Cc + c0 + lc];
    }
    __syncthreads();
    #pragma unroll
    for (int l = 0; l < 16; ++l) {
        int cc = l * 4 + lr;
        d[(size_t)(c0 + cc) * R + r0 + lc] = T[lc][cc];
    }
}

// ---------------------------------------------------------------------------
__global__ void ws_marker_kernel(float* __restrict__ out0)
{
    if (threadIdx.x == 0) out0[0] = 777.0f;
}

// ---------------------------------------------------------------------------
extern "C" void kernel_launch(void* const* d_in, const int* in_sizes, int n_in,
                              void* d_out, int out_size, void* d_ws, size_t ws_size,
                              hipStream_t stream)
{
    const float* x        = (const float*)d_in[0];
    const float* gamma    = (const float*)d_in[1];
    const float* beta     = (const float*)d_in[2];
    const float* qkv_l_w  = (const float*)d_in[3];
    const float* qkv_l_b  = (const float*)d_in[4];
    const float* proj_l_w = (const float*)d_in[5];
    const float* proj_l_b = (const float*)d_in[6];
    const float* rpb      = (const float*)d_in[7];
    const float* qkv_c_w  = (const float*)d_in[8];
    const float* qkv_c_b  = (const float*)d_in[9];
    const float* proj_c_w = (const float*)d_in[10];
    const float* proj_c_b = (const float*)d_in[11];
    const float* proj_w   = (const float*)d_in[12];

    float* out0 = (float*)d_out;
    float* out1 = out0 + ELEMS;

    copy_f32_kernel<<<(int)(ELEMS / 1024), 256, 0, stream>>>(x, out1);

    char* ws = (char*)d_ws;
    if (ws_size < 6 * SZ) {
        ws_marker_kernel<<<1, 64, 0, stream>>>(out0);
        return;
    }

    const size_t P = SZ;
    // plane/lifetime map (verified: no overlap while live):
    __hip_bfloat16* localOut  = (__hip_bfloat16*)(ws + 0 * P);          // K5 W -> K11 R
    __hip_bfloat16* patches   = (__hip_bfloat16*)(ws + 1 * P);          // K1 W -> K6a R
    __hip_bfloat16* qkv_l     = (__hip_bfloat16*)(ws + 2 * P);          // K3 W -> K4 R (3 planes)
    __hip_bfloat16* attnL     = (__hip_bfloat16*)(ws + 5 * P);          // K4 W -> K5 R
    unsigned short* wt_qkv_l  = (unsigned short*)(ws + 0 * P);          // K0 W -> K3 R (plane0, 393KB)
    float*          biasb     = (float*)(ws + 0 * P + 0x80000);         // K0b W -> K4 R (plane0, 131KB)
    char*           G         = ws + 4 * P;                             // weight gap (free after K4)
    unsigned short* wt_proj_l = (unsigned short*)(G + 0x000000);
    unsigned short* wt_qkv_c  = (unsigned short*)(G + 0x080000);
    unsigned short* wt_proj_c = (unsigned short*)(G + 0x100000);
    unsigned short* wt_final  = (unsigned short*)(G + 0x180000);
    __hip_bfloat16* pc_dense  = (__hip_bfloat16*)(ws + 2 * P);          // K6a W -> K6b R
    __hip_bfloat16* pc_pad    = (__hip_bfloat16*)(ws + 6 * P - (size_t)262144 * 64 * 2); // K6b W -> K7 R
    __hip_bfloat16* qkvc      = (__hip_bfloat16*)(ws + 1 * P);          // K7 W -> K8 R (exactly 3P)
    __hip_bfloat16* crossAttn = pc_pad;                                 // K8 W -> K9 R
    __hip_bfloat16* crossProj = (__hip_bfloat16*)(ws + 1 * P);          // K9 W -> K10 R
    __hip_bfloat16* crossT    = (__hip_bfloat16*)(ws + 2 * P);          // K10 W -> K11 R

    // K0) weight prep needed before K3; bias table before K4
    prep_wt_kernel<<<768, 256, 0, stream>>>(qkv_l_w, wt_qkv_l, 256, 768, 256, 768);
    bias_prep_kernel<<<128, 256, 0, stream>>>(rpb, biasb);
    // K1) LN + window partition
    ln_partition_kernel<<<BB * HH * 7, 256, 0, stream>>>(x, gamma, beta, patches);
    // K3) qkv_local: [50176,256] @ [256,768]
    gemm_mfma_kernel<<<dim3(12, 392), 256, 0, stream>>>(
        patches, nullptr, 256, wt_qkv_l, qkv_l_b, qkv_l, nullptr, 50176, 768, 256);
    // K4) local attention (MFMA)
    local_attn_mfma_kernel<<<1024 * NHEAD, 64, 0, stream>>>(qkv_l, biasb, attnL);
    // K4.5) remaining weight preps (gap free after K4)
    prep_wt_kernel<<<256, 256, 0, stream>>>(proj_l_w, wt_proj_l, 256, 256, 256, 256);
    prep_wt_kernel<<<48, 256, 0, stream>>>(qkv_c_w, wt_qkv_c, 49, 147, 64, 192);
    prep_wt_kernel<<<16, 256, 0, stream>>>(proj_c_w, wt_proj_c, 49, 49, 64, 64);
    prep_wt_kernel<<<512, 256, 0, stream>>>(proj_w, wt_final, 512, 256, 512, 256);
    // K5) proj_local: [50176,256] @ [256,256]
    gemm_mfma_kernel<<<dim3(4, 392), 256, 0, stream>>>(
        attnL, nullptr, 256, wt_proj_l, proj_l_b, localOut, nullptr, 50176, 256, 256);
    // K6a) pc_dense = per-b transpose of patches
    transpose_bf16_kernel<<<dim3(4, 196, BB), 256, 0, stream>>>(patches, pc_dense, 12544, 256);
    // K6b) zero-pad rows 49 -> 64
    pad49_kernel<<<65536, 256, 0, stream>>>(
        (const unsigned short*)pc_dense, (unsigned short*)pc_pad);
    // K7) qkv_cross: [262144,64pad] @ [64,147]
    gemm_mfma_kernel<<<dim3(3, 2048), 256, 0, stream>>>(
        pc_pad, nullptr, 64, wt_qkv_c, qkv_c_b, qkvc, nullptr, 262144, 147, 64);
    // K8) cross attention
    cross_attn_mfma_kernel<<<1024, 256, 0, stream>>>(qkvc, crossAttn);
    // K9) proj_cross: [262144,64pad] @ [64,49]
    gemm_mfma_kernel<<<dim3(1, 2048), 256, 0, stream>>>(
        crossAttn, nullptr, 64, wt_proj_c, proj_c_b, crossProj, nullptr, 262144, 49, 64);
    // K10) crossT = per-b transpose back
    transpose_bf16_kernel<<<dim3(196, 4, BB), 256, 0, stream>>>(crossProj, crossT, 256, 12544);
    // K11) final: concat[localOut|crossT] @ proj_w -> out0 fp32 BCHW
    gemm_mfma_kernel<<<dim3(4, 392), 256, 0, stream>>>(
        localOut, crossT, 256, wt_final, nullptr, nullptr, out0, 50176, 256, 512);
}

// Round 11
// 378.146 us; speedup vs baseline: 4.4799x; 1.1968x over previous
//
#include <hip/hip_runtime.h>
#include <hip/hip_bf16.h>

// Problem geometry (fixed by the reference):
// B=4, C=256, H=W=112, ps=7, N=49, nP=256 windows/batch, NH=8, d=32.
// Inputs fp32. d_out is FP32: [out | shortcut], each (B,C,H,W).

#define PS 7
#define NWIN_N 49
#define CH 256
#define HH 112
#define WW 112
#define BB 4
#define NHEAD 8
#define HD 32

static constexpr size_t ELEMS = (size_t)BB * CH * HH * WW;      // 12,845,056
static constexpr size_t SZ    = ELEMS * 2;                      // 25,690,112 B (one bf16 plane)

typedef __attribute__((ext_vector_type(8))) short short8;
typedef __attribute__((ext_vector_type(4))) float f32x4;

static __device__ __forceinline__ unsigned short bf16_bits(float v) {
    __hip_bfloat16 h = __float2bfloat16(v);
    return *reinterpret_cast<unsigned short*>(&h);
}

// ---------------------------------------------------------------------------
// 1) LayerNorm over C + window partition -> patches[(b*256+p)*49+i][c] (bf16)
// ---------------------------------------------------------------------------
__global__ __launch_bounds__(256) void ln_partition_kernel(
    const float* __restrict__ x, const float* __restrict__ gamma,
    const float* __restrict__ beta, __hip_bfloat16* __restrict__ patches)
{
    int blk = blockIdx.x;
    int seg = blk % 7;
    int bh = blk / 7;
    int h = bh % HH, b = bh / HH;
    int w0 = seg * 16;
    int tid = threadIdx.x;

    __shared__ float X[256][17];
    __shared__ float mus[16], rstds[16];

    #pragma unroll
    for (int l = 0; l < 16; ++l) {
        int idx = l * 256 + tid;
        int c = idx >> 4, wl = idx & 15;
        X[c][wl] = x[((size_t)(b * CH + c) * HH + h) * WW + w0 + wl];
    }
    __syncthreads();

    if (tid < 16) {
        float s = 0.f, ss = 0.f;
        for (int c = 0; c < 256; ++c) { float v = X[c][tid]; s += v; ss += v * v; }
        float mu = s * (1.f / 256.f);
        float var = ss * (1.f / 256.f) - mu * mu;
        mus[tid] = mu;
        rstds[tid] = rsqrtf(var + 1e-5f);
    }
    __syncthreads();

    int c = tid;
    float g = gamma[c], be = beta[c];
    int hp = h / PS, r = h - hp * PS;
    #pragma unroll
    for (int wl = 0; wl < 16; ++wl) {
        int w = w0 + wl;
        int wp = w / PS, cc = w - wp * PS;
        int win = (b * 16 + hp) * 16 + wp;
        int i = r * PS + cc;
        float v = (X[c][wl] - mus[wl]) * rstds[wl] * g + be;
        patches[((size_t)win * NWIN_N + i) * CH + c] = __float2bfloat16(v);
    }
}

// ---------------------------------------------------------------------------
// 2) shortcut: fp32 -> fp32 copy (float4)
// ---------------------------------------------------------------------------
__global__ __launch_bounds__(256) void copy_f32_kernel(
    const float* __restrict__ x, float* __restrict__ out)
{
    size_t i = ((size_t)blockIdx.x * 256 + threadIdx.x) * 4;
    *(float4*)(out + i) = *(const float4*)(x + i);
}

// ---------------------------------------------------------------------------
// prep: W fp32 [Kreal][N] -> Wt bf16 [Npad][Kpad] k-major, zero padded
// ---------------------------------------------------------------------------
__global__ __launch_bounds__(256) void prep_wt_kernel(
    const float* __restrict__ W, unsigned short* __restrict__ Wt,
    int Kreal, int N, int Kpad, int Npad)
{
    int idx = blockIdx.x * 256 + threadIdx.x;
    if (idx >= Npad * Kpad) return;
    int n = idx / Kpad, k = idx - n * Kpad;
    float v = (n < N && k < Kreal) ? W[(size_t)k * N + n] : 0.f;
    Wt[idx] = bf16_bits(v);
}

// ---------------------------------------------------------------------------
// bias prep: rpb [169][8] -> biasb[8][64][64] fp32 padded.
// ---------------------------------------------------------------------------
__global__ __launch_bounds__(256) void bias_prep_kernel(
    const float* __restrict__ rpb, float* __restrict__ biasb)
{
    int idx = blockIdx.x * 256 + threadIdx.x;   // < 32768
    int head = idx >> 12;
    int rem = idx & 4095;
    int i = rem >> 6, j = rem & 63;
    float v;
    if (j >= NWIN_N) v = -1e9f;
    else if (i >= NWIN_N) v = 0.f;
    else {
        int ri = i / 7, ci = i - ri * 7;
        int rj = j / 7, cj = j - rj * 7;
        v = rpb[((ri - rj + 6) * 13 + (ci - cj + 6)) * NHEAD + head];
    }
    biasb[idx] = v;
}

// ---------------------------------------------------------------------------
// pad49: src [M][49] -> dst [M][64] zero-padded (M = 262144)
// ---------------------------------------------------------------------------
__global__ __launch_bounds__(256) void pad49_kernel(
    const unsigned short* __restrict__ src, unsigned short* __restrict__ dst)
{
    size_t idx = (size_t)blockIdx.x * 256 + threadIdx.x;   // < 262144*64
    int t = idx & 63;
    size_t m = idx >> 6;
    dst[idx] = (t < 49) ? src[m * 49 + t] : (unsigned short)0;
}

// ---------------------------------------------------------------------------
// Unified MFMA GEMM: C[M][N] = concat(A1[.][K1], A2[.][K-K1]) @ Wt^T + bias
// BM=128, BN=64, BK=64; 256 thr = 4 waves (2x2); 16x16x32 MFMA.
// XCD-chunked tile swizzle (requires ntiles % 8 == 0, all call sites comply).
// Cb path: pitchN%8==0 -> LDS-staged coalesced dwordx4 stores (Alds reused);
//          else scalar guarded stores. Cf path: fused fp32 BCHW scatter.
// ---------------------------------------------------------------------------
__global__ __launch_bounds__(256) void gemm_mfma_kernel(
    const __hip_bfloat16* __restrict__ A1p, const __hip_bfloat16* __restrict__ A2p,
    int K1, const unsigned short* __restrict__ Wt, const float* __restrict__ bias,
    __hip_bfloat16* __restrict__ Cb, float* __restrict__ Cf,
    int M, int N, int K, int pitchN)
{
    __shared__ __align__(16) unsigned short Alds[128][72];
    __shared__ __align__(16) unsigned short Wlds[64][72];
    const unsigned short* A1 = (const unsigned short*)A1p;
    const unsigned short* A2 = (const unsigned short*)A2p;

    // XCD-aware chunked swizzle: each XCD gets a contiguous tile range,
    // n fastest within m -> A-panels become L2-resident per XCD.
    const int nb = gridDim.x;
    const int ntiles = nb * gridDim.y;
    const int bid = blockIdx.y * nb + blockIdx.x;
    const int chunk = ntiles >> 3;
    const int tile = (bid & 7) * chunk + (bid >> 3);
    const int m0 = (tile / nb) * 128, n0 = (tile % nb) * 64;

    const int tid = threadIdx.x, lane = tid & 63, wave = tid >> 6;
    const int wm = wave >> 1, wn = wave & 1;
    const int lr = lane & 15, lk = lane >> 4;

    f32x4 acc[4][2];
    #pragma unroll
    for (int i = 0; i < 4; ++i)
        #pragma unroll
        for (int j = 0; j < 2; ++j) acc[i][j] = (f32x4){0.f, 0.f, 0.f, 0.f};

    for (int k0 = 0; k0 < K; k0 += 64) {
        #pragma unroll
        for (int i = 0; i < 4; ++i) {
            int s = tid + 256 * i;
            int row = s >> 3, c8 = (s & 7) * 8;
            int k = k0 + c8;
            const unsigned short* src = (k < K1)
                ? A1 + (size_t)(m0 + row) * K1 + k
                : A2 + (size_t)(m0 + row) * (K - K1) + (k - K1);
            *(short8*)&Alds[row][c8] = *(const short8*)src;
        }
        #pragma unroll
        for (int i = 0; i < 2; ++i) {
            int s = tid + 256 * i;
            int row = s >> 3, c8 = (s & 7) * 8;
            *(short8*)&Wlds[row][c8] =
                *(const short8*)(Wt + (size_t)(n0 + row) * K + k0 + c8);
        }
        __syncthreads();
        #pragma unroll
        for (int kk = 0; kk < 64; kk += 32) {
            short8 a[4], w[2];
            #pragma unroll
            for (int mi = 0; mi < 4; ++mi)
                a[mi] = *(const short8*)&Alds[wm * 64 + mi * 16 + lr][kk + lk * 8];
            #pragma unroll
            for (int nj = 0; nj < 2; ++nj)
                w[nj] = *(const short8*)&Wlds[wn * 32 + nj * 16 + lr][kk + lk * 8];
            #pragma unroll
            for (int mi = 0; mi < 4; ++mi)
                #pragma unroll
                for (int nj = 0; nj < 2; ++nj)
                    acc[mi][nj] = __builtin_amdgcn_mfma_f32_16x16x32_bf16(
                        a[mi], w[nj], acc[mi][nj], 0, 0, 0);
        }
        __syncthreads();
    }

    if (Cb) {
        if ((pitchN & 7) == 0) {
            // ---- coalesced epilogue: stage C tile in Alds, write 16B rows ----
            #pragma unroll
            for (int nj = 0; nj < 2; ++nj) {
                int n = n0 + wn * 32 + nj * 16 + lr;
                float bv = (bias && n < N) ? bias[n] : 0.f;
                #pragma unroll
                for (int mi = 0; mi < 4; ++mi)
                    #pragma unroll
                    for (int r = 0; r < 4; ++r)
                        Alds[wm * 64 + mi * 16 + lk * 4 + r][wn * 32 + nj * 16 + lr] =
                            bf16_bits(acc[mi][nj][r] + bv);
            }
            __syncthreads();
            #pragma unroll
            for (int i = 0; i < 4; ++i) {
                int s = tid + 256 * i;
                int row = s >> 3, c8 = (s & 7) * 8;
                if (n0 + c8 + 8 <= pitchN)
                    *(short8*)((unsigned short*)Cb + (size_t)(m0 + row) * pitchN + n0 + c8) =
                        *(const short8*)&Alds[row][c8];
            }
        } else {
            #pragma unroll
            for (int nj = 0; nj < 2; ++nj) {
                int n = n0 + wn * 32 + nj * 16 + lr;
                if (n >= N) continue;
                float bv = bias ? bias[n] : 0.f;
                #pragma unroll
                for (int mi = 0; mi < 4; ++mi) {
                    #pragma unroll
                    for (int r = 0; r < 4; ++r) {
                        int m = m0 + wm * 64 + mi * 16 + lk * 4 + r;
                        ((unsigned short*)Cb)[(size_t)m * pitchN + n] =
                            bf16_bits(acc[mi][nj][r] + bv);
                    }
                }
            }
        }
    } else {
        // fused epilogue: m=(b*256+p)*49+t -> (b,h,w); n -> ch; fp32 BCHW
        #pragma unroll
        for (int mi = 0; mi < 4; ++mi) {
            #pragma unroll
            for (int r = 0; r < 4; ++r) {
                int m = m0 + wm * 64 + mi * 16 + lk * 4 + r;
                int b = m / 12544, rem = m - b * 12544;
                int p = rem / 49, t = rem - p * 49;
                int h = (p >> 4) * 7 + t / 7, w = (p & 15) * 7 + (t % 7);
                size_t ob = ((size_t)(b * 256) * HH + h) * WW + w;
                #pragma unroll
                for (int nj = 0; nj < 2; ++nj) {
                    int ch = n0 + wn * 32 + nj * 16 + lr;
                    Cf[ob + (size_t)ch * (HH * WW)] = acc[mi][nj][r];
                }
            }
        }
    }
}

// ---------------------------------------------------------------------------
// 4) local windowed attention, MFMA. One wave per (win, head).
// ---------------------------------------------------------------------------
__global__ __launch_bounds__(64) void local_attn_mfma_kernel(
    const __hip_bfloat16* __restrict__ qkv,   // [50176][768] q|k|v
    const float* __restrict__ biasb,          // [8][64][64] fp32 padded
    __hip_bfloat16* __restrict__ outp)        // [50176][256]
{
    __shared__ __align__(16) unsigned short VT_lds[32][72];
    __shared__ __align__(16) unsigned short P_lds[16][72];

    const int win  = blockIdx.x >> 3;
    const int head = blockIdx.x & 7;
    const int lane = threadIdx.x;
    const int lr = lane & 15, lk = lane >> 4;
    const unsigned short* q16 = (const unsigned short*)qkv;
    const size_t rowbase = (size_t)win * NWIN_N;
    const float scale = 0.17677669529663687f;   // 32^-0.5

    for (int t = 0; t < 32; ++t) {
        int idx = lane + 64 * t;
        int j = idx >> 5, d = idx & 31;
        unsigned short v = 0;
        if (j < NWIN_N) v = q16[(rowbase + j) * 768 + 512 + head * HD + d];
        VT_lds[d][j] = v;
    }

    short8 kf[4], qf[4];
    #pragma unroll
    for (int jt = 0; jt < 4; ++jt) {
        int j = jt * 16 + lr;
        short8 f = *(const short8*)(q16 + (rowbase + j) * 768 + 256 + head * HD + lk * 8);
        if (j >= NWIN_N) {
            #pragma unroll
            for (int e = 0; e < 8; ++e) f[e] = 0;
        }
        kf[jt] = f;
    }
    #pragma unroll
    for (int it = 0; it < 4; ++it) {
        int i = it * 16 + lr;
        qf[it] = *(const short8*)(q16 + (rowbase + i) * 768 + head * HD + lk * 8);
    }
    __syncthreads();

    #pragma unroll
    for (int it = 0; it < 4; ++it) {
        const int i = it * 16 + lr;
        f32x4 sacc[4];
        #pragma unroll
        for (int jt = 0; jt < 4; ++jt) {
            f32x4 z = (f32x4){0.f, 0.f, 0.f, 0.f};
            sacc[jt] = __builtin_amdgcn_mfma_f32_16x16x32_bf16(kf[jt], qf[it], z, 0, 0, 0);
        }
        const float* brow = biasb + head * 4096 + i * 64;
        float sv[4][4];
        float mt = -1e30f;
        #pragma unroll
        for (int jt = 0; jt < 4; ++jt) {
            float4 bv = *(const float4*)&brow[jt * 16 + lk * 4];
            sv[jt][0] = sacc[jt][0] * scale + bv.x;
            sv[jt][1] = sacc[jt][1] * scale + bv.y;
            sv[jt][2] = sacc[jt][2] * scale + bv.z;
            sv[jt][3] = sacc[jt][3] * scale + bv.w;
            #pragma unroll
            for (int r = 0; r < 4; ++r) mt = fmaxf(mt, sv[jt][r]);
        }
        mt = fmaxf(mt, __shfl_xor(mt, 16, 64));
        mt = fmaxf(mt, __shfl_xor(mt, 32, 64));
        float psum = 0.f;
        #pragma unroll
        for (int jt = 0; jt < 4; ++jt) {
            float p0 = __expf(sv[jt][0] - mt);
            float p1 = __expf(sv[jt][1] - mt);
            float p2 = __expf(sv[jt][2] - mt);
            float p3 = __expf(sv[jt][3] - mt);
            psum += (p0 + p1) + (p2 + p3);
            uint2 wv;
            wv.x = (unsigned)bf16_bits(p0) | ((unsigned)bf16_bits(p1) << 16);
            wv.y = (unsigned)bf16_bits(p2) | ((unsigned)bf16_bits(p3) << 16);
            *(uint2*)&P_lds[lr][jt * 16 + lk * 4] = wv;
        }
        psum += __shfl_xor(psum, 16, 64);
        psum += __shfl_xor(psum, 32, 64);
        __syncthreads();

        f32x4 oacc[2];
        oacc[0] = (f32x4){0.f, 0.f, 0.f, 0.f};
        oacc[1] = (f32x4){0.f, 0.f, 0.f, 0.f};
        #pragma unroll
        for (int kst = 0; kst < 2; ++kst) {
            short8 bfv = *(const short8*)&P_lds[lr][kst * 32 + lk * 8];
            #pragma unroll
            for (int dt = 0; dt < 2; ++dt) {
                short8 af = *(const short8*)&VT_lds[dt * 16 + lr][kst * 32 + lk * 8];
                oacc[dt] = __builtin_amdgcn_mfma_f32_16x16x32_bf16(af, bfv, oacc[dt], 0, 0, 0);
            }
        }
        if (i < NWIN_N) {
            float inv = 1.f / psum;
            unsigned short* orow = (unsigned short*)outp + (rowbase + i) * CH + head * HD;
            #pragma unroll
            for (int dt = 0; dt < 2; ++dt) {
                uint2 wv;
                wv.x = (unsigned)bf16_bits(oacc[dt][0] * inv)
                     | ((unsigned)bf16_bits(oacc[dt][1] * inv) << 16);
                wv.y = (unsigned)bf16_bits(oacc[dt][2] * inv)
                     | ((unsigned)bf16_bits(oacc[dt][3] * inv) << 16);
                *(uint2*)&orow[dt * 16 + lk * 4] = wv;
            }
        }
        __syncthreads();
    }
}

// ---------------------------------------------------------------------------
// 5) cross-channel attention, MFMA flash. qkvc rows now pitch 160 (16B
// aligned; cols: q 0..48 | k 49..97 | v 98..146 | pad).
// ---------------------------------------------------------------------------
__global__ __launch_bounds__(256) void cross_attn_mfma_kernel(
    const __hip_bfloat16* __restrict__ qkv,   // [262144][160] q|k|v padded
    __hip_bfloat16* __restrict__ outp)        // [262144][64] padded
{
    __shared__ __align__(16) unsigned short K_lds[64][72];
    __shared__ __align__(16) unsigned short VT_lds[64][72];
    __shared__ __align__(16) unsigned short P_lds[64][72];   // 16 rows per wave

    const int bc = blockIdx.x;
    const size_t base = (size_t)bc * 256;
    const int tid  = threadIdx.x;
    const int lane = tid & 63;
    const int wave = tid >> 6;
    const int i0w  = wave * 64;
    const int lr   = lane & 15;
    const int lk   = lane >> 4;
    const int prow = wave * 16 + lr;

    const unsigned short* q16 = (const unsigned short*)qkv;
    const float inv7 = 1.f / 7.f;   // 49^-0.5

    short8 qf[4][2];
    #pragma unroll
    for (int it = 0; it < 4; ++it) {
        const unsigned short* qrow = q16 + (base + i0w + it * 16 + lr) * 160;
        #pragma unroll
        for (int kst = 0; kst < 2; ++kst) {
            int k0 = lk * 8 + kst * 32;
            short8 f;
            #pragma unroll
            for (int e = 0; e < 8; ++e) {
                int k = k0 + e;
                f[e] = (short)((k < 49) ? qrow[k] : 0);
            }
            qf[it][kst] = f;
        }
    }

    float m_run[4], l_run[4];
    f32x4 acc_o[4][4];   // [dt][it]
    #pragma unroll
    for (int it = 0; it < 4; ++it) { m_run[it] = -1e30f; l_run[it] = 0.f; }
    #pragma unroll
    for (int dt = 0; dt < 4; ++dt)
        #pragma unroll
        for (int it = 0; it < 4; ++it) acc_o[dt][it] = (f32x4){0.f, 0.f, 0.f, 0.f};

    for (int jt4 = 0; jt4 < 4; ++jt4) {
        const int j0 = jt4 * 64;
        {
            int j = tid >> 2, sub = tid & 3;
            const unsigned short* krow = q16 + (base + j0 + j) * 160 + 49;
            #pragma unroll
            for (int e = 0; e < 16; ++e) {
                int c = sub * 16 + e;
                K_lds[j][c] = (c < 49) ? krow[c] : (unsigned short)0;
            }
            int jj = tid & 63, dg = tid >> 6;
            const unsigned short* vrow = q16 + (base + j0 + jj) * 160 + 98;
            #pragma unroll
            for (int e = 0; e < 16; ++e) {
                int d = dg * 16 + e;
                VT_lds[d][jj] = (d < 49) ? vrow[d] : (unsigned short)0;
            }
        }
        __syncthreads();

        #pragma unroll
        for (int it = 0; it < 4; ++it) {
            f32x4 sacc[4];
            #pragma unroll
            for (int jt = 0; jt < 4; ++jt) sacc[jt] = (f32x4){0.f, 0.f, 0.f, 0.f};
            #pragma unroll
            for (int kst = 0; kst < 2; ++kst) {
                #pragma unroll
                for (int jt = 0; jt < 4; ++jt) {
                    short8 af = *(const short8*)&K_lds[jt * 16 + lr][lk * 8 + kst * 32];
                    sacc[jt] = __builtin_amdgcn_mfma_f32_16x16x32_bf16(
                        af, qf[it][kst], sacc[jt], 0, 0, 0);
                }
            }
            float mt = -1e30f;
            #pragma unroll
            for (int jt = 0; jt < 4; ++jt)
                #pragma unroll
                for (int r = 0; r < 4; ++r) mt = fmaxf(mt, sacc[jt][r]);
            mt = fmaxf(mt, __shfl_xor(mt, 16, 64));
            mt = fmaxf(mt, __shfl_xor(mt, 32, 64));
            float mnew = fmaxf(m_run[it], mt * inv7);
            float corr = __expf(m_run[it] - mnew);
            m_run[it] = mnew;
            l_run[it] *= corr;
            #pragma unroll
            for (int dt = 0; dt < 4; ++dt)
                #pragma unroll
                for (int r = 0; r < 4; ++r) acc_o[dt][it][r] *= corr;

            float psum = 0.f;
            #pragma unroll
            for (int jt = 0; jt < 4; ++jt) {
                float p0 = __expf(sacc[jt][0] * inv7 - mnew);
                float p1 = __expf(sacc[jt][1] * inv7 - mnew);
                float p2 = __expf(sacc[jt][2] * inv7 - mnew);
                float p3 = __expf(sacc[jt][3] * inv7 - mnew);
                psum += (p0 + p1) + (p2 + p3);
                uint2 wv;
                wv.x = (unsigned)bf16_bits(p0) | ((unsigned)bf16_bits(p1) << 16);
                wv.y = (unsigned)bf16_bits(p2) | ((unsigned)bf16_bits(p3) << 16);
                *(uint2*)&P_lds[prow][jt * 16 + lk * 4] = wv;
            }
            psum += __shfl_xor(psum, 16, 64);
            psum += __shfl_xor(psum, 32, 64);
            l_run[it] += psum;

            #pragma unroll
            for (int kst = 0; kst < 2; ++kst) {
                short8 bfv = *(const short8*)&P_lds[prow][kst * 32 + lk * 8];
                #pragma unroll
                for (int dt = 0; dt < 4; ++dt) {
                    short8 af = *(const short8*)&VT_lds[dt * 16 + lr][kst * 32 + lk * 8];
                    acc_o[dt][it] = __builtin_amdgcn_mfma_f32_16x16x32_bf16(
                        af, bfv, acc_o[dt][it], 0, 0, 0);
                }
            }
        }
        __syncthreads();
    }

    #pragma unroll
    for (int it = 0; it < 4; ++it) {
        float inv = 1.f / l_run[it];
        unsigned short* orow = (unsigned short*)outp + (base + i0w + it * 16 + lr) * 64;
        #pragma unroll
        for (int dt = 0; dt < 4; ++dt) {
            #pragma unroll
            for (int r = 0; r < 4; ++r) {
                int d = dt * 16 + lk * 4 + r;
                orow[d] = bf16_bits(acc_o[dt][it][r] * inv);
            }
        }
    }
}

// ---------------------------------------------------------------------------
// 6) batched 2D transpose: src[b][R][Cc] -> dst[b][Cc][R]; grid (Cc/64,R/64,B)
// ---------------------------------------------------------------------------
__global__ __launch_bounds__(256) void transpose_bf16_kernel(
    const __hip_bfloat16* __restrict__ src, __hip_bfloat16* __restrict__ dst,
    int R, int Cc)
{
    __shared__ __hip_bfloat16 T[64][66];
    int b = blockIdx.z;
    int r0 = blockIdx.y * 64, c0 = blockIdx.x * 64;
    const __hip_bfloat16* s = src + (size_t)b * R * Cc;
    __hip_bfloat16* d = dst + (size_t)b * R * Cc;
    int tid = threadIdx.x;
    int lr = tid >> 6, lc = tid & 63;

    #pragma unroll
    for (int l = 0; l < 16; ++l) {
        int rr = l * 4 + lr;
        T[rr][lc] = s[(size_t)(r0 + rr) * Cc + c0 + lc];
    }
    __syncthreads();
    #pragma unroll
    for (int l = 0; l < 16; ++l) {
        int cc = l * 4 + lr;
        d[(size_t)(c0 + cc) * R + r0 + lc] = T[lc][cc];
    }
}

// ---------------------------------------------------------------------------
__global__ void ws_marker_kernel(float* __restrict__ out0)
{
    if (threadIdx.x == 0) out0[0] = 777.0f;
}

// ---------------------------------------------------------------------------
extern "C" void kernel_launch(void* const* d_in, const int* in_sizes, int n_in,
                              void* d_out, int out_size, void* d_ws, size_t ws_size,
                              hipStream_t stream)
{
    const float* x        = (const float*)d_in[0];
    const float* gamma    = (const float*)d_in[1];
    const float* beta     = (const float*)d_in[2];
    const float* qkv_l_w  = (const float*)d_in[3];
    const float* qkv_l_b  = (const float*)d_in[4];
    const float* proj_l_w = (const float*)d_in[5];
    const float* proj_l_b = (const float*)d_in[6];
    const float* rpb      = (const float*)d_in[7];
    const float* qkv_c_w  = (const float*)d_in[8];
    const float* qkv_c_b  = (const float*)d_in[9];
    const float* proj_c_w = (const float*)d_in[10];
    const float* proj_c_b = (const float*)d_in[11];
    const float* proj_w   = (const float*)d_in[12];

    float* out0 = (float*)d_out;
    float* out1 = out0 + ELEMS;

    copy_f32_kernel<<<(int)(ELEMS / 1024), 256, 0, stream>>>(x, out1);

    char* ws = (char*)d_ws;
    if (ws_size < 6 * SZ) {
        ws_marker_kernel<<<1, 64, 0, stream>>>(out0);
        return;
    }

    const size_t P = SZ;
    // plane/lifetime map (re-verified):
    //   localOut  [0,1P)                 K5 W -> K11 R
    //   wt_qkv_l  [0, 393KB)             K0 W -> K3 R (dead before K5)
    //   biasb     [0.5MB, 0.63MB)        K0b W -> K4 R
    //   patches   [1P,2P)                K1 W -> K6a R
    //   qkv_l     [2P,5P)                K3 W -> K4 R
    //   attnL     [5P,6P)                K4 W -> K5 R
    //   G weights [4P+7MB, 4P+9MB)       K4.5 W -> K5..K11 R (inside dead qkv_l)
    //   pc_dense  [2P,3P)                K6a W -> K6b R
    //   pc_pad    [6P-33.5MB, 6P)        K6b W -> K7 R
    //   qkvc      [1P, 1P+84MB=4.27P)    K7 W -> K8 R (pitch 160)
    //   crossAttn = pc_pad               K8 W -> K9 R
    //   crossProj [1P, 1P+25.7MB)        K9 W -> K10 R
    //   crossT    [2P,3P)                K10 W -> K11 R
    __hip_bfloat16* localOut  = (__hip_bfloat16*)(ws + 0 * P);
    unsigned short* wt_qkv_l  = (unsigned short*)(ws + 0 * P);
    float*          biasb     = (float*)(ws + 0 * P + 0x80000);
    __hip_bfloat16* patches   = (__hip_bfloat16*)(ws + 1 * P);
    __hip_bfloat16* qkv_l     = (__hip_bfloat16*)(ws + 2 * P);
    __hip_bfloat16* attnL     = (__hip_bfloat16*)(ws + 5 * P);
    char*           G         = ws + 4 * P + 0x700000;
    unsigned short* wt_proj_l = (unsigned short*)(G + 0x000000);
    unsigned short* wt_qkv_c  = (unsigned short*)(G + 0x080000);
    unsigned short* wt_proj_c = (unsigned short*)(G + 0x100000);
    unsigned short* wt_final  = (unsigned short*)(G + 0x180000);
    __hip_bfloat16* pc_dense  = (__hip_bfloat16*)(ws + 2 * P);
    __hip_bfloat16* pc_pad    = (__hip_bfloat16*)(ws + 6 * P - (size_t)262144 * 64 * 2);
    __hip_bfloat16* qkvc      = (__hip_bfloat16*)(ws + 1 * P);
    __hip_bfloat16* crossAttn = pc_pad;
    __hip_bfloat16* crossProj = (__hip_bfloat16*)(ws + 1 * P);
    __hip_bfloat16* crossT    = (__hip_bfloat16*)(ws + 2 * P);

    // K0) weight prep needed before K3; bias table before K4
    prep_wt_kernel<<<768, 256, 0, stream>>>(qkv_l_w, wt_qkv_l, 256, 768, 256, 768);
    bias_prep_kernel<<<128, 256, 0, stream>>>(rpb, biasb);
    // K1) LN + window partition
    ln_partition_kernel<<<BB * HH * 7, 256, 0, stream>>>(x, gamma, beta, patches);
    // K3) qkv_local: [50176,256] @ [256,768], pitch 768
    gemm_mfma_kernel<<<dim3(12, 392), 256, 0, stream>>>(
        patches, nullptr, 256, wt_qkv_l, qkv_l_b, qkv_l, nullptr, 50176, 768, 256, 768);
    // K4) local attention (MFMA)
    local_attn_mfma_kernel<<<1024 * NHEAD, 64, 0, stream>>>(qkv_l, biasb, attnL);
    // K4.5) remaining weight preps
    prep_wt_kernel<<<256, 256, 0, stream>>>(proj_l_w, wt_proj_l, 256, 256, 256, 256);
    prep_wt_kernel<<<48, 256, 0, stream>>>(qkv_c_w, wt_qkv_c, 49, 147, 64, 192);
    prep_wt_kernel<<<16, 256, 0, stream>>>(proj_c_w, wt_proj_c, 49, 49, 64, 64);
    prep_wt_kernel<<<512, 256, 0, stream>>>(proj_w, wt_final, 512, 256, 512, 256);
    // K5) proj_local: [50176,256] @ [256,256], pitch 256
    gemm_mfma_kernel<<<dim3(4, 392), 256, 0, stream>>>(
        attnL, nullptr, 256, wt_proj_l, proj_l_b, localOut, nullptr, 50176, 256, 256, 256);
    // K6a) pc_dense = per-b transpose of patches
    transpose_bf16_kernel<<<dim3(4, 196, BB), 256, 0, stream>>>(patches, pc_dense, 12544, 256);
    // K6b) zero-pad rows 49 -> 64
    pad49_kernel<<<65536, 256, 0, stream>>>(
        (const unsigned short*)pc_dense, (unsigned short*)pc_pad);
    // K7) qkv_cross: [262144,64pad] @ [64,147] -> qkvc pitch 160
    gemm_mfma_kernel<<<dim3(3, 2048), 256, 0, stream>>>(
        pc_pad, nullptr, 64, wt_qkv_c, qkv_c_b, qkvc, nullptr, 262144, 147, 64, 160);
    // K8) cross attention (reads pitch 160)
    cross_attn_mfma_kernel<<<1024, 256, 0, stream>>>(qkvc, crossAttn);
    // K9) proj_cross: [262144,64pad] @ [64,49] -> dense [262144][49] (scalar path)
    gemm_mfma_kernel<<<dim3(1, 2048), 256, 0, stream>>>(
        crossAttn, nullptr, 64, wt_proj_c, proj_c_b, crossProj, nullptr, 262144, 49, 64, 49);
    // K10) crossT = per-b transpose back
    transpose_bf16_kernel<<<dim3(196, 4, BB), 256, 0, stream>>>(crossProj, crossT, 256, 12544);
    // K11) final: concat[localOut|crossT] @ proj_w -> out0 fp32 BCHW
    gemm_mfma_kernel<<<dim3(4, 392), 256, 0, stream>>>(
        localOut, crossT, 256, wt_final, nullptr, nullptr, out0, 50176, 256, 512, 256);
}

// Round 12
// 357.426 us; speedup vs baseline: 4.7396x; 1.0580x over previous
//
#include <hip/hip_runtime.h>
#include <hip/hip_bf16.h>

// Problem geometry (fixed by the reference):
// B=4, C=256, H=W=112, ps=7, N=49, nP=256 windows/batch, NH=8, d=32.
// Inputs fp32. d_out is FP32: [out | shortcut], each (B,C,H,W).

#define PS 7
#define NWIN_N 49
#define CH 256
#define HH 112
#define WW 112
#define BB 4
#define NHEAD 8
#define HD 32

static constexpr size_t ELEMS = (size_t)BB * CH * HH * WW;      // 12,845,056
static constexpr size_t SZ    = ELEMS * 2;                      // 25,690,112 B (one bf16 plane)

typedef __attribute__((ext_vector_type(8))) short short8;
typedef __attribute__((ext_vector_type(4))) float f32x4;

static __device__ __forceinline__ unsigned short bf16_bits(float v) {
    __hip_bfloat16 h = __float2bfloat16(v);
    return *reinterpret_cast<unsigned short*>(&h);
}

// ---------------------------------------------------------------------------
// 1) LayerNorm over C + window partition -> patches[(b*256+p)*49+i][c] (bf16)
// ---------------------------------------------------------------------------
__global__ __launch_bounds__(256) void ln_partition_kernel(
    const float* __restrict__ x, const float* __restrict__ gamma,
    const float* __restrict__ beta, __hip_bfloat16* __restrict__ patches)
{
    int blk = blockIdx.x;
    int seg = blk % 7;
    int bh = blk / 7;
    int h = bh % HH, b = bh / HH;
    int w0 = seg * 16;
    int tid = threadIdx.x;

    __shared__ float X[256][17];
    __shared__ float mus[16], rstds[16];

    #pragma unroll
    for (int l = 0; l < 16; ++l) {
        int idx = l * 256 + tid;
        int c = idx >> 4, wl = idx & 15;
        X[c][wl] = x[((size_t)(b * CH + c) * HH + h) * WW + w0 + wl];
    }
    __syncthreads();

    if (tid < 16) {
        float s = 0.f, ss = 0.f;
        for (int c = 0; c < 256; ++c) { float v = X[c][tid]; s += v; ss += v * v; }
        float mu = s * (1.f / 256.f);
        float var = ss * (1.f / 256.f) - mu * mu;
        mus[tid] = mu;
        rstds[tid] = rsqrtf(var + 1e-5f);
    }
    __syncthreads();

    int c = tid;
    float g = gamma[c], be = beta[c];
    int hp = h / PS, r = h - hp * PS;
    #pragma unroll
    for (int wl = 0; wl < 16; ++wl) {
        int w = w0 + wl;
        int wp = w / PS, cc = w - wp * PS;
        int win = (b * 16 + hp) * 16 + wp;
        int i = r * PS + cc;
        float v = (X[c][wl] - mus[wl]) * rstds[wl] * g + be;
        patches[((size_t)win * NWIN_N + i) * CH + c] = __float2bfloat16(v);
    }
}

// ---------------------------------------------------------------------------
// 2) shortcut: fp32 -> fp32 copy (float4)
// ---------------------------------------------------------------------------
__global__ __launch_bounds__(256) void copy_f32_kernel(
    const float* __restrict__ x, float* __restrict__ out)
{
    size_t i = ((size_t)blockIdx.x * 256 + threadIdx.x) * 4;
    *(float4*)(out + i) = *(const float4*)(x + i);
}

// ---------------------------------------------------------------------------
// prep: W fp32 [Kreal][N] -> Wt bf16 [Npad][Kpad] k-major, zero padded
// ---------------------------------------------------------------------------
__global__ __launch_bounds__(256) void prep_wt_kernel(
    const float* __restrict__ W, unsigned short* __restrict__ Wt,
    int Kreal, int N, int Kpad, int Npad)
{
    int idx = blockIdx.x * 256 + threadIdx.x;
    if (idx >= Npad * Kpad) return;
    int n = idx / Kpad, k = idx - n * Kpad;
    float v = (n < N && k < Kreal) ? W[(size_t)k * N + n] : 0.f;
    Wt[idx] = bf16_bits(v);
}

// ---------------------------------------------------------------------------
// prep for qkv_cross with aligned-segment remap: out col n -> src col s:
//   n in [0,49)    -> s = n        (q)
//   n in [56,105)  -> s = n - 7    (k)
//   n in [112,161) -> s = n - 14   (v)
//   else zero. Wt [192][64] k-major.
// ---------------------------------------------------------------------------
__global__ __launch_bounds__(256) void prep_wt_qkvc_kernel(
    const float* __restrict__ W, unsigned short* __restrict__ Wt)
{
    int idx = blockIdx.x * 256 + threadIdx.x;
    if (idx >= 192 * 64) return;
    int n = idx >> 6, k = idx & 63;
    int s = -1;
    if (n < 49) s = n;
    else if (n >= 56 && n < 105) s = n - 7;
    else if (n >= 112 && n < 161) s = n - 14;
    float v = (s >= 0 && k < 49) ? W[(size_t)k * 147 + s] : 0.f;
    Wt[idx] = bf16_bits(v);
}

__global__ __launch_bounds__(192) void prep_bias_c_kernel(
    const float* __restrict__ b, float* __restrict__ bc)
{
    int n = threadIdx.x;   // < 192
    int s = -1;
    if (n < 49) s = n;
    else if (n >= 56 && n < 105) s = n - 7;
    else if (n >= 112 && n < 161) s = n - 14;
    bc[n] = (s >= 0) ? b[s] : 0.f;
}

// ---------------------------------------------------------------------------
// bias prep: rpb [169][8] -> biasb[8][64][64] fp32 padded.
// ---------------------------------------------------------------------------
__global__ __launch_bounds__(256) void bias_prep_kernel(
    const float* __restrict__ rpb, float* __restrict__ biasb)
{
    int idx = blockIdx.x * 256 + threadIdx.x;   // < 32768
    int head = idx >> 12;
    int rem = idx & 4095;
    int i = rem >> 6, j = rem & 63;
    float v;
    if (j >= NWIN_N) v = -1e9f;
    else if (i >= NWIN_N) v = 0.f;
    else {
        int ri = i / 7, ci = i - ri * 7;
        int rj = j / 7, cj = j - rj * 7;
        v = rpb[((ri - rj + 6) * 13 + (ci - cj + 6)) * NHEAD + head];
    }
    biasb[idx] = v;
}

// ---------------------------------------------------------------------------
// pad49: src [M][49] -> dst [M][64] zero-padded (M = 262144)
// ---------------------------------------------------------------------------
__global__ __launch_bounds__(256) void pad49_kernel(
    const unsigned short* __restrict__ src, unsigned short* __restrict__ dst)
{
    size_t idx = (size_t)blockIdx.x * 256 + threadIdx.x;   // < 262144*64
    int t = idx & 63;
    size_t m = idx >> 6;
    dst[idx] = (t < 49) ? src[m * 49 + t] : (unsigned short)0;
}

// ---------------------------------------------------------------------------
// Unified MFMA GEMM: C[M][N] = concat(A1[.][K1], A2[.][K-K1]) @ Wt^T + bias
// BM=128, BN=64, BK=64; 256 thr = 4 waves (2x2); 16x16x32 MFMA.
// XCD-chunked tile swizzle (requires ntiles % 8 == 0, all call sites comply).
// ---------------------------------------------------------------------------
__global__ __launch_bounds__(256) void gemm_mfma_kernel(
    const __hip_bfloat16* __restrict__ A1p, const __hip_bfloat16* __restrict__ A2p,
    int K1, const unsigned short* __restrict__ Wt, const float* __restrict__ bias,
    __hip_bfloat16* __restrict__ Cb, float* __restrict__ Cf,
    int M, int N, int K, int pitchN)
{
    __shared__ __align__(16) unsigned short Alds[128][72];
    __shared__ __align__(16) unsigned short Wlds[64][72];
    const unsigned short* A1 = (const unsigned short*)A1p;
    const unsigned short* A2 = (const unsigned short*)A2p;

    const int nb = gridDim.x;
    const int ntiles = nb * gridDim.y;
    const int bid = blockIdx.y * nb + blockIdx.x;
    const int chunk = ntiles >> 3;
    const int tile = (bid & 7) * chunk + (bid >> 3);
    const int m0 = (tile / nb) * 128, n0 = (tile % nb) * 64;

    const int tid = threadIdx.x, lane = tid & 63, wave = tid >> 6;
    const int wm = wave >> 1, wn = wave & 1;
    const int lr = lane & 15, lk = lane >> 4;

    f32x4 acc[4][2];
    #pragma unroll
    for (int i = 0; i < 4; ++i)
        #pragma unroll
        for (int j = 0; j < 2; ++j) acc[i][j] = (f32x4){0.f, 0.f, 0.f, 0.f};

    for (int k0 = 0; k0 < K; k0 += 64) {
        #pragma unroll
        for (int i = 0; i < 4; ++i) {
            int s = tid + 256 * i;
            int row = s >> 3, c8 = (s & 7) * 8;
            int k = k0 + c8;
            const unsigned short* src = (k < K1)
                ? A1 + (size_t)(m0 + row) * K1 + k
                : A2 + (size_t)(m0 + row) * (K - K1) + (k - K1);
            *(short8*)&Alds[row][c8] = *(const short8*)src;
        }
        #pragma unroll
        for (int i = 0; i < 2; ++i) {
            int s = tid + 256 * i;
            int row = s >> 3, c8 = (s & 7) * 8;
            *(short8*)&Wlds[row][c8] =
                *(const short8*)(Wt + (size_t)(n0 + row) * K + k0 + c8);
        }
        __syncthreads();
        #pragma unroll
        for (int kk = 0; kk < 64; kk += 32) {
            short8 a[4], w[2];
            #pragma unroll
            for (int mi = 0; mi < 4; ++mi)
                a[mi] = *(const short8*)&Alds[wm * 64 + mi * 16 + lr][kk + lk * 8];
            #pragma unroll
            for (int nj = 0; nj < 2; ++nj)
                w[nj] = *(const short8*)&Wlds[wn * 32 + nj * 16 + lr][kk + lk * 8];
            #pragma unroll
            for (int mi = 0; mi < 4; ++mi)
                #pragma unroll
                for (int nj = 0; nj < 2; ++nj)
                    acc[mi][nj] = __builtin_amdgcn_mfma_f32_16x16x32_bf16(
                        a[mi], w[nj], acc[mi][nj], 0, 0, 0);
        }
        __syncthreads();
    }

    if (Cb) {
        if ((pitchN & 7) == 0) {
            #pragma unroll
            for (int nj = 0; nj < 2; ++nj) {
                int n = n0 + wn * 32 + nj * 16 + lr;
                float bv = (bias && n < N) ? bias[n] : 0.f;
                #pragma unroll
                for (int mi = 0; mi < 4; ++mi)
                    #pragma unroll
                    for (int r = 0; r < 4; ++r)
                        Alds[wm * 64 + mi * 16 + lk * 4 + r][wn * 32 + nj * 16 + lr] =
                            bf16_bits(acc[mi][nj][r] + bv);
            }
            __syncthreads();
            #pragma unroll
            for (int i = 0; i < 4; ++i) {
                int s = tid + 256 * i;
                int row = s >> 3, c8 = (s & 7) * 8;
                if (n0 + c8 + 8 <= pitchN)
                    *(short8*)((unsigned short*)Cb + (size_t)(m0 + row) * pitchN + n0 + c8) =
                        *(const short8*)&Alds[row][c8];
            }
        } else {
            #pragma unroll
            for (int nj = 0; nj < 2; ++nj) {
                int n = n0 + wn * 32 + nj * 16 + lr;
                if (n >= N) continue;
                float bv = bias ? bias[n] : 0.f;
                #pragma unroll
                for (int mi = 0; mi < 4; ++mi) {
                    #pragma unroll
                    for (int r = 0; r < 4; ++r) {
                        int m = m0 + wm * 64 + mi * 16 + lk * 4 + r;
                        ((unsigned short*)Cb)[(size_t)m * pitchN + n] =
                            bf16_bits(acc[mi][nj][r] + bv);
                    }
                }
            }
        }
    } else {
        #pragma unroll
        for (int mi = 0; mi < 4; ++mi) {
            #pragma unroll
            for (int r = 0; r < 4; ++r) {
                int m = m0 + wm * 64 + mi * 16 + lk * 4 + r;
                int b = m / 12544, rem = m - b * 12544;
                int p = rem / 49, t = rem - p * 49;
                int h = (p >> 4) * 7 + t / 7, w = (p & 15) * 7 + (t % 7);
                size_t ob = ((size_t)(b * 256) * HH + h) * WW + w;
                #pragma unroll
                for (int nj = 0; nj < 2; ++nj) {
                    int ch = n0 + wn * 32 + nj * 16 + lr;
                    Cf[ob + (size_t)ch * (HH * WW)] = acc[mi][nj][r];
                }
            }
        }
    }
}

// ---------------------------------------------------------------------------
// 4) local windowed attention, MFMA. One wave per (win, head).
// ---------------------------------------------------------------------------
__global__ __launch_bounds__(64) void local_attn_mfma_kernel(
    const __hip_bfloat16* __restrict__ qkv,   // [50176][768] q|k|v
    const float* __restrict__ biasb,          // [8][64][64] fp32 padded
    __hip_bfloat16* __restrict__ outp)        // [50176][256]
{
    __shared__ __align__(16) unsigned short VT_lds[32][72];
    __shared__ __align__(16) unsigned short P_lds[16][72];

    const int win  = blockIdx.x >> 3;
    const int head = blockIdx.x & 7;
    const int lane = threadIdx.x;
    const int lr = lane & 15, lk = lane >> 4;
    const unsigned short* q16 = (const unsigned short*)qkv;
    const size_t rowbase = (size_t)win * NWIN_N;
    const float scale = 0.17677669529663687f;   // 32^-0.5

    for (int t = 0; t < 32; ++t) {
        int idx = lane + 64 * t;
        int j = idx >> 5, d = idx & 31;
        unsigned short v = 0;
        if (j < NWIN_N) v = q16[(rowbase + j) * 768 + 512 + head * HD + d];
        VT_lds[d][j] = v;
    }

    short8 kf[4], qf[4];
    #pragma unroll
    for (int jt = 0; jt < 4; ++jt) {
        int j = jt * 16 + lr;
        short8 f = *(const short8*)(q16 + (rowbase + j) * 768 + 256 + head * HD + lk * 8);
        if (j >= NWIN_N) {
            #pragma unroll
            for (int e = 0; e < 8; ++e) f[e] = 0;
        }
        kf[jt] = f;
    }
    #pragma unroll
    for (int it = 0; it < 4; ++it) {
        int i = it * 16 + lr;
        qf[it] = *(const short8*)(q16 + (rowbase + i) * 768 + head * HD + lk * 8);
    }
    __syncthreads();

    #pragma unroll
    for (int it = 0; it < 4; ++it) {
        const int i = it * 16 + lr;
        f32x4 sacc[4];
        #pragma unroll
        for (int jt = 0; jt < 4; ++jt) {
            f32x4 z = (f32x4){0.f, 0.f, 0.f, 0.f};
            sacc[jt] = __builtin_amdgcn_mfma_f32_16x16x32_bf16(kf[jt], qf[it], z, 0, 0, 0);
        }
        const float* brow = biasb + head * 4096 + i * 64;
        float sv[4][4];
        float mt = -1e30f;
        #pragma unroll
        for (int jt = 0; jt < 4; ++jt) {
            float4 bv = *(const float4*)&brow[jt * 16 + lk * 4];
            sv[jt][0] = sacc[jt][0] * scale + bv.x;
            sv[jt][1] = sacc[jt][1] * scale + bv.y;
            sv[jt][2] = sacc[jt][2] * scale + bv.z;
            sv[jt][3] = sacc[jt][3] * scale + bv.w;
            #pragma unroll
            for (int r = 0; r < 4; ++r) mt = fmaxf(mt, sv[jt][r]);
        }
        mt = fmaxf(mt, __shfl_xor(mt, 16, 64));
        mt = fmaxf(mt, __shfl_xor(mt, 32, 64));
        float psum = 0.f;
        #pragma unroll
        for (int jt = 0; jt < 4; ++jt) {
            float p0 = __expf(sv[jt][0] - mt);
            float p1 = __expf(sv[jt][1] - mt);
            float p2 = __expf(sv[jt][2] - mt);
            float p3 = __expf(sv[jt][3] - mt);
            psum += (p0 + p1) + (p2 + p3);
            uint2 wv;
            wv.x = (unsigned)bf16_bits(p0) | ((unsigned)bf16_bits(p1) << 16);
            wv.y = (unsigned)bf16_bits(p2) | ((unsigned)bf16_bits(p3) << 16);
            *(uint2*)&P_lds[lr][jt * 16 + lk * 4] = wv;
        }
        psum += __shfl_xor(psum, 16, 64);
        psum += __shfl_xor(psum, 32, 64);
        __syncthreads();

        f32x4 oacc[2];
        oacc[0] = (f32x4){0.f, 0.f, 0.f, 0.f};
        oacc[1] = (f32x4){0.f, 0.f, 0.f, 0.f};
        #pragma unroll
        for (int kst = 0; kst < 2; ++kst) {
            short8 bfv = *(const short8*)&P_lds[lr][kst * 32 + lk * 8];
            #pragma unroll
            for (int dt = 0; dt < 2; ++dt) {
                short8 af = *(const short8*)&VT_lds[dt * 16 + lr][kst * 32 + lk * 8];
                oacc[dt] = __builtin_amdgcn_mfma_f32_16x16x32_bf16(af, bfv, oacc[dt], 0, 0, 0);
            }
        }
        if (i < NWIN_N) {
            float inv = 1.f / psum;
            unsigned short* orow = (unsigned short*)outp + (rowbase + i) * CH + head * HD;
            #pragma unroll
            for (int dt = 0; dt < 2; ++dt) {
                uint2 wv;
                wv.x = (unsigned)bf16_bits(oacc[dt][0] * inv)
                     | ((unsigned)bf16_bits(oacc[dt][1] * inv) << 16);
                wv.y = (unsigned)bf16_bits(oacc[dt][2] * inv)
                     | ((unsigned)bf16_bits(oacc[dt][3] * inv) << 16);
                *(uint2*)&orow[dt * 16 + lk * 4] = wv;
            }
        }
        __syncthreads();
    }
}

// ---------------------------------------------------------------------------
// 5) cross-channel attention, MFMA flash. qkvc pitch 168: q@0, k@56, v@112,
// all 16B-aligned; gap cols are exact zeros (built by remapped GEMM).
// Vectorized K/V staging (7x short8 + zero), V^T via in-LDS transpose,
// P double-buffered by it-parity, packed uint2 output stores.
// ---------------------------------------------------------------------------
__global__ __launch_bounds__(256) void cross_attn_mfma_kernel(
    const __hip_bfloat16* __restrict__ qkv,   // [262144][168]
    __hip_bfloat16* __restrict__ outp)        // [262144][64] padded
{
    __shared__ __align__(16) unsigned short K_lds[64][72];
    __shared__ __align__(16) unsigned short VT_lds[64][72];
    __shared__ __align__(16) unsigned short P_lds[2][64][72]; // [0] doubles as V-scratch

    const int bc = blockIdx.x;
    const size_t base = (size_t)bc * 256;
    const int tid  = threadIdx.x;
    const int lane = tid & 63;
    const int wave = tid >> 6;
    const int i0w  = wave * 64;
    const int lr   = lane & 15;
    const int lk   = lane >> 4;
    const int prow = wave * 16 + lr;

    const unsigned short* q16 = (const unsigned short*)qkv;
    const float inv7 = 1.f / 7.f;   // 49^-0.5
    const short8 zf = (short8){0, 0, 0, 0, 0, 0, 0, 0};

    // q fragments: aligned vector loads (cols 49..55 are zeros; k0=56 -> 0)
    short8 qf[4][2];
    #pragma unroll
    for (int it = 0; it < 4; ++it) {
        const unsigned short* qrow = q16 + (base + i0w + it * 16 + lr) * 168;
        #pragma unroll
        for (int kst = 0; kst < 2; ++kst) {
            int k0 = lk * 8 + kst * 32;
            qf[it][kst] = (k0 <= 48) ? *(const short8*)(qrow + k0) : zf;
        }
    }

    float m_run[4], l_run[4];
    f32x4 acc_o[4][4];   // [dt][it]
    #pragma unroll
    for (int it = 0; it < 4; ++it) { m_run[it] = -1e30f; l_run[it] = 0.f; }
    #pragma unroll
    for (int dt = 0; dt < 4; ++dt)
        #pragma unroll
        for (int it = 0; it < 4; ++it) acc_o[dt][it] = (f32x4){0.f, 0.f, 0.f, 0.f};

    for (int jt4 = 0; jt4 < 4; ++jt4) {
        const int j0 = jt4 * 64;
        // ---- vectorized staging: K -> K_lds, V -> P_lds[0] (scratch) ----
        {
            const int jr = tid >> 3, c8 = (tid & 7) * 8;
            #pragma unroll
            for (int h = 0; h < 2; ++h) {
                int jj = jr + h * 32;
                const unsigned short* row = q16 + (base + j0 + jj) * 168;
                *(short8*)&K_lds[jj][c8]    = (c8 <= 48) ? *(const short8*)(row + 56 + c8) : zf;
                *(short8*)&P_lds[0][jj][c8] = (c8 <= 48) ? *(const short8*)(row + 112 + c8) : zf;
            }
        }
        __syncthreads();
        // ---- in-LDS transpose: VT[d][j] = Vscr[j][d] (rows d>=49 auto-zero) ----
        {
            const int jj = tid & 63, dg = tid >> 6;
            #pragma unroll
            for (int e = 0; e < 16; ++e) {
                int d = dg * 16 + e;
                VT_lds[d][jj] = P_lds[0][jj][d];
            }
        }
        __syncthreads();

        #pragma unroll
        for (int it = 0; it < 4; ++it) {
            unsigned short* prowp = &P_lds[it & 1][prow][0];
            // ---- S^T = mfma(K, Q) ----
            f32x4 sacc[4];
            #pragma unroll
            for (int jt = 0; jt < 4; ++jt) sacc[jt] = (f32x4){0.f, 0.f, 0.f, 0.f};
            #pragma unroll
            for (int kst = 0; kst < 2; ++kst) {
                #pragma unroll
                for (int jt = 0; jt < 4; ++jt) {
                    short8 af = *(const short8*)&K_lds[jt * 16 + lr][lk * 8 + kst * 32];
                    sacc[jt] = __builtin_amdgcn_mfma_f32_16x16x32_bf16(
                        af, qf[it][kst], sacc[jt], 0, 0, 0);
                }
            }
            // ---- online softmax over j ----
            float mt = -1e30f;
            #pragma unroll
            for (int jt = 0; jt < 4; ++jt)
                #pragma unroll
                for (int r = 0; r < 4; ++r) mt = fmaxf(mt, sacc[jt][r]);
            mt = fmaxf(mt, __shfl_xor(mt, 16, 64));
            mt = fmaxf(mt, __shfl_xor(mt, 32, 64));
            float mnew = fmaxf(m_run[it], mt * inv7);
            float corr = __expf(m_run[it] - mnew);
            m_run[it] = mnew;
            l_run[it] *= corr;
            #pragma unroll
            for (int dt = 0; dt < 4; ++dt)
                #pragma unroll
                for (int r = 0; r < 4; ++r) acc_o[dt][it][r] *= corr;

            float psum = 0.f;
            #pragma unroll
            for (int jt = 0; jt < 4; ++jt) {
                float p0 = __expf(sacc[jt][0] * inv7 - mnew);
                float p1 = __expf(sacc[jt][1] * inv7 - mnew);
                float p2 = __expf(sacc[jt][2] * inv7 - mnew);
                float p3 = __expf(sacc[jt][3] * inv7 - mnew);
                psum += (p0 + p1) + (p2 + p3);
                uint2 wv;
                wv.x = (unsigned)bf16_bits(p0) | ((unsigned)bf16_bits(p1) << 16);
                wv.y = (unsigned)bf16_bits(p2) | ((unsigned)bf16_bits(p3) << 16);
                *(uint2*)(prowp + jt * 16 + lk * 4) = wv;
            }
            psum += __shfl_xor(psum, 16, 64);
            psum += __shfl_xor(psum, 32, 64);
            l_run[it] += psum;

            // ---- PV fused: O^T += mfma(V^T, P) (wave-local P rows) ----
            #pragma unroll
            for (int kst = 0; kst < 2; ++kst) {
                short8 bfv = *(const short8*)(prowp + kst * 32 + lk * 8);
                #pragma unroll
                for (int dt = 0; dt < 4; ++dt) {
                    short8 af = *(const short8*)&VT_lds[dt * 16 + lr][kst * 32 + lk * 8];
                    acc_o[dt][it] = __builtin_amdgcn_mfma_f32_16x16x32_bf16(
                        af, bfv, acc_o[dt][it], 0, 0, 0);
                }
            }
        }
        __syncthreads();   // protect K/VT/P0 before next tile's staging
    }

    #pragma unroll
    for (int it = 0; it < 4; ++it) {
        float inv = 1.f / l_run[it];
        unsigned short* orow = (unsigned short*)outp + (base + i0w + it * 16 + lr) * 64;
        #pragma unroll
        for (int dt = 0; dt < 4; ++dt) {
            uint2 wv;
            wv.x = (unsigned)bf16_bits(acc_o[dt][it][0] * inv)
                 | ((unsigned)bf16_bits(acc_o[dt][it][1] * inv) << 16);
            wv.y = (unsigned)bf16_bits(acc_o[dt][it][2] * inv)
                 | ((unsigned)bf16_bits(acc_o[dt][it][3] * inv) << 16);
            *(uint2*)&orow[dt * 16 + lk * 4] = wv;
        }
    }
}

// ---------------------------------------------------------------------------
// 6) batched 2D transpose: src[b][R][Cc] -> dst[b][Cc][R]; grid (Cc/64,R/64,B)
// ---------------------------------------------------------------------------
__global__ __launch_bounds__(256) void transpose_bf16_kernel(
    const __hip_bfloat16* __restrict__ src, __hip_bfloat16* __restrict__ dst,
    int R, int Cc)
{
    __shared__ __hip_bfloat16 T[64][66];
    int b = blockIdx.z;
    int r0 = blockIdx.y * 64, c0 = blockIdx.x * 64;
    const __hip_bfloat16* s = src + (size_t)b * R * Cc;
    __hip_bfloat16* d = dst + (size_t)b * R * Cc;
    int tid = threadIdx.x;
    int lr = tid >> 6, lc = tid & 63;

    #pragma unroll
    for (int l = 0; l < 16; ++l) {
        int rr = l * 4 + lr;
        T[rr][lc] = s[(size_t)(r0 + rr) * Cc + c0 + lc];
    }
    __syncthreads();
    #pragma unroll
    for (int l = 0; l < 16; ++l) {
        int cc = l * 4 + lr;
        d[(size_t)(c0 + cc) * R + r0 + lc] = T[lc][cc];
    }
}

// ---------------------------------------------------------------------------
__global__ void ws_marker_kernel(float* __restrict__ out0)
{
    if (threadIdx.x == 0) out0[0] = 777.0f;
}

// ---------------------------------------------------------------------------
extern "C" void kernel_launch(void* const* d_in, const int* in_sizes, int n_in,
                              void* d_out, int out_size, void* d_ws, size_t ws_size,
                              hipStream_t stream)
{
    const float* x        = (const float*)d_in[0];
    const float* gamma    = (const float*)d_in[1];
    const float* beta     = (const float*)d_in[2];
    const float* qkv_l_w  = (const float*)d_in[3];
    const float* qkv_l_b  = (const float*)d_in[4];
    const float* proj_l_w = (const float*)d_in[5];
    const float* proj_l_b = (const float*)d_in[6];
    const float* rpb      = (const float*)d_in[7];
    const float* qkv_c_w  = (const float*)d_in[8];
    const float* qkv_c_b  = (const float*)d_in[9];
    const float* proj_c_w = (const float*)d_in[10];
    const float* proj_c_b = (const float*)d_in[11];
    const float* proj_w   = (const float*)d_in[12];

    float* out0 = (float*)d_out;
    float* out1 = out0 + ELEMS;

    copy_f32_kernel<<<(int)(ELEMS / 1024), 256, 0, stream>>>(x, out1);

    char* ws = (char*)d_ws;
    if (ws_size < 6 * SZ) {
        ws_marker_kernel<<<1, 64, 0, stream>>>(out0);
        return;
    }

    const size_t P = SZ;
    // plane/lifetime map (re-verified):
    //   localOut  [0,1P)                    K5 W -> K11 R
    //   wt_qkv_l  [0, 393KB)                K0 W -> K3 R (dead before K5)
    //   biasb     [0.5MB, 0.63MB)           K0b W -> K4 R
    //   patches   [1P,2P)                   K1 W -> K6a R
    //   qkv_l     [2P,5P)                   K3 W -> K4 R
    //   attnL     [5P,6P)                   K4 W -> K5 R
    //   G weights [4P+11MB, 4P+14.2MB)      K4.5 W -> K11 R (inside dead qkv_l;
    //                                        clears qkvc end 4P+10.5MB & pc_pad 4P+17.9MB)
    //   pc_dense  [2P,3P)                   K6a W -> K6b R
    //   pc_pad    [6P-33.5MB, 6P)           K6b W -> K7 R
    //   qkvc      [1P, 1P+88MB=4P+10.5MB)   K7 W -> K8 R (pitch 168)
    //   crossAttn = pc_pad                  K8 W -> K9 R
    //   crossProj [1P, 1P+25.7MB)           K9 W -> K10 R
    //   crossT    [2P,3P)                   K10 W -> K11 R
    __hip_bfloat16* localOut  = (__hip_bfloat16*)(ws + 0 * P);
    unsigned short* wt_qkv_l  = (unsigned short*)(ws + 0 * P);
    float*          biasb     = (float*)(ws + 0 * P + 0x80000);
    __hip_bfloat16* patches   = (__hip_bfloat16*)(ws + 1 * P);
    __hip_bfloat16* qkv_l     = (__hip_bfloat16*)(ws + 2 * P);
    __hip_bfloat16* attnL     = (__hip_bfloat16*)(ws + 5 * P);
    char*           G         = ws + 4 * P + 0xB00000;
    unsigned short* wt_proj_l = (unsigned short*)(G + 0x000000);
    unsigned short* wt_qkv_c  = (unsigned short*)(G + 0x080000);
    unsigned short* wt_proj_c = (unsigned short*)(G + 0x100000);
    unsigned short* wt_final  = (unsigned short*)(G + 0x180000);
    float*          biasc     = (float*)(G + 0x300000);
    __hip_bfloat16* pc_dense  = (__hip_bfloat16*)(ws + 2 * P);
    __hip_bfloat16* pc_pad    = (__hip_bfloat16*)(ws + 6 * P - (size_t)262144 * 64 * 2);
    __hip_bfloat16* qkvc      = (__hip_bfloat16*)(ws + 1 * P);
    __hip_bfloat16* crossAttn = pc_pad;
    __hip_bfloat16* crossProj = (__hip_bfloat16*)(ws + 1 * P);
    __hip_bfloat16* crossT    = (__hip_bfloat16*)(ws + 2 * P);

    // K0) weight prep needed before K3; bias table before K4
    prep_wt_kernel<<<768, 256, 0, stream>>>(qkv_l_w, wt_qkv_l, 256, 768, 256, 768);
    bias_prep_kernel<<<128, 256, 0, stream>>>(rpb, biasb);
    // K1) LN + window partition
    ln_partition_kernel<<<BB * HH * 7, 256, 0, stream>>>(x, gamma, beta, patches);
    // K3) qkv_local: [50176,256] @ [256,768], pitch 768
    gemm_mfma_kernel<<<dim3(12, 392), 256, 0, stream>>>(
        patches, nullptr, 256, wt_qkv_l, qkv_l_b, qkv_l, nullptr, 50176, 768, 256, 768);
    // K4) local attention (MFMA)
    local_attn_mfma_kernel<<<1024 * NHEAD, 64, 0, stream>>>(qkv_l, biasb, attnL);
    // K4.5) remaining weight preps
    prep_wt_kernel<<<256, 256, 0, stream>>>(proj_l_w, wt_proj_l, 256, 256, 256, 256);
    prep_wt_qkvc_kernel<<<48, 256, 0, stream>>>(qkv_c_w, wt_qkv_c);
    prep_bias_c_kernel<<<1, 192, 0, stream>>>(qkv_c_b, biasc);
    prep_wt_kernel<<<16, 256, 0, stream>>>(proj_c_w, wt_proj_c, 49, 49, 64, 64);
    prep_wt_kernel<<<512, 256, 0, stream>>>(proj_w, wt_final, 512, 256, 512, 256);
    // K5) proj_local: [50176,256] @ [256,256], pitch 256
    gemm_mfma_kernel<<<dim3(4, 392), 256, 0, stream>>>(
        attnL, nullptr, 256, wt_proj_l, proj_l_b, localOut, nullptr, 50176, 256, 256, 256);
    // K6a) pc_dense = per-b transpose of patches
    transpose_bf16_kernel<<<dim3(4, 196, BB), 256, 0, stream>>>(patches, pc_dense, 12544, 256);
    // K6b) zero-pad rows 49 -> 64
    pad49_kernel<<<65536, 256, 0, stream>>>(
        (const unsigned short*)pc_dense, (unsigned short*)pc_pad);
    // K7) qkv_cross: [262144,64pad] @ [64,161 remapped] -> qkvc pitch 168
    gemm_mfma_kernel<<<dim3(3, 2048), 256, 0, stream>>>(
        pc_pad, nullptr, 64, wt_qkv_c, biasc, qkvc, nullptr, 262144, 161, 64, 168);
    // K8) cross attention (reads pitch 168, aligned segments)
    cross_attn_mfma_kernel<<<1024, 256, 0, stream>>>(qkvc, crossAttn);
    // K9) proj_cross: [262144,64pad] @ [64,49] -> dense [262144][49]
    gemm_mfma_kernel<<<dim3(1, 2048), 256, 0, stream>>>(
        crossAttn, nullptr, 64, wt_proj_c, proj_c_b, crossProj, nullptr, 262144, 49, 64, 49);
    // K10) crossT = per-b transpose back
    transpose_bf16_kernel<<<dim3(196, 4, BB), 256, 0, stream>>>(crossProj, crossT, 256, 12544);
    // K11) final: concat[localOut|crossT] @ proj_w -> out0 fp32 BCHW
    gemm_mfma_kernel<<<dim3(4, 392), 256, 0, stream>>>(
        localOut, crossT, 256, wt_final, nullptr, nullptr, out0, 50176, 256, 512, 256);
}

// Round 13
// 343.963 us; speedup vs baseline: 4.9251x; 1.0391x over previous
//
#include <hip/hip_runtime.h>
#include <hip/hip_bf16.h>

// Problem geometry (fixed by the reference):
// B=4, C=256, H=W=112, ps=7, N=49, nP=256 windows/batch, NH=8, d=32.
// Inputs fp32. d_out is FP32: [out | shortcut], each (B,C,H,W).

#define PS 7
#define NWIN_N 49
#define CH 256
#define HH 112
#define WW 112
#define BB 4
#define NHEAD 8
#define HD 32

static constexpr size_t ELEMS = (size_t)BB * CH * HH * WW;      // 12,845,056
static constexpr size_t SZ    = ELEMS * 2;                      // 25,690,112 B (one bf16 plane)

typedef __attribute__((ext_vector_type(8))) short short8;
typedef __attribute__((ext_vector_type(4))) float f32x4;

static __device__ __forceinline__ unsigned short bf16_bits(float v) {
    __hip_bfloat16 h = __float2bfloat16(v);
    return *reinterpret_cast<unsigned short*>(&h);
}

// async global->LDS, 16B per lane; lptr must be wave-uniform (lane lands at
// lptr + lane*16), gptr is per-lane. [guide §5 / m97 / m104]
static __device__ __forceinline__ void gload_lds16(const void* g, void* l) {
    __builtin_amdgcn_global_load_lds(
        (const __attribute__((address_space(1))) unsigned int*)g,
        (__attribute__((address_space(3))) unsigned int*)l, 16, 0, 0);
}

// ---------------------------------------------------------------------------
// 1) LayerNorm over C + window partition -> patches[(b*256+p)*49+i][c] (bf16)
// ---------------------------------------------------------------------------
__global__ __launch_bounds__(256) void ln_partition_kernel(
    const float* __restrict__ x, const float* __restrict__ gamma,
    const float* __restrict__ beta, __hip_bfloat16* __restrict__ patches)
{
    int blk = blockIdx.x;
    int seg = blk % 7;
    int bh = blk / 7;
    int h = bh % HH, b = bh / HH;
    int w0 = seg * 16;
    int tid = threadIdx.x;

    __shared__ float X[256][17];
    __shared__ float mus[16], rstds[16];

    #pragma unroll
    for (int l = 0; l < 16; ++l) {
        int idx = l * 256 + tid;
        int c = idx >> 4, wl = idx & 15;
        X[c][wl] = x[((size_t)(b * CH + c) * HH + h) * WW + w0 + wl];
    }
    __syncthreads();

    if (tid < 16) {
        float s = 0.f, ss = 0.f;
        for (int c = 0; c < 256; ++c) { float v = X[c][tid]; s += v; ss += v * v; }
        float mu = s * (1.f / 256.f);
        float var = ss * (1.f / 256.f) - mu * mu;
        mus[tid] = mu;
        rstds[tid] = rsqrtf(var + 1e-5f);
    }
    __syncthreads();

    int c = tid;
    float g = gamma[c], be = beta[c];
    int hp = h / PS, r = h - hp * PS;
    #pragma unroll
    for (int wl = 0; wl < 16; ++wl) {
        int w = w0 + wl;
        int wp = w / PS, cc = w - wp * PS;
        int win = (b * 16 + hp) * 16 + wp;
        int i = r * PS + cc;
        float v = (X[c][wl] - mus[wl]) * rstds[wl] * g + be;
        patches[((size_t)win * NWIN_N + i) * CH + c] = __float2bfloat16(v);
    }
}

// ---------------------------------------------------------------------------
// 2) shortcut: fp32 -> fp32 copy (float4)
// ---------------------------------------------------------------------------
__global__ __launch_bounds__(256) void copy_f32_kernel(
    const float* __restrict__ x, float* __restrict__ out)
{
    size_t i = ((size_t)blockIdx.x * 256 + threadIdx.x) * 4;
    *(float4*)(out + i) = *(const float4*)(x + i);
}

// ---------------------------------------------------------------------------
// prep: W fp32 [Kreal][N] -> Wt bf16 [Npad][Kpad] k-major, zero padded
// ---------------------------------------------------------------------------
__global__ __launch_bounds__(256) void prep_wt_kernel(
    const float* __restrict__ W, unsigned short* __restrict__ Wt,
    int Kreal, int N, int Kpad, int Npad)
{
    int idx = blockIdx.x * 256 + threadIdx.x;
    if (idx >= Npad * Kpad) return;
    int n = idx / Kpad, k = idx - n * Kpad;
    float v = (n < N && k < Kreal) ? W[(size_t)k * N + n] : 0.f;
    Wt[idx] = bf16_bits(v);
}

// ---------------------------------------------------------------------------
// prep for qkv_cross with aligned-segment remap (q@0, k@56, v@112):
// ---------------------------------------------------------------------------
__global__ __launch_bounds__(256) void prep_wt_qkvc_kernel(
    const float* __restrict__ W, unsigned short* __restrict__ Wt)
{
    int idx = blockIdx.x * 256 + threadIdx.x;
    if (idx >= 192 * 64) return;
    int n = idx >> 6, k = idx & 63;
    int s = -1;
    if (n < 49) s = n;
    else if (n >= 56 && n < 105) s = n - 7;
    else if (n >= 112 && n < 161) s = n - 14;
    float v = (s >= 0 && k < 49) ? W[(size_t)k * 147 + s] : 0.f;
    Wt[idx] = bf16_bits(v);
}

__global__ __launch_bounds__(192) void prep_bias_c_kernel(
    const float* __restrict__ b, float* __restrict__ bc)
{
    int n = threadIdx.x;   // < 192
    int s = -1;
    if (n < 49) s = n;
    else if (n >= 56 && n < 105) s = n - 7;
    else if (n >= 112 && n < 161) s = n - 14;
    bc[n] = (s >= 0) ? b[s] : 0.f;
}

// ---------------------------------------------------------------------------
// bias prep: rpb [169][8] -> biasb[8][64][64] fp32 padded.
// ---------------------------------------------------------------------------
__global__ __launch_bounds__(256) void bias_prep_kernel(
    const float* __restrict__ rpb, float* __restrict__ biasb)
{
    int idx = blockIdx.x * 256 + threadIdx.x;   // < 32768
    int head = idx >> 12;
    int rem = idx & 4095;
    int i = rem >> 6, j = rem & 63;
    float v;
    if (j >= NWIN_N) v = -1e9f;
    else if (i >= NWIN_N) v = 0.f;
    else {
        int ri = i / 7, ci = i - ri * 7;
        int rj = j / 7, cj = j - rj * 7;
        v = rpb[((ri - rj + 6) * 13 + (ci - cj + 6)) * NHEAD + head];
    }
    biasb[idx] = v;
}

// ---------------------------------------------------------------------------
// Unified MFMA GEMM: C[M][N] = concat(A1[.][K1], A2[.][K-K1]) @ Wt^T + bias
// BM=128, BN=64, BK=64; 256 thr = 4 waves (2x2); 16x16x32 MFMA.
// Staging via global_load_lds(16B): LINEAR LDS dest (pitch 64) with the
// global SOURCE address pre-swizzled and the same XOR on the read side
// (rule #21: both-sides-or-neither). slot' = slot ^ (row&7).
// XCD-chunked tile swizzle (all call sites have ntiles % 8 == 0).
// ---------------------------------------------------------------------------
__global__ __launch_bounds__(256) void gemm_mfma_kernel(
    const __hip_bfloat16* __restrict__ A1p, const __hip_bfloat16* __restrict__ A2p,
    int K1, const unsigned short* __restrict__ Wt, const float* __restrict__ bias,
    __hip_bfloat16* __restrict__ Cb, float* __restrict__ Cf,
    int M, int N, int K, int pitchN)
{
    __shared__ __align__(16) unsigned short Alds[128 * 64];   // 16 KB, swizzled slots
    __shared__ __align__(16) unsigned short Wlds[64 * 64];    // 8 KB
    const unsigned short* A1 = (const unsigned short*)A1p;
    const unsigned short* A2 = (const unsigned short*)A2p;

    const int nb = gridDim.x;
    const int ntiles = nb * gridDim.y;
    const int bid = blockIdx.y * nb + blockIdx.x;
    const int chunk = ntiles >> 3;
    const int tile = (bid & 7) * chunk + (bid >> 3);
    const int m0 = (tile / nb) * 128, n0 = (tile % nb) * 64;

    const int tid = threadIdx.x, lane = tid & 63, wave = tid >> 6;
    const int wm = wave >> 1, wn = wave & 1;
    const int lr = lane & 15, lk = lane >> 4;

    f32x4 acc[4][2];
    #pragma unroll
    for (int i = 0; i < 4; ++i)
        #pragma unroll
        for (int j = 0; j < 2; ++j) acc[i][j] = (f32x4){0.f, 0.f, 0.f, 0.f};

    for (int k0 = 0; k0 < K; k0 += 64) {
        // ---- A: 1024 slots of 16B; 4 gload_lds per thread ----
        #pragma unroll
        for (int i = 0; i < 4; ++i) {
            int s_lin = i * 256 + tid;               // = dest slot (linear)
            int row = s_lin >> 3, sl = s_lin & 7;
            int c8 = ((sl ^ (row & 7)) << 3);        // pre-swizzled source col
            int k = k0 + c8;
            const unsigned short* src = (k < K1)
                ? A1 + (size_t)(m0 + row) * K1 + k
                : A2 + (size_t)(m0 + row) * (K - K1) + (k - K1);
            gload_lds16(src, Alds + (size_t)(i * 256 + wave * 64) * 8);
        }
        // ---- W: 512 slots; 2 gload_lds per thread ----
        #pragma unroll
        for (int i = 0; i < 2; ++i) {
            int s_lin = i * 256 + tid;
            int row = s_lin >> 3, sl = s_lin & 7;
            int c8 = ((sl ^ (row & 7)) << 3);
            gload_lds16(Wt + (size_t)(n0 + row) * K + k0 + c8,
                        Wlds + (size_t)(i * 256 + wave * 64) * 8);
        }
        __syncthreads();
        #pragma unroll
        for (int kk = 0; kk < 64; kk += 32) {
            short8 a[4], w[2];
            #pragma unroll
            for (int mi = 0; mi < 4; ++mi) {
                int r = wm * 64 + mi * 16 + lr;
                int sl = (kk >> 3) + lk;
                a[mi] = *(const short8*)&Alds[(r << 6) + (((sl) ^ (r & 7)) << 3)];
            }
            #pragma unroll
            for (int nj = 0; nj < 2; ++nj) {
                int r = wn * 32 + nj * 16 + lr;
                int sl = (kk >> 3) + lk;
                w[nj] = *(const short8*)&Wlds[(r << 6) + (((sl) ^ (r & 7)) << 3)];
            }
            #pragma unroll
            for (int mi = 0; mi < 4; ++mi)
                #pragma unroll
                for (int nj = 0; nj < 2; ++nj)
                    acc[mi][nj] = __builtin_amdgcn_mfma_f32_16x16x32_bf16(
                        a[mi], w[nj], acc[mi][nj], 0, 0, 0);
        }
        __syncthreads();
    }

    if (Cb) {
        if ((pitchN & 7) == 0) {
            // stage C tile into Alds (swizzled), then coalesced 16B row stores
            #pragma unroll
            for (int nj = 0; nj < 2; ++nj) {
                int n = n0 + wn * 32 + nj * 16 + lr;
                float bv = (bias && n < N) ? bias[n] : 0.f;
                int col = wn * 32 + nj * 16 + lr;
                #pragma unroll
                for (int mi = 0; mi < 4; ++mi)
                    #pragma unroll
                    for (int r = 0; r < 4; ++r) {
                        int row = wm * 64 + mi * 16 + lk * 4 + r;
                        int idx = (row << 6) + (((col >> 3) ^ (row & 7)) << 3) + (col & 7);
                        Alds[idx] = bf16_bits(acc[mi][nj][r] + bv);
                    }
            }
            __syncthreads();
            #pragma unroll
            for (int i = 0; i < 4; ++i) {
                int s = tid + 256 * i;
                int row = s >> 3, sl = s & 7;
                if (n0 + sl * 8 + 8 <= pitchN)
                    *(short8*)((unsigned short*)Cb + (size_t)(m0 + row) * pitchN + n0 + sl * 8) =
                        *(const short8*)&Alds[(row << 6) + (((sl) ^ (row & 7)) << 3)];
            }
        } else {
            #pragma unroll
            for (int nj = 0; nj < 2; ++nj) {
                int n = n0 + wn * 32 + nj * 16 + lr;
                if (n >= N) continue;
                float bv = bias ? bias[n] : 0.f;
                #pragma unroll
                for (int mi = 0; mi < 4; ++mi) {
                    #pragma unroll
                    for (int r = 0; r < 4; ++r) {
                        int m = m0 + wm * 64 + mi * 16 + lk * 4 + r;
                        ((unsigned short*)Cb)[(size_t)m * pitchN + n] =
                            bf16_bits(acc[mi][nj][r] + bv);
                    }
                }
            }
        }
    } else {
        #pragma unroll
        for (int mi = 0; mi < 4; ++mi) {
            #pragma unroll
            for (int r = 0; r < 4; ++r) {
                int m = m0 + wm * 64 + mi * 16 + lk * 4 + r;
                int b = m / 12544, rem = m - b * 12544;
                int p = rem / 49, t = rem - p * 49;
                int h = (p >> 4) * 7 + t / 7, w = (p & 15) * 7 + (t % 7);
                size_t ob = ((size_t)(b * 256) * HH + h) * WW + w;
                #pragma unroll
                for (int nj = 0; nj < 2; ++nj) {
                    int ch = n0 + wn * 32 + nj * 16 + lr;
                    Cf[ob + (size_t)ch * (HH * WW)] = acc[mi][nj][r];
                }
            }
        }
    }
}

// ---------------------------------------------------------------------------
// 4) local windowed attention, MFMA. One wave per (win, head).
// ---------------------------------------------------------------------------
__global__ __launch_bounds__(64) void local_attn_mfma_kernel(
    const __hip_bfloat16* __restrict__ qkv,   // [50176][768] q|k|v
    const float* __restrict__ biasb,          // [8][64][64] fp32 padded
    __hip_bfloat16* __restrict__ outp)        // [50176][256]
{
    __shared__ __align__(16) unsigned short VT_lds[32][72];
    __shared__ __align__(16) unsigned short P_lds[16][72];

    const int win  = blockIdx.x >> 3;
    const int head = blockIdx.x & 7;
    const int lane = threadIdx.x;
    const int lr = lane & 15, lk = lane >> 4;
    const unsigned short* q16 = (const unsigned short*)qkv;
    const size_t rowbase = (size_t)win * NWIN_N;
    const float scale = 0.17677669529663687f;   // 32^-0.5

    for (int t = 0; t < 32; ++t) {
        int idx = lane + 64 * t;
        int j = idx >> 5, d = idx & 31;
        unsigned short v = 0;
        if (j < NWIN_N) v = q16[(rowbase + j) * 768 + 512 + head * HD + d];
        VT_lds[d][j] = v;
    }

    short8 kf[4], qf[4];
    #pragma unroll
    for (int jt = 0; jt < 4; ++jt) {
        int j = jt * 16 + lr;
        short8 f = *(const short8*)(q16 + (rowbase + j) * 768 + 256 + head * HD + lk * 8);
        if (j >= NWIN_N) {
            #pragma unroll
            for (int e = 0; e < 8; ++e) f[e] = 0;
        }
        kf[jt] = f;
    }
    #pragma unroll
    for (int it = 0; it < 4; ++it) {
        int i = it * 16 + lr;
        qf[it] = *(const short8*)(q16 + (rowbase + i) * 768 + head * HD + lk * 8);
    }
    __syncthreads();

    #pragma unroll
    for (int it = 0; it < 4; ++it) {
        const int i = it * 16 + lr;
        f32x4 sacc[4];
        #pragma unroll
        for (int jt = 0; jt < 4; ++jt) {
            f32x4 z = (f32x4){0.f, 0.f, 0.f, 0.f};
            sacc[jt] = __builtin_amdgcn_mfma_f32_16x16x32_bf16(kf[jt], qf[it], z, 0, 0, 0);
        }
        const float* brow = biasb + head * 4096 + i * 64;
        float sv[4][4];
        float mt = -1e30f;
        #pragma unroll
        for (int jt = 0; jt < 4; ++jt) {
            float4 bv = *(const float4*)&brow[jt * 16 + lk * 4];
            sv[jt][0] = sacc[jt][0] * scale + bv.x;
            sv[jt][1] = sacc[jt][1] * scale + bv.y;
            sv[jt][2] = sacc[jt][2] * scale + bv.z;
            sv[jt][3] = sacc[jt][3] * scale + bv.w;
            #pragma unroll
            for (int r = 0; r < 4; ++r) mt = fmaxf(mt, sv[jt][r]);
        }
        mt = fmaxf(mt, __shfl_xor(mt, 16, 64));
        mt = fmaxf(mt, __shfl_xor(mt, 32, 64));
        float psum = 0.f;
        #pragma unroll
        for (int jt = 0; jt < 4; ++jt) {
            float p0 = __expf(sv[jt][0] - mt);
            float p1 = __expf(sv[jt][1] - mt);
            float p2 = __expf(sv[jt][2] - mt);
            float p3 = __expf(sv[jt][3] - mt);
            psum += (p0 + p1) + (p2 + p3);
            uint2 wv;
            wv.x = (unsigned)bf16_bits(p0) | ((unsigned)bf16_bits(p1) << 16);
            wv.y = (unsigned)bf16_bits(p2) | ((unsigned)bf16_bits(p3) << 16);
            *(uint2*)&P_lds[lr][jt * 16 + lk * 4] = wv;
        }
        psum += __shfl_xor(psum, 16, 64);
        psum += __shfl_xor(psum, 32, 64);
        __syncthreads();

        f32x4 oacc[2];
        oacc[0] = (f32x4){0.f, 0.f, 0.f, 0.f};
        oacc[1] = (f32x4){0.f, 0.f, 0.f, 0.f};
        #pragma unroll
        for (int kst = 0; kst < 2; ++kst) {
            short8 bfv = *(const short8*)&P_lds[lr][kst * 32 + lk * 8];
            #pragma unroll
            for (int dt = 0; dt < 2; ++dt) {
                short8 af = *(const short8*)&VT_lds[dt * 16 + lr][kst * 32 + lk * 8];
                oacc[dt] = __builtin_amdgcn_mfma_f32_16x16x32_bf16(af, bfv, oacc[dt], 0, 0, 0);
            }
        }
        if (i < NWIN_N) {
            float inv = 1.f / psum;
            unsigned short* orow = (unsigned short*)outp + (rowbase + i) * CH + head * HD;
            #pragma unroll
            for (int dt = 0; dt < 2; ++dt) {
                uint2 wv;
                wv.x = (unsigned)bf16_bits(oacc[dt][0] * inv)
                     | ((unsigned)bf16_bits(oacc[dt][1] * inv) << 16);
                wv.y = (unsigned)bf16_bits(oacc[dt][2] * inv)
                     | ((unsigned)bf16_bits(oacc[dt][3] * inv) << 16);
                *(uint2*)&orow[dt * 16 + lk * 4] = wv;
            }
        }
        __syncthreads();
    }
}

// ---------------------------------------------------------------------------
// 5) cross-channel attention, MFMA flash. qkvc pitch 168: q@0, k@56, v@112.
// ---------------------------------------------------------------------------
__global__ __launch_bounds__(256) void cross_attn_mfma_kernel(
    const __hip_bfloat16* __restrict__ qkv,   // [262144][168]
    __hip_bfloat16* __restrict__ outp)        // [262144][64] padded
{
    __shared__ __align__(16) unsigned short K_lds[64][72];
    __shared__ __align__(16) unsigned short VT_lds[64][72];
    __shared__ __align__(16) unsigned short P_lds[2][64][72]; // [0] doubles as V-scratch

    const int bc = blockIdx.x;
    const size_t base = (size_t)bc * 256;
    const int tid  = threadIdx.x;
    const int lane = tid & 63;
    const int wave = tid >> 6;
    const int i0w  = wave * 64;
    const int lr   = lane & 15;
    const int lk   = lane >> 4;
    const int prow = wave * 16 + lr;

    const unsigned short* q16 = (const unsigned short*)qkv;
    const float inv7 = 1.f / 7.f;   // 49^-0.5
    const short8 zf = (short8){0, 0, 0, 0, 0, 0, 0, 0};

    short8 qf[4][2];
    #pragma unroll
    for (int it = 0; it < 4; ++it) {
        const unsigned short* qrow = q16 + (base + i0w + it * 16 + lr) * 168;
        #pragma unroll
        for (int kst = 0; kst < 2; ++kst) {
            int k0 = lk * 8 + kst * 32;
            qf[it][kst] = (k0 <= 48) ? *(const short8*)(qrow + k0) : zf;
        }
    }

    float m_run[4], l_run[4];
    f32x4 acc_o[4][4];   // [dt][it]
    #pragma unroll
    for (int it = 0; it < 4; ++it) { m_run[it] = -1e30f; l_run[it] = 0.f; }
    #pragma unroll
    for (int dt = 0; dt < 4; ++dt)
        #pragma unroll
        for (int it = 0; it < 4; ++it) acc_o[dt][it] = (f32x4){0.f, 0.f, 0.f, 0.f};

    for (int jt4 = 0; jt4 < 4; ++jt4) {
        const int j0 = jt4 * 64;
        {
            const int jr = tid >> 3, c8 = (tid & 7) * 8;
            #pragma unroll
            for (int h = 0; h < 2; ++h) {
                int jj = jr + h * 32;
                const unsigned short* row = q16 + (base + j0 + jj) * 168;
                *(short8*)&K_lds[jj][c8]    = (c8 <= 48) ? *(const short8*)(row + 56 + c8) : zf;
                *(short8*)&P_lds[0][jj][c8] = (c8 <= 48) ? *(const short8*)(row + 112 + c8) : zf;
            }
        }
        __syncthreads();
        {
            const int jj = tid & 63, dg = tid >> 6;
            #pragma unroll
            for (int e = 0; e < 16; ++e) {
                int d = dg * 16 + e;
                VT_lds[d][jj] = P_lds[0][jj][d];
            }
        }
        __syncthreads();

        #pragma unroll
        for (int it = 0; it < 4; ++it) {
            unsigned short* prowp = &P_lds[it & 1][prow][0];
            f32x4 sacc[4];
            #pragma unroll
            for (int jt = 0; jt < 4; ++jt) sacc[jt] = (f32x4){0.f, 0.f, 0.f, 0.f};
            #pragma unroll
            for (int kst = 0; kst < 2; ++kst) {
                #pragma unroll
                for (int jt = 0; jt < 4; ++jt) {
                    short8 af = *(const short8*)&K_lds[jt * 16 + lr][lk * 8 + kst * 32];
                    sacc[jt] = __builtin_amdgcn_mfma_f32_16x16x32_bf16(
                        af, qf[it][kst], sacc[jt], 0, 0, 0);
                }
            }
            float mt = -1e30f;
            #pragma unroll
            for (int jt = 0; jt < 4; ++jt)
                #pragma unroll
                for (int r = 0; r < 4; ++r) mt = fmaxf(mt, sacc[jt][r]);
            mt = fmaxf(mt, __shfl_xor(mt, 16, 64));
            mt = fmaxf(mt, __shfl_xor(mt, 32, 64));
            float mnew = fmaxf(m_run[it], mt * inv7);
            float corr = __expf(m_run[it] - mnew);
            m_run[it] = mnew;
            l_run[it] *= corr;
            #pragma unroll
            for (int dt = 0; dt < 4; ++dt)
                #pragma unroll
                for (int r = 0; r < 4; ++r) acc_o[dt][it][r] *= corr;

            float psum = 0.f;
            #pragma unroll
            for (int jt = 0; jt < 4; ++jt) {
                float p0 = __expf(sacc[jt][0] * inv7 - mnew);
                float p1 = __expf(sacc[jt][1] * inv7 - mnew);
                float p2 = __expf(sacc[jt][2] * inv7 - mnew);
                float p3 = __expf(sacc[jt][3] * inv7 - mnew);
                psum += (p0 + p1) + (p2 + p3);
                uint2 wv;
                wv.x = (unsigned)bf16_bits(p0) | ((unsigned)bf16_bits(p1) << 16);
                wv.y = (unsigned)bf16_bits(p2) | ((unsigned)bf16_bits(p3) << 16);
                *(uint2*)(prowp + jt * 16 + lk * 4) = wv;
            }
            psum += __shfl_xor(psum, 16, 64);
            psum += __shfl_xor(psum, 32, 64);
            l_run[it] += psum;

            #pragma unroll
            for (int kst = 0; kst < 2; ++kst) {
                short8 bfv = *(const short8*)(prowp + kst * 32 + lk * 8);
                #pragma unroll
                for (int dt = 0; dt < 4; ++dt) {
                    short8 af = *(const short8*)&VT_lds[dt * 16 + lr][kst * 32 + lk * 8];
                    acc_o[dt][it] = __builtin_amdgcn_mfma_f32_16x16x32_bf16(
                        af, bfv, acc_o[dt][it], 0, 0, 0);
                }
            }
        }
        __syncthreads();
    }

    #pragma unroll
    for (int it = 0; it < 4; ++it) {
        float inv = 1.f / l_run[it];
        unsigned short* orow = (unsigned short*)outp + (base + i0w + it * 16 + lr) * 64;
        #pragma unroll
        for (int dt = 0; dt < 4; ++dt) {
            uint2 wv;
            wv.x = (unsigned)bf16_bits(acc_o[dt][it][0] * inv)
                 | ((unsigned)bf16_bits(acc_o[dt][it][1] * inv) << 16);
            wv.y = (unsigned)bf16_bits(acc_o[dt][it][2] * inv)
                 | ((unsigned)bf16_bits(acc_o[dt][it][3] * inv) << 16);
            *(uint2*)&orow[dt * 16 + lk * 4] = wv;
        }
    }
}

// ---------------------------------------------------------------------------
// 6a) FUSED transpose + pad: patches[b][r=p*49+t][c] -> pc_pad[((b*256+c)*256+p)*64+t]
// grid (4, 196, B), 256 threads; cols 49..63 pre-zeroed by one wavefront pass.
// ---------------------------------------------------------------------------
__global__ __launch_bounds__(256) void transpose_pad_kernel(
    const __hip_bfloat16* __restrict__ patches, unsigned short* __restrict__ pc_pad)
{
    __shared__ __hip_bfloat16 T[64][66];
    int b = blockIdx.z;
    int r0 = blockIdx.y * 64, c0 = blockIdx.x * 64;
    const __hip_bfloat16* s = patches + (size_t)b * 12544 * 256;
    int tid = threadIdx.x;
    int lr4 = tid >> 6, lc = tid & 63;

    #pragma unroll
    for (int l = 0; l < 16; ++l) {
        int rr = l * 4 + lr4;
        T[rr][lc] = s[(size_t)(r0 + rr) * 256 + c0 + lc];
    }
    __syncthreads();
    // write: element (c = c0+cc, r = r0+lc) -> pc_pad[((b*256+c)*256 + p)*64 + t]
    int r = r0 + lc;
    int p = r / 49, t = r - p * 49;
    #pragma unroll
    for (int l = 0; l < 16; ++l) {
        int cc = l * 4 + lr4;
        size_t dst = (((size_t)(b * 256 + c0 + cc) * 256) + p) * 64 + t;
        pc_pad[dst] = *(unsigned short*)&T[lc][cc];
    }
    // zero pad cols t=49..63: 262144/4 rows per b handled by... each block zeroes
    // its own (c-range, p-range): c0..c0+63 x p-range touched by r0..r0+63.
    int plo = r0 / 49, phi = (r0 + 63) / 49;
    for (int pp = plo; pp <= phi; ++pp) {
        if (pp >= 256) break;
        for (int idx = tid; idx < 64 * 15; idx += 256) {
            int cc = idx / 15, t2 = 49 + idx % 15;
            size_t dst = (((size_t)(b * 256 + c0 + cc) * 256) + pp) * 64 + t2;
            pc_pad[dst] = 0;
        }
    }
}

// ---------------------------------------------------------------------------
// 6) batched 2D transpose: src[b][R][Cc] -> dst[b][Cc][R]; grid (Cc/64,R/64,B)
// ---------------------------------------------------------------------------
__global__ __launch_bounds__(256) void transpose_bf16_kernel(
    const __hip_bfloat16* __restrict__ src, __hip_bfloat16* __restrict__ dst,
    int R, int Cc)
{
    __shared__ __hip_bfloat16 T[64][66];
    int b = blockIdx.z;
    int r0 = blockIdx.y * 64, c0 = blockIdx.x * 64;
    const __hip_bfloat16* s = src + (size_t)b * R * Cc;
    __hip_bfloat16* d = dst + (size_t)b * R * Cc;
    int tid = threadIdx.x;
    int lr = tid >> 6, lc = tid & 63;

    #pragma unroll
    for (int l = 0; l < 16; ++l) {
        int rr = l * 4 + lr;
        T[rr][lc] = s[(size_t)(r0 + rr) * Cc + c0 + lc];
    }
    __syncthreads();
    #pragma unroll
    for (int l = 0; l < 16; ++l) {
        int cc = l * 4 + lr;
        d[(size_t)(c0 + cc) * R + r0 + lc] = T[lc][cc];
    }
}

// ---------------------------------------------------------------------------
__global__ void ws_marker_kernel(float* __restrict__ out0)
{
    if (threadIdx.x == 0) out0[0] = 777.0f;
}

// ---------------------------------------------------------------------------
extern "C" void kernel_launch(void* const* d_in, const int* in_sizes, int n_in,
                              void* d_out, int out_size, void* d_ws, size_t ws_size,
                              hipStream_t stream)
{
    const float* x        = (const float*)d_in[0];
    const float* gamma    = (const float*)d_in[1];
    const float* beta     = (const float*)d_in[2];
    const float* qkv_l_w  = (const float*)d_in[3];
    const float* qkv_l_b  = (const float*)d_in[4];
    const float* proj_l_w = (const float*)d_in[5];
    const float* proj_l_b = (const float*)d_in[6];
    const float* rpb      = (const float*)d_in[7];
    const float* qkv_c_w  = (const float*)d_in[8];
    const float* qkv_c_b  = (const float*)d_in[9];
    const float* proj_c_w = (const float*)d_in[10];
    const float* proj_c_b = (const float*)d_in[11];
    const float* proj_w   = (const float*)d_in[12];

    float* out0 = (float*)d_out;
    float* out1 = out0 + ELEMS;

    copy_f32_kernel<<<(int)(ELEMS / 1024), 256, 0, stream>>>(x, out1);

    char* ws = (char*)d_ws;
    if (ws_size < 6 * SZ) {
        ws_marker_kernel<<<1, 64, 0, stream>>>(out0);
        return;
    }

    const size_t P = SZ;
    // plane/lifetime map (same as R12, pc_dense deleted):
    __hip_bfloat16* localOut  = (__hip_bfloat16*)(ws + 0 * P);
    unsigned short* wt_qkv_l  = (unsigned short*)(ws + 0 * P);
    float*          biasb     = (float*)(ws + 0 * P + 0x80000);
    __hip_bfloat16* patches   = (__hip_bfloat16*)(ws + 1 * P);
    __hip_bfloat16* qkv_l     = (__hip_bfloat16*)(ws + 2 * P);
    __hip_bfloat16* attnL     = (__hip_bfloat16*)(ws + 5 * P);
    char*           G         = ws + 4 * P + 0xB00000;
    unsigned short* wt_proj_l = (unsigned short*)(G + 0x000000);
    unsigned short* wt_qkv_c  = (unsigned short*)(G + 0x080000);
    unsigned short* wt_proj_c = (unsigned short*)(G + 0x100000);
    unsigned short* wt_final  = (unsigned short*)(G + 0x180000);
    float*          biasc     = (float*)(G + 0x300000);
    __hip_bfloat16* pc_pad    = (__hip_bfloat16*)(ws + 6 * P - (size_t)262144 * 64 * 2);
    __hip_bfloat16* qkvc      = (__hip_bfloat16*)(ws + 1 * P);
    __hip_bfloat16* crossAttn = pc_pad;
    __hip_bfloat16* crossProj = (__hip_bfloat16*)(ws + 1 * P);
    __hip_bfloat16* crossT    = (__hip_bfloat16*)(ws + 2 * P);

    // K0) weight prep needed before K3; bias table before K4
    prep_wt_kernel<<<768, 256, 0, stream>>>(qkv_l_w, wt_qkv_l, 256, 768, 256, 768);
    bias_prep_kernel<<<128, 256, 0, stream>>>(rpb, biasb);
    // K1) LN + window partition
    ln_partition_kernel<<<BB * HH * 7, 256, 0, stream>>>(x, gamma, beta, patches);
    // K3) qkv_local: [50176,256] @ [256,768], pitch 768
    gemm_mfma_kernel<<<dim3(12, 392), 256, 0, stream>>>(
        patches, nullptr, 256, wt_qkv_l, qkv_l_b, qkv_l, nullptr, 50176, 768, 256, 768);
    // K4) local attention (MFMA)
    local_attn_mfma_kernel<<<1024 * NHEAD, 64, 0, stream>>>(qkv_l, biasb, attnL);
    // K4.5) remaining weight preps
    prep_wt_kernel<<<256, 256, 0, stream>>>(proj_l_w, wt_proj_l, 256, 256, 256, 256);
    prep_wt_qkvc_kernel<<<48, 256, 0, stream>>>(qkv_c_w, wt_qkv_c);
    prep_bias_c_kernel<<<1, 192, 0, stream>>>(qkv_c_b, biasc);
    prep_wt_kernel<<<16, 256, 0, stream>>>(proj_c_w, wt_proj_c, 49, 49, 64, 64);
    prep_wt_kernel<<<512, 256, 0, stream>>>(proj_w, wt_final, 512, 256, 512, 256);
    // K5) proj_local: [50176,256] @ [256,256], pitch 256
    gemm_mfma_kernel<<<dim3(4, 392), 256, 0, stream>>>(
        attnL, nullptr, 256, wt_proj_l, proj_l_b, localOut, nullptr, 50176, 256, 256, 256);
    // K6) fused transpose+pad: patches -> pc_pad [262144][64]
    transpose_pad_kernel<<<dim3(4, 196, BB), 256, 0, stream>>>(
        patches, (unsigned short*)pc_pad);
    // K7) qkv_cross: [262144,64pad] @ [64,161 remapped] -> qkvc pitch 168
    gemm_mfma_kernel<<<dim3(3, 2048), 256, 0, stream>>>(
        pc_pad, nullptr, 64, wt_qkv_c, biasc, qkvc, nullptr, 262144, 161, 64, 168);
    // K8) cross attention (reads pitch 168, aligned segments)
    cross_attn_mfma_kernel<<<1024, 256, 0, stream>>>(qkvc, crossAttn);
    // K9) proj_cross: [262144,64pad] @ [64,49] -> dense [262144][49]
    gemm_mfma_kernel<<<dim3(1, 2048), 256, 0, stream>>>(
        crossAttn, nullptr, 64, wt_proj_c, proj_c_b, crossProj, nullptr, 262144, 49, 64, 49);
    // K10) crossT = per-b transpose back
    transpose_bf16_kernel<<<dim3(196, 4, BB), 256, 0, stream>>>(crossProj, crossT, 256, 12544);
    // K11) final: concat[localOut|crossT] @ proj_w -> out0 fp32 BCHW
    gemm_mfma_kernel<<<dim3(4, 392), 256, 0, stream>>>(
        localOut, crossT, 256, wt_final, nullptr, nullptr, out0, 50176, 256, 512, 256);
}